// Round 4
// baseline (603.327 us; speedup 1.0000x reference)
//
#include <hip/hip_runtime.h>
#include <hip/hip_bf16.h>

typedef __hip_bfloat16 bf16;
typedef __hip_bfloat162 bf162;

__device__ __forceinline__ float b2f(bf16 v) { return __bfloat162float(v); }
__device__ __forceinline__ float2 b22f(bf162 v) {
  return make_float2(__bfloat162float(v.x), __bfloat162float(v.y));
}

// ------------------------------------------------------------------
// dtype detector: bf16 weights have exponent field <= 126 in every
// 16-bit half; fp32 buffers read as halves have ~18% with exp >= 160.
// flag: 0 = bf16, 1 = fp32.
// ------------------------------------------------------------------
__global__ __launch_bounds__(256) void detect_kernel(
    const unsigned short* __restrict__ probe, int nhalves, int* __restrict__ flag) {
  __shared__ int cnt;
  if (threadIdx.x == 0) cnt = 0;
  __syncthreads();
  int local = 0;
  for (int i = threadIdx.x; i < nhalves; i += 256) {
    int e = (probe[i] >> 7) & 0xFF;
    if (e >= 160) local++;
  }
  atomicAdd(&cnt, local);
  __syncthreads();
  if (threadIdx.x == 0) *flag = (cnt > 16) ? 1 : 0;
}

// ------------------------------------------------------------------
// convert a tensor (bf16 or fp32 per flag) to fp32
// ------------------------------------------------------------------
__global__ __launch_bounds__(256) void convert_kernel(
    const void* __restrict__ src, float* __restrict__ dst, int n,
    const int* __restrict__ flag) {
  int i = blockIdx.x * blockDim.x + threadIdx.x;
  if (i >= n) return;
  if (*flag)
    dst[i] = ((const float*)src)[i];
  else
    dst[i] = b2f(((const bf16*)src)[i]);
}

// ------------------------------------------------------------------
// prep: x0 = maxnorm(node_emb[x_idx]); counts = 1 (self loop).
// node_emb dtype per flag. Writes xf (fp32) if store_f, else bf16 mirror xb.
// ------------------------------------------------------------------
__global__ __launch_bounds__(256) void prep_kernel(
    const int* __restrict__ x_idx, const void* __restrict__ node_emb,
    const int* __restrict__ flag, float* __restrict__ xf, bf16* __restrict__ xb,
    int store_f, int* __restrict__ counts, int N) {
  int wid = threadIdx.x >> 6, lane = threadIdx.x & 63;
  int n = blockIdx.x * 4 + wid;
  if (n >= N) return;
  int idx = x_idx[n];
  if ((unsigned)idx >= (unsigned)N) idx = 0;  // safety clamp
  float v0, v1;
  if (*flag) {
    const float* er = (const float*)node_emb + (size_t)idx * 128;
    v0 = er[lane]; v1 = er[lane + 64];
  } else {
    const bf16* er = (const bf16*)node_emb + (size_t)idx * 128;
    v0 = b2f(er[lane]); v1 = b2f(er[lane + 64]);
  }
  float ss = v0 * v0 + v1 * v1;
#pragma unroll
  for (int d = 32; d > 0; d >>= 1) ss += __shfl_xor(ss, d);
  float norm = sqrtf(ss);
  float scale = norm > 1.0f ? 1.0f / norm : 1.0f;
  v0 *= scale; v1 *= scale;
  if (store_f) {
    xf[(size_t)n * 128 + lane] = v0;
    xf[(size_t)n * 128 + 64 + lane] = v1;
  } else {
    xb[(size_t)n * 128 + lane] = __float2bfloat16(v0);
    xb[(size_t)n * 128 + 64 + lane] = __float2bfloat16(v1);
  }
  if (lane == 0) counts[n] = 1;
}

// ------------------------------------------------------------------
__global__ __launch_bounds__(256) void count_kernel(
    const int* __restrict__ dst, int* __restrict__ counts, int E0, int N) {
  int i = blockIdx.x * blockDim.x + threadIdx.x;
  if (i < E0) {
    int d = dst[i];
    if ((unsigned)d >= (unsigned)N) d = 0;
    atomicAdd(&counts[d], 1);
  }
}

// ------------------------------------------------------------------
// exclusive scan: counts -> row_ptr; counts becomes cursor (in place)
// ------------------------------------------------------------------
__global__ __launch_bounds__(64) void scan_kernel(
    int* __restrict__ counts, int* __restrict__ row_ptr, int N) {
  int lane = threadIdx.x;
  int chunk = (N + 63) / 64;
  int lo = lane * chunk;
  int hi = lo + chunk; if (hi > N) hi = N; if (lo > N) lo = N;
  int s = 0;
  for (int i = lo; i < hi; ++i) s += counts[i];
  int incl = s;
#pragma unroll
  for (int d = 1; d < 64; d <<= 1) {
    int t = __shfl_up(incl, d);
    if (lane >= d) incl += t;
  }
  int run = incl - s;  // exclusive
  for (int i = lo; i < hi; ++i) {
    int c = counts[i];
    row_ptr[i] = run;
    counts[i] = run;   // becomes cursor
    run += c;
  }
  if (lane == 63) row_ptr[N] = run;
}

// ------------------------------------------------------------------
// scatter edges (+self loops, etype=64) into CSR: packed = src | et<<16
// ------------------------------------------------------------------
__global__ __launch_bounds__(256) void scatter_kernel(
    const int* __restrict__ src, const int* __restrict__ dst,
    const int* __restrict__ et, int* __restrict__ cursor,
    int* __restrict__ packed, int E0, int N) {
  int E = E0 + N;
  int i = blockIdx.x * blockDim.x + threadIdx.x;
  if (i < E0) {
    int d = dst[i];
    if ((unsigned)d >= (unsigned)N) d = 0;
    int p = atomicAdd(&cursor[d], 1);
    if ((unsigned)p >= (unsigned)E) p = 0;
    int t = et[i] & 63;
    packed[p] = (src[i] & 0xFFFF) | (t << 16);
  } else if (i < E) {
    int n = i - E0;
    int p = atomicAdd(&cursor[n], 1);
    if ((unsigned)p >= (unsigned)E) p = 0;
    packed[p] = (n & 0xFFFF) | (64 << 16);
  }
}

// ------------------------------------------------------------------
// s_et[l][t][h] = dot(edge_emb[t], att_l[h, 256:288]); t==64 -> 0
// all inputs fp32 (converted)
// ------------------------------------------------------------------
__global__ __launch_bounds__(512) void set_kernel(
    const float* __restrict__ eef, const float* __restrict__ att1f,
    const float* __restrict__ att2f, float* __restrict__ s_et) {
  int id = threadIdx.x;
  if (id >= 2 * 65 * 3) return;
  int l = id / (65 * 3);
  int r = id % (65 * 3);
  int t = r / 3, h = r % 3;
  const float* att = l ? att2f : att1f;
  float s = 0.0f;
  if (t < 64) {
    for (int d = 0; d < 32; ++d)
      s += eef[t * 32 + d] * att[h * 288 + 256 + d];
  }
  s_et[id] = s;
}

// ------------------------------------------------------------------
// xh = x @ W ([N,128]x[128,384]) fp32 acc, bf16 store. W fp32 (converted).
// XB=1: x from bf16 mirror; XB=0: x from fp32 xf.
// ------------------------------------------------------------------
template <int XB>
__global__ __launch_bounds__(384) void gemm_xh_kernel(
    const float* __restrict__ xf, const bf16* __restrict__ xb,
    const float* __restrict__ Wf, bf16* __restrict__ xh, int N) {
  int m = threadIdx.x;
  int row0 = blockIdx.x * 16;
  float acc[16];
#pragma unroll
  for (int r = 0; r < 16; ++r) acc[r] = 0.0f;
#pragma unroll 4
  for (int k = 0; k < 128; ++k) {
    float w = Wf[k * 384 + m];
#pragma unroll
    for (int r = 0; r < 16; ++r) {
      size_t xi = (size_t)(row0 + r) * 128 + k;
      float xv = XB ? b2f(xb[xi]) : xf[xi];
      acc[r] = fmaf(xv, w, acc[r]);
    }
  }
#pragma unroll
  for (int r = 0; r < 16; ++r) {
    int row = row0 + r;
    if (row < N) xh[(size_t)row * 384 + m] = __float2bfloat16(acc[r]);
  }
}

// ------------------------------------------------------------------
// s_i[n,h] = dot(xh[n,h], att[h,0:128]); s_j[n,h] = dot(xh[n,h], att[h,128:256])
// xh bf16 internal, att fp32 (converted, viewed as float2)
// ------------------------------------------------------------------
__global__ __launch_bounds__(256) void s_kernel(
    const bf162* __restrict__ xh2, const float2* __restrict__ attf2,
    float* __restrict__ s_i, float* __restrict__ s_j, int N) {
  int wid = threadIdx.x >> 6, lane = threadIdx.x & 63;
  int n = blockIdx.x * 4 + wid;
  if (n >= N) return;
  const bf162* xr = xh2 + (size_t)n * 192;
#pragma unroll
  for (int h = 0; h < 3; ++h) {
    float2 v = b22f(xr[h * 64 + lane]);
    float2 ai = attf2[h * 144 + lane];
    float2 aj = attf2[h * 144 + 64 + lane];
    float pi = v.x * ai.x + v.y * ai.y;
    float pj = v.x * aj.x + v.y * aj.y;
#pragma unroll
    for (int d = 32; d > 0; d >>= 1) {
      pi += __shfl_xor(pi, d);
      pj += __shfl_xor(pj, d);
    }
    if (lane == 0) {
      s_i[n * 3 + h] = pi;
      s_j[n * 3 + h] = pj;
    }
  }
}

// ------------------------------------------------------------------
// fused: per-dst softmax + weighted aggregation + (aggr @ euw + bias)
// + optional ELU. euw/bias/edge_emb fp32 (converted).
// Output: xf (fp32, if store_f) / bf16 mirror xb (if !store_f) /
// final: d_out in detected dtype.
// ------------------------------------------------------------------
__global__ __launch_bounds__(256) void edge_aggr_kernel(
    const bf162* __restrict__ xh2, const float* __restrict__ s_i,
    const float* __restrict__ s_j, const float* __restrict__ s_et,
    const float2* __restrict__ eef2, const int* __restrict__ row_ptr,
    const int* __restrict__ packed,
    const float* __restrict__ euwf, const float* __restrict__ biasf,
    float* __restrict__ xf, bf16* __restrict__ xb, void* __restrict__ dout,
    const int* __restrict__ flag,
    int N, int E, int do_elu, int store_f, int do_final) {
  __shared__ __align__(16) float srow[4][160];
  int wid = threadIdx.x >> 6, lane = threadIdx.x & 63;
  int n0 = blockIdx.x * 4 + wid;
  int n = n0 < N ? n0 : N - 1;  // clamp; all threads stay for barrier
  int start = row_ptr[n], end = row_ptr[n + 1];
  if (start < 0) start = 0;
  if (start > E) start = E;
  if (end < start) end = start;
  if (end > E) end = E;
  float si0 = s_i[n * 3 + 0], si1 = s_i[n * 3 + 1], si2 = s_i[n * 3 + 2];

  // pass 1: per-head max of leaky_relu(logit)
  float m0 = -1e30f, m1 = -1e30f, m2 = -1e30f;
  for (int e = start + lane; e < end; e += 64) {
    int p = packed[e];
    int s = p & 0xFFFF; if (s >= N) s = N - 1;
    int t = (p >> 16) & 127; if (t > 64) t = 64;
    float a0 = si0 + s_j[s * 3 + 0] + s_et[t * 3 + 0];
    float a1 = si1 + s_j[s * 3 + 1] + s_et[t * 3 + 1];
    float a2 = si2 + s_j[s * 3 + 2] + s_et[t * 3 + 2];
    a0 = a0 > 0.0f ? a0 : 0.2f * a0;
    a1 = a1 > 0.0f ? a1 : 0.2f * a1;
    a2 = a2 > 0.0f ? a2 : 0.2f * a2;
    m0 = fmaxf(m0, a0); m1 = fmaxf(m1, a1); m2 = fmaxf(m2, a2);
  }
#pragma unroll
  for (int d = 32; d > 0; d >>= 1) {
    m0 = fmaxf(m0, __shfl_xor(m0, d));
    m1 = fmaxf(m1, __shfl_xor(m1, d));
    m2 = fmaxf(m2, __shfl_xor(m2, d));
  }

  // pass 2: exp weights + aggregate (edges serial, features lane-parallel)
  float d0 = 0.0f, d1 = 0.0f, d2 = 0.0f;
  float2 ax0 = make_float2(0.f, 0.f), ax1 = ax0, ax2 = ax0;
  float2 ae0 = ax0, ae1 = ax0, ae2 = ax0;
  for (int e = start; e < end; ++e) {
    int p = packed[e];
    int s = p & 0xFFFF; if (s >= N) s = N - 1;
    int t = (p >> 16) & 127; if (t > 64) t = 64;
    float a0 = si0 + s_j[s * 3 + 0] + s_et[t * 3 + 0];
    float a1 = si1 + s_j[s * 3 + 1] + s_et[t * 3 + 1];
    float a2 = si2 + s_j[s * 3 + 2] + s_et[t * 3 + 2];
    a0 = a0 > 0.0f ? a0 : 0.2f * a0;
    a1 = a1 > 0.0f ? a1 : 0.2f * a1;
    a2 = a2 > 0.0f ? a2 : 0.2f * a2;
    float p0 = __expf(a0 - m0);
    float p1 = __expf(a1 - m1);
    float p2 = __expf(a2 - m2);
    d0 += p0; d1 += p1; d2 += p2;
    const bf162* xrow = xh2 + (size_t)s * 192;
    float2 v0 = b22f(xrow[lane]);
    float2 v1 = b22f(xrow[64 + lane]);
    float2 v2 = b22f(xrow[128 + lane]);
    ax0.x = fmaf(p0, v0.x, ax0.x); ax0.y = fmaf(p0, v0.y, ax0.y);
    ax1.x = fmaf(p1, v1.x, ax1.x); ax1.y = fmaf(p1, v1.y, ax1.y);
    ax2.x = fmaf(p2, v2.x, ax2.x); ax2.y = fmaf(p2, v2.y, ax2.y);
    if (t != 64 && lane < 16) {
      float2 ev = eef2[t * 16 + lane];
      ae0.x = fmaf(p0, ev.x, ae0.x); ae0.y = fmaf(p0, ev.y, ae0.y);
      ae1.x = fmaf(p1, ev.x, ae1.x); ae1.y = fmaf(p1, ev.y, ae1.y);
      ae2.x = fmaf(p2, ev.x, ae2.x); ae2.y = fmaf(p2, ev.y, ae2.y);
    }
  }
  const float third = 1.0f / 3.0f;
  float i0 = third / fmaxf(d0, 1e-30f);
  float i1 = third / fmaxf(d1, 1e-30f);
  float i2 = third / fmaxf(d2, 1e-30f);
  float2* row2 = (float2*)srow[wid];
  row2[lane] = make_float2(ax0.x * i0 + ax1.x * i1 + ax2.x * i2,
                           ax0.y * i0 + ax1.y * i1 + ax2.y * i2);
  if (lane < 16)
    row2[64 + lane] = make_float2(ae0.x * i0 + ae1.x * i1 + ae2.x * i2,
                                  ae0.y * i0 + ae1.y * i1 + ae2.y * i2);
  __syncthreads();

  // epilogue: out[n, m] = bias[m] + sum_k row[k] * euw[k*128+m]
  const float* row = srow[wid];
  float a0 = 0.0f, a1 = 0.0f;
#pragma unroll 4
  for (int k = 0; k < 160; ++k) {
    float rv = row[k];
    a0 = fmaf(rv, euwf[k * 128 + lane], a0);
    a1 = fmaf(rv, euwf[k * 128 + 64 + lane], a1);
  }
  a0 += biasf[lane];
  a1 += biasf[64 + lane];
  if (do_elu) {
    a0 = a0 > 0.0f ? a0 : expm1f(a0);
    a1 = a1 > 0.0f ? a1 : expm1f(a1);
  }
  if (n0 < N) {
    if (do_final) {
      if (*flag) {
        ((float*)dout)[(size_t)n0 * 128 + lane] = a0;
        ((float*)dout)[(size_t)n0 * 128 + 64 + lane] = a1;
      } else {
        ((bf16*)dout)[(size_t)n0 * 128 + lane] = __float2bfloat16(a0);
        ((bf16*)dout)[(size_t)n0 * 128 + 64 + lane] = __float2bfloat16(a1);
      }
    } else if (store_f) {
      xf[(size_t)n0 * 128 + lane] = a0;
      xf[(size_t)n0 * 128 + 64 + lane] = a1;
    } else {
      xb[(size_t)n0 * 128 + lane] = __float2bfloat16(a0);
      xb[(size_t)n0 * 128 + 64 + lane] = __float2bfloat16(a1);
    }
  }
}

// ------------------------------------------------------------------
extern "C" void kernel_launch(void* const* d_in, const int* in_sizes, int n_in,
                              void* d_out, int out_size, void* d_ws, size_t ws_size,
                              hipStream_t stream) {
  const int* x_idx = (const int*)d_in[0];
  const int* edge_index = (const int*)d_in[1];
  const int* edge_attr_idx = (const int*)d_in[2];

  int N = in_sizes[0];
  int E0 = in_sizes[1] / 2;
  int E = E0 + N;
  const int* src = edge_index;
  const int* dst = edge_index + E0;

  // ---- workspace carve ----
  size_t off = 0;
  char* base = (char*)d_ws;
  auto carve = [&](size_t bytes) -> void* {
    void* p = base + off;
    off += (bytes + 255) & ~(size_t)255;
    return p;
  };
  int* flag     = (int*)carve(256);
  int* counts   = (int*)carve((size_t)N * 4);        // becomes cursor after scan
  int* row_ptr  = (int*)carve((size_t)(N + 1) * 4);
  int* packed   = (int*)carve((size_t)E * 4);
  float* s_i    = (float*)carve((size_t)N * 3 * 4);
  float* s_j    = (float*)carve((size_t)N * 3 * 4);
  float* s_et   = (float*)carve(2 * 65 * 3 * 4);
  // fp32 weight copies
  float* eef    = (float*)carve(64 * 32 * 4);
  float* w1f    = (float*)carve(128 * 384 * 4);
  float* att1f  = (float*)carve(3 * 288 * 4);
  float* euw1f  = (float*)carve(160 * 128 * 4);
  float* b1f    = (float*)carve(128 * 4);
  float* w2f    = (float*)carve(128 * 384 * 4);
  float* att2f  = (float*)carve(3 * 288 * 4);
  float* euw2f  = (float*)carve(160 * 128 * 4);
  float* b2f_   = (float*)carve(128 * 4);
  bf16* xh      = (bf16*)carve((size_t)N * 384 * 2);
  // optional fp32 x buffer if it fits; else bf16 x mirror lives in d_out
  size_t x_bytes = (size_t)N * 128 * 4;
  float* xf = nullptr;
  int store_f = 0;
  if (off + x_bytes <= ws_size) {
    xf = (float*)carve(x_bytes);
    store_f = 1;
  }
  bf16* xb = (bf16*)d_out;  // bf16 intermediate mirror (fits either dtype)
  (void)n_in; (void)out_size;

  // ---- dtype detect + weight conversion ----
  detect_kernel<<<1, 256, 0, stream>>>((const unsigned short*)d_in[5], 2048, flag);
  auto conv = [&](int i, float* dstp, int n) {
    convert_kernel<<<(n + 255) / 256, 256, 0, stream>>>(d_in[i], dstp, n, flag);
  };
  conv(4, eef, 64 * 32);
  conv(5, w1f, 128 * 384);
  conv(6, att1f, 3 * 288);
  conv(7, euw1f, 160 * 128);
  conv(8, b1f, 128);
  conv(9, w2f, 128 * 384);
  conv(10, att2f, 3 * 288);
  conv(11, euw2f, 160 * 128);
  conv(12, b2f_, 128);

  int nb4 = (N + 3) / 4;

  prep_kernel<<<nb4, 256, 0, stream>>>(x_idx, d_in[3], flag, xf, xb, store_f,
                                       counts, N);
  count_kernel<<<(E0 + 255) / 256, 256, 0, stream>>>(dst, counts, E0, N);
  set_kernel<<<1, 512, 0, stream>>>(eef, att1f, att2f, s_et);
  scan_kernel<<<1, 64, 0, stream>>>(counts, row_ptr, N);
  scatter_kernel<<<(E + 255) / 256, 256, 0, stream>>>(src, dst, edge_attr_idx,
                                                      counts, packed, E0, N);

  const float* Ws[2] = {w1f, w2f};
  const float* atts[2] = {att1f, att2f};
  const float* euws[2] = {euw1f, euw2f};
  const float* bs[2] = {b1f, b2f_};

  for (int round = 0; round < 2; ++round) {
    for (int l = 0; l < 2; ++l) {
      int do_elu = (l == 0) ? 1 : 0;
      int do_final = (round == 1 && l == 1) ? 1 : 0;
      if (store_f)
        gemm_xh_kernel<0><<<(N + 15) / 16, 384, 0, stream>>>(xf, xb, Ws[l], xh, N);
      else
        gemm_xh_kernel<1><<<(N + 15) / 16, 384, 0, stream>>>(xf, xb, Ws[l], xh, N);
      s_kernel<<<nb4, 256, 0, stream>>>((const bf162*)xh, (const float2*)atts[l],
                                        s_i, s_j, N);
      edge_aggr_kernel<<<nb4, 256, 0, stream>>>(
          (const bf162*)xh, s_i, s_j, s_et + l * 195, (const float2*)eef,
          row_ptr, packed, euws[l], bs[l], xf, xb, d_out, flag,
          N, E, do_elu, store_f, do_final);
    }
  }
}

// Round 5
// 509.857 us; speedup vs baseline: 1.1833x; 1.1833x over previous
//
#include <hip/hip_runtime.h>
#include <hip/hip_bf16.h>

typedef __hip_bfloat16 bf16;
typedef __hip_bfloat162 bf162;

__device__ __forceinline__ float b2f(bf16 v) { return __bfloat162float(v); }
__device__ __forceinline__ float2 b22f(bf162 v) {
  return make_float2(__bfloat162float(v.x), __bfloat162float(v.y));
}
__device__ __forceinline__ float ldv(const void* p, int i, int f) {
  return f ? ((const float*)p)[i] : b2f(((const bf16*)p)[i]);
}

// weight block offsets inside the fp32 workspace copy
#define OFF_EE    0
#define OFF_W1    2048
#define OFF_ATT1  51200
#define OFF_EUW1  52064
#define OFF_B1    72544
#define OFF_W2    72672
#define OFF_ATT2  121824
#define OFF_EUW2  122688
#define OFF_B2    143168
#define WF_TOTAL  143296

// ------------------------------------------------------------------
// 1 block: dtype detect (flag: 0=bf16, 1=fp32) + s_et table.
// s_et[l][t][h] = dot(edge_emb[t], att_l[h,256:288]); t==64 -> 0
// ------------------------------------------------------------------
__global__ __launch_bounds__(512) void detect_set_kernel(
    const unsigned short* __restrict__ probe, int nhalves, int* __restrict__ flag,
    const void* __restrict__ eeraw, const void* __restrict__ att1raw,
    const void* __restrict__ att2raw, float* __restrict__ s_et) {
  __shared__ int cnt;
  __shared__ int fl;
  if (threadIdx.x == 0) cnt = 0;
  __syncthreads();
  int local = 0;
  for (int i = threadIdx.x; i < nhalves; i += 512) {
    int e = (probe[i] >> 7) & 0xFF;
    if (e >= 160) local++;
  }
  if (local) atomicAdd(&cnt, local);
  __syncthreads();
  if (threadIdx.x == 0) { fl = (cnt > 16) ? 1 : 0; *flag = fl; }
  __syncthreads();
  int f = fl;
  int id = threadIdx.x;
  if (id < 2 * 65 * 3) {
    int l = id / (65 * 3);
    int r = id % (65 * 3);
    int t = r / 3, h = r % 3;
    const void* att = l ? att2raw : att1raw;
    float s = 0.0f;
    if (t < 64) {
      for (int d = 0; d < 32; ++d)
        s += ldv(eeraw, t * 32 + d, f) * ldv(att, h * 288 + 256 + d, f);
    }
    s_et[id] = s;
  }
}

// ------------------------------------------------------------------
// convert all 9 weight tensors to fp32 into wf; zero counts.
// ------------------------------------------------------------------
__global__ __launch_bounds__(256) void wconv_kernel(
    const void* __restrict__ ee, const void* __restrict__ w1,
    const void* __restrict__ a1, const void* __restrict__ eu1,
    const void* __restrict__ b1, const void* __restrict__ w2,
    const void* __restrict__ a2, const void* __restrict__ eu2,
    const void* __restrict__ b2, const int* __restrict__ flag,
    float* __restrict__ wf, int* __restrict__ counts, int N) {
  int i = blockIdx.x * 256 + threadIdx.x;
  if (i < WF_TOTAL) {
    int f = *flag;
    const void* src; int base;
    if (i < OFF_W1)        { src = ee;  base = OFF_EE; }
    else if (i < OFF_ATT1) { src = w1;  base = OFF_W1; }
    else if (i < OFF_EUW1) { src = a1;  base = OFF_ATT1; }
    else if (i < OFF_B1)   { src = eu1; base = OFF_EUW1; }
    else if (i < OFF_W2)   { src = b1;  base = OFF_B1; }
    else if (i < OFF_ATT2) { src = w2;  base = OFF_W2; }
    else if (i < OFF_EUW2) { src = a2;  base = OFF_ATT2; }
    else if (i < OFF_B2)   { src = eu2; base = OFF_EUW2; }
    else                   { src = b2;  base = OFF_B2; }
    wf[i] = ldv(src, i - base, f);
  } else if (i < WF_TOTAL + N) {
    counts[i - WF_TOTAL] = 0;
  }
}

// ------------------------------------------------------------------
// prep: x0 = maxnorm(node_emb[x_idx]) (one wave per node)
// + edge counting (grid-stride over edges). counts pre-zeroed by wconv.
// ------------------------------------------------------------------
__global__ __launch_bounds__(256) void prep_kernel(
    const int* __restrict__ x_idx, const void* __restrict__ node_emb,
    const int* __restrict__ flag, float* __restrict__ xf, bf16* __restrict__ xb,
    int store_f, int* __restrict__ counts, const int* __restrict__ dst,
    int E0, int N) {
  int wid = threadIdx.x >> 6, lane = threadIdx.x & 63;
  int n = blockIdx.x * 4 + wid;
  if (n < N) {
    int idx = x_idx[n];
    if ((unsigned)idx >= (unsigned)N) idx = 0;
    float v0, v1;
    if (*flag) {
      const float* er = (const float*)node_emb + (size_t)idx * 128;
      v0 = er[lane]; v1 = er[lane + 64];
    } else {
      const bf16* er = (const bf16*)node_emb + (size_t)idx * 128;
      v0 = b2f(er[lane]); v1 = b2f(er[lane + 64]);
    }
    float ss = v0 * v0 + v1 * v1;
#pragma unroll
    for (int d = 32; d > 0; d >>= 1) ss += __shfl_xor(ss, d);
    float norm = sqrtf(ss);
    float scale = norm > 1.0f ? 1.0f / norm : 1.0f;
    v0 *= scale; v1 *= scale;
    if (store_f) {
      xf[(size_t)n * 128 + lane] = v0;
      xf[(size_t)n * 128 + 64 + lane] = v1;
    } else {
      xb[(size_t)n * 128 + lane] = __float2bfloat16(v0);
      xb[(size_t)n * 128 + 64 + lane] = __float2bfloat16(v1);
    }
  }
  // edge counting
  int gid = blockIdx.x * 256 + threadIdx.x;
  int stride = gridDim.x * 256;
  for (int i = gid; i < E0; i += stride) {
    int d = dst[i];
    if ((unsigned)d >= (unsigned)N) d = 0;
    atomicAdd(&counts[d], 1);
  }
}

// ------------------------------------------------------------------
// exclusive scan with +1 per row (self loop): counts -> row_ptr,
// counts becomes cursor (row start) in place. single wave.
// ------------------------------------------------------------------
__global__ __launch_bounds__(64) void scan_kernel(
    int* __restrict__ counts, int* __restrict__ row_ptr, int N) {
  int lane = threadIdx.x;
  int chunk = (N + 63) / 64;
  int lo = lane * chunk;
  int hi = lo + chunk; if (hi > N) hi = N; if (lo > N) lo = N;
  int s = 0;
  for (int i = lo; i < hi; ++i) s += counts[i] + 1;
  int incl = s;
#pragma unroll
  for (int d = 1; d < 64; d <<= 1) {
    int t = __shfl_up(incl, d);
    if (lane >= d) incl += t;
  }
  int run = incl - s;  // exclusive
  for (int i = lo; i < hi; ++i) {
    int c = counts[i] + 1;
    row_ptr[i] = run;
    counts[i] = run;   // becomes cursor
    run += c;
  }
  if (lane == 63) row_ptr[N] = run;
}

// ------------------------------------------------------------------
// scatter edges (+self loops, etype=64) into CSR: packed = src | et<<16
// ------------------------------------------------------------------
__global__ __launch_bounds__(256) void scatter_kernel(
    const int* __restrict__ src, const int* __restrict__ dst,
    const int* __restrict__ et, int* __restrict__ cursor,
    int* __restrict__ packed, int E0, int N) {
  int E = E0 + N;
  int i = blockIdx.x * blockDim.x + threadIdx.x;
  if (i < E0) {
    int d = dst[i];
    if ((unsigned)d >= (unsigned)N) d = 0;
    int p = atomicAdd(&cursor[d], 1);
    if ((unsigned)p >= (unsigned)E) p = 0;
    int t = et[i] & 63;
    packed[p] = (src[i] & 0xFFFF) | (t << 16);
  } else if (i < E) {
    int n = i - E0;
    int p = atomicAdd(&cursor[n], 1);
    if ((unsigned)p >= (unsigned)E) p = 0;
    packed[p] = (n & 0xFFFF) | (64 << 16);
  }
}

// ------------------------------------------------------------------
// xh = x @ W ([N,128]x[128,384]) fp32 acc, bf16 store + fused s_i/s_j.
// 384 threads = out column; 16 rows/block; x loads wave-uniform.
// s_i[n,h] = dot(xh_f32[n,h,:], att[h,0:128]); s_j: att[h,128:256].
// ------------------------------------------------------------------
template <int XB>
__global__ __launch_bounds__(384) void gemm_xh_s_kernel(
    const float* __restrict__ xf, const bf16* __restrict__ xb,
    const float* __restrict__ Wf, const float* __restrict__ attf,
    bf16* __restrict__ xh, float* __restrict__ s_i, float* __restrict__ s_j,
    int N) {
  __shared__ float lds_i[6][16];
  __shared__ float lds_j[6][16];
  int m = threadIdx.x;
  int row0 = blockIdx.x * 16;
  float acc[16];
#pragma unroll
  for (int r = 0; r < 16; ++r) acc[r] = 0.0f;
#pragma unroll 4
  for (int k = 0; k < 128; ++k) {
    float w = Wf[k * 384 + m];
#pragma unroll
    for (int r = 0; r < 16; ++r) {
      size_t xi = (size_t)(row0 + r) * 128 + k;
      float xv = XB ? b2f(xb[xi]) : xf[xi];
      acc[r] = fmaf(xv, w, acc[r]);
    }
  }
#pragma unroll
  for (int r = 0; r < 16; ++r) {
    int row = row0 + r;
    if (row < N) xh[(size_t)row * 384 + m] = __float2bfloat16(acc[r]);
  }
  // fused s reduction: thread owns column m (head h = m>>7, pos k = m&127)
  int h = m >> 7, k = m & 127;
  float ai = attf[h * 288 + k];
  float aj = attf[h * 288 + 128 + k];
  int wv = m >> 6, lane = m & 63;
#pragma unroll
  for (int r = 0; r < 16; ++r) {
    float pi = acc[r] * ai;
    float pj = acc[r] * aj;
#pragma unroll
    for (int d = 32; d > 0; d >>= 1) {
      pi += __shfl_xor(pi, d);
      pj += __shfl_xor(pj, d);
    }
    if (lane == 0) { lds_i[wv][r] = pi; lds_j[wv][r] = pj; }
  }
  __syncthreads();
  if (m < 48) {
    int hh = m / 16, r = m % 16;
    int row = row0 + r;
    if (row < N) s_i[row * 3 + hh] = lds_i[2 * hh][r] + lds_i[2 * hh + 1][r];
  } else if (m < 96) {
    int t = m - 48;
    int hh = t / 16, r = t % 16;
    int row = row0 + r;
    if (row < N) s_j[row * 3 + hh] = lds_j[2 * hh][r] + lds_j[2 * hh + 1][r];
  }
}

// ------------------------------------------------------------------
// fused: per-dst softmax + weighted aggregation + (aggr @ euw + bias)
// + optional ELU. One wave per node.
// Phase A: one edge per lane -> p = exp(clamp(leaky(logit))) in regs.
//   (no max pass: logits are O(1); clamp +-60 preserves exactness)
// Phase B: serial feature aggregation, edge params via __shfl, 2x unroll.
// ------------------------------------------------------------------
__global__ __launch_bounds__(256) void edge_aggr_kernel(
    const bf162* __restrict__ xh2, const float* __restrict__ s_i,
    const float* __restrict__ s_j, const float* __restrict__ s_et,
    const float2* __restrict__ eef2, const int* __restrict__ row_ptr,
    const int* __restrict__ packed,
    const float* __restrict__ euwf, const float* __restrict__ biasf,
    float* __restrict__ xf, bf16* __restrict__ xb, void* __restrict__ dout,
    const int* __restrict__ flag,
    int N, int E, int do_elu, int store_f, int do_final) {
  __shared__ __align__(16) float srow[4][160];
  int wid = threadIdx.x >> 6, lane = threadIdx.x & 63;
  int n0 = blockIdx.x * 4 + wid;
  int n = n0 < N ? n0 : N - 1;  // clamp; all threads stay for barrier
  int start = row_ptr[n], end = row_ptr[n + 1];
  if (start < 0) start = 0;
  if (start > E) start = E;
  if (end < start) end = start;
  if (end > E) end = E;
  int deg = end - start;
  float si0 = s_i[n * 3 + 0], si1 = s_i[n * 3 + 1], si2 = s_i[n * 3 + 2];

  // ---- phase A: lane-parallel p for first 128 edges, cached in regs ----
  float p0r[2], p1r[2], p2r[2];
  int pkr[2];
  float dp0 = 0.0f, dp1 = 0.0f, dp2 = 0.0f;
#pragma unroll
  for (int it = 0; it < 2; ++it) {
    p0r[it] = p1r[it] = p2r[it] = 0.0f; pkr[it] = 0;
    int slot = it * 64 + lane;
    if (slot < deg) {
      int p = packed[start + slot];
      int s = p & 0xFFFF; if (s >= N) s = N - 1;
      int t = (p >> 16) & 127; if (t > 64) t = 64;
      float a0 = si0 + s_j[s * 3 + 0] + s_et[t * 3 + 0];
      float a1 = si1 + s_j[s * 3 + 1] + s_et[t * 3 + 1];
      float a2 = si2 + s_j[s * 3 + 2] + s_et[t * 3 + 2];
      a0 = a0 > 0.0f ? a0 : 0.2f * a0;
      a1 = a1 > 0.0f ? a1 : 0.2f * a1;
      a2 = a2 > 0.0f ? a2 : 0.2f * a2;
      a0 = fminf(fmaxf(a0, -60.0f), 60.0f);
      a1 = fminf(fmaxf(a1, -60.0f), 60.0f);
      a2 = fminf(fmaxf(a2, -60.0f), 60.0f);
      float p0 = __expf(a0), p1 = __expf(a1), p2 = __expf(a2);
      dp0 += p0; dp1 += p1; dp2 += p2;
      p0r[it] = p0; p1r[it] = p1; p2r[it] = p2;
      pkr[it] = s | (t << 16);
    }
  }
#pragma unroll
  for (int d = 32; d > 0; d >>= 1) {
    dp0 += __shfl_xor(dp0, d);
    dp1 += __shfl_xor(dp1, d);
    dp2 += __shfl_xor(dp2, d);
  }
  float d0 = dp0, d1 = dp1, d2 = dp2;

  // ---- phase B: serial aggregation, params broadcast via shfl ----
  float2 ax0 = make_float2(0.f, 0.f), ax1 = ax0, ax2 = ax0;
  float2 ae0 = ax0, ae1 = ax0, ae2 = ax0;
  int mm = deg < 128 ? deg : 128;

  auto agg_range = [&](int pk_s, float q0_s, float q1_s, float q2_s, int cnt) {
    int j = 0;
    for (; j + 2 <= cnt; j += 2) {
      int pkA = __shfl(pk_s, j), pkB = __shfl(pk_s, j + 1);
      float qA0 = __shfl(q0_s, j), qB0 = __shfl(q0_s, j + 1);
      float qA1 = __shfl(q1_s, j), qB1 = __shfl(q1_s, j + 1);
      float qA2 = __shfl(q2_s, j), qB2 = __shfl(q2_s, j + 1);
      int sA = pkA & 0xFFFF, tA = pkA >> 16;
      int sB = pkB & 0xFFFF, tB = pkB >> 16;
      const bf162* xrA = xh2 + (size_t)sA * 192;
      const bf162* xrB = xh2 + (size_t)sB * 192;
      float2 vA0 = b22f(xrA[lane]);
      float2 vA1 = b22f(xrA[64 + lane]);
      float2 vA2 = b22f(xrA[128 + lane]);
      float2 vB0 = b22f(xrB[lane]);
      float2 vB1 = b22f(xrB[64 + lane]);
      float2 vB2 = b22f(xrB[128 + lane]);
      ax0.x = fmaf(qA0, vA0.x, ax0.x); ax0.y = fmaf(qA0, vA0.y, ax0.y);
      ax1.x = fmaf(qA1, vA1.x, ax1.x); ax1.y = fmaf(qA1, vA1.y, ax1.y);
      ax2.x = fmaf(qA2, vA2.x, ax2.x); ax2.y = fmaf(qA2, vA2.y, ax2.y);
      ax0.x = fmaf(qB0, vB0.x, ax0.x); ax0.y = fmaf(qB0, vB0.y, ax0.y);
      ax1.x = fmaf(qB1, vB1.x, ax1.x); ax1.y = fmaf(qB1, vB1.y, ax1.y);
      ax2.x = fmaf(qB2, vB2.x, ax2.x); ax2.y = fmaf(qB2, vB2.y, ax2.y);
      if (lane < 16) {
        if (tA != 64) {
          float2 ev = eef2[tA * 16 + lane];
          ae0.x = fmaf(qA0, ev.x, ae0.x); ae0.y = fmaf(qA0, ev.y, ae0.y);
          ae1.x = fmaf(qA1, ev.x, ae1.x); ae1.y = fmaf(qA1, ev.y, ae1.y);
          ae2.x = fmaf(qA2, ev.x, ae2.x); ae2.y = fmaf(qA2, ev.y, ae2.y);
        }
        if (tB != 64) {
          float2 ev = eef2[tB * 16 + lane];
          ae0.x = fmaf(qB0, ev.x, ae0.x); ae0.y = fmaf(qB0, ev.y, ae0.y);
          ae1.x = fmaf(qB1, ev.x, ae1.x); ae1.y = fmaf(qB1, ev.y, ae1.y);
          ae2.x = fmaf(qB2, ev.x, ae2.x); ae2.y = fmaf(qB2, ev.y, ae2.y);
        }
      }
    }
    if (j < cnt) {
      int pkA = __shfl(pk_s, j);
      float qA0 = __shfl(q0_s, j), qA1 = __shfl(q1_s, j), qA2 = __shfl(q2_s, j);
      int sA = pkA & 0xFFFF, tA = pkA >> 16;
      const bf162* xrA = xh2 + (size_t)sA * 192;
      float2 vA0 = b22f(xrA[lane]);
      float2 vA1 = b22f(xrA[64 + lane]);
      float2 vA2 = b22f(xrA[128 + lane]);
      ax0.x = fmaf(qA0, vA0.x, ax0.x); ax0.y = fmaf(qA0, vA0.y, ax0.y);
      ax1.x = fmaf(qA1, vA1.x, ax1.x); ax1.y = fmaf(qA1, vA1.y, ax1.y);
      ax2.x = fmaf(qA2, vA2.x, ax2.x); ax2.y = fmaf(qA2, vA2.y, ax2.y);
      if (lane < 16 && tA != 64) {
        float2 ev = eef2[tA * 16 + lane];
        ae0.x = fmaf(qA0, ev.x, ae0.x); ae0.y = fmaf(qA0, ev.y, ae0.y);
        ae1.x = fmaf(qA1, ev.x, ae1.x); ae1.y = fmaf(qA1, ev.y, ae1.y);
        ae2.x = fmaf(qA2, ev.x, ae2.x); ae2.y = fmaf(qA2, ev.y, ae2.y);
      }
    }
  };
  agg_range(pkr[0], p0r[0], p1r[0], p2r[0], mm < 64 ? mm : 64);
  if (mm > 64) agg_range(pkr[1], p0r[1], p1r[1], p2r[1], mm - 64);

  // rare fallback: degree > 128, serial recompute (lane-uniform)
  for (int e = start + 128; e < end; ++e) {
    int p = packed[e];
    int s = p & 0xFFFF; if (s >= N) s = N - 1;
    int t = (p >> 16) & 127; if (t > 64) t = 64;
    float a0 = si0 + s_j[s * 3 + 0] + s_et[t * 3 + 0];
    float a1 = si1 + s_j[s * 3 + 1] + s_et[t * 3 + 1];
    float a2 = si2 + s_j[s * 3 + 2] + s_et[t * 3 + 2];
    a0 = a0 > 0.0f ? a0 : 0.2f * a0;
    a1 = a1 > 0.0f ? a1 : 0.2f * a1;
    a2 = a2 > 0.0f ? a2 : 0.2f * a2;
    a0 = fminf(fmaxf(a0, -60.0f), 60.0f);
    a1 = fminf(fmaxf(a1, -60.0f), 60.0f);
    a2 = fminf(fmaxf(a2, -60.0f), 60.0f);
    float p0 = __expf(a0), p1 = __expf(a1), p2 = __expf(a2);
    d0 += p0; d1 += p1; d2 += p2;
    const bf162* xrow = xh2 + (size_t)s * 192;
    float2 v0 = b22f(xrow[lane]);
    float2 v1 = b22f(xrow[64 + lane]);
    float2 v2 = b22f(xrow[128 + lane]);
    ax0.x = fmaf(p0, v0.x, ax0.x); ax0.y = fmaf(p0, v0.y, ax0.y);
    ax1.x = fmaf(p1, v1.x, ax1.x); ax1.y = fmaf(p1, v1.y, ax1.y);
    ax2.x = fmaf(p2, v2.x, ax2.x); ax2.y = fmaf(p2, v2.y, ax2.y);
    if (t != 64 && lane < 16) {
      float2 ev = eef2[t * 16 + lane];
      ae0.x = fmaf(p0, ev.x, ae0.x); ae0.y = fmaf(p0, ev.y, ae0.y);
      ae1.x = fmaf(p1, ev.x, ae1.x); ae1.y = fmaf(p1, ev.y, ae1.y);
      ae2.x = fmaf(p2, ev.x, ae2.x); ae2.y = fmaf(p2, ev.y, ae2.y);
    }
  }

  const float third = 1.0f / 3.0f;
  float i0 = third / fmaxf(d0, 1e-30f);
  float i1 = third / fmaxf(d1, 1e-30f);
  float i2 = third / fmaxf(d2, 1e-30f);
  float2* row2 = (float2*)srow[wid];
  row2[lane] = make_float2(ax0.x * i0 + ax1.x * i1 + ax2.x * i2,
                           ax0.y * i0 + ax1.y * i1 + ax2.y * i2);
  if (lane < 16)
    row2[64 + lane] = make_float2(ae0.x * i0 + ae1.x * i1 + ae2.x * i2,
                                  ae0.y * i0 + ae1.y * i1 + ae2.y * i2);
  __syncthreads();

  // epilogue: out[n, m] = bias[m] + sum_k row[k] * euw[k*128+m]
  const float* row = srow[wid];
  float a0 = 0.0f, a1 = 0.0f;
#pragma unroll 4
  for (int k = 0; k < 160; ++k) {
    float rv = row[k];
    a0 = fmaf(rv, euwf[k * 128 + lane], a0);
    a1 = fmaf(rv, euwf[k * 128 + 64 + lane], a1);
  }
  a0 += biasf[lane];
  a1 += biasf[64 + lane];
  if (do_elu) {
    a0 = a0 > 0.0f ? a0 : expm1f(a0);
    a1 = a1 > 0.0f ? a1 : expm1f(a1);
  }
  if (n0 < N) {
    if (do_final) {
      if (*flag) {
        ((float*)dout)[(size_t)n0 * 128 + lane] = a0;
        ((float*)dout)[(size_t)n0 * 128 + 64 + lane] = a1;
      } else {
        ((bf16*)dout)[(size_t)n0 * 128 + lane] = __float2bfloat16(a0);
        ((bf16*)dout)[(size_t)n0 * 128 + 64 + lane] = __float2bfloat16(a1);
      }
    } else if (store_f) {
      xf[(size_t)n0 * 128 + lane] = a0;
      xf[(size_t)n0 * 128 + 64 + lane] = a1;
    } else {
      xb[(size_t)n0 * 128 + lane] = __float2bfloat16(a0);
      xb[(size_t)n0 * 128 + 64 + lane] = __float2bfloat16(a1);
    }
  }
}

// ------------------------------------------------------------------
extern "C" void kernel_launch(void* const* d_in, const int* in_sizes, int n_in,
                              void* d_out, int out_size, void* d_ws, size_t ws_size,
                              hipStream_t stream) {
  const int* x_idx = (const int*)d_in[0];
  const int* edge_index = (const int*)d_in[1];
  const int* edge_attr_idx = (const int*)d_in[2];

  int N = in_sizes[0];
  int E0 = in_sizes[1] / 2;
  int E = E0 + N;
  const int* src = edge_index;
  const int* dst = edge_index + E0;

  // ---- workspace carve ----
  size_t off = 0;
  char* base = (char*)d_ws;
  auto carve = [&](size_t bytes) -> void* {
    void* p = base + off;
    off += (bytes + 255) & ~(size_t)255;
    return p;
  };
  int* flag     = (int*)carve(256);
  int* counts   = (int*)carve((size_t)N * 4);        // becomes cursor after scan
  int* row_ptr  = (int*)carve((size_t)(N + 1) * 4);
  int* packed   = (int*)carve((size_t)E * 4);
  float* s_i    = (float*)carve((size_t)N * 3 * 4);
  float* s_j    = (float*)carve((size_t)N * 3 * 4);
  float* s_et   = (float*)carve(2 * 65 * 3 * 4);
  float* wf     = (float*)carve((size_t)WF_TOTAL * 4);
  bf16* xh      = (bf16*)carve((size_t)N * 384 * 2);
  size_t x_bytes = (size_t)N * 128 * 4;
  float* xf = nullptr;
  int store_f = 0;
  if (off + x_bytes <= ws_size) {
    xf = (float*)carve(x_bytes);
    store_f = 1;
  }
  bf16* xb = (bf16*)d_out;  // bf16 intermediate mirror
  (void)n_in; (void)out_size;

  float* eef   = wf + OFF_EE;
  float* w1f   = wf + OFF_W1;
  float* att1f = wf + OFF_ATT1;
  float* euw1f = wf + OFF_EUW1;
  float* b1f   = wf + OFF_B1;
  float* w2f   = wf + OFF_W2;
  float* att2f = wf + OFF_ATT2;
  float* euw2f = wf + OFF_EUW2;
  float* b2f_  = wf + OFF_B2;

  // ---- setup: 5 dispatches ----
  detect_set_kernel<<<1, 512, 0, stream>>>(
      (const unsigned short*)d_in[5], 2048, flag, d_in[4], d_in[6], d_in[10], s_et);
  wconv_kernel<<<(WF_TOTAL + N + 255) / 256, 256, 0, stream>>>(
      d_in[4], d_in[5], d_in[6], d_in[7], d_in[8], d_in[9], d_in[10], d_in[11],
      d_in[12], flag, wf, counts, N);
  int nb4 = (N + 3) / 4;
  prep_kernel<<<nb4, 256, 0, stream>>>(x_idx, d_in[3], flag, xf, xb, store_f,
                                       counts, dst, E0, N);
  scan_kernel<<<1, 64, 0, stream>>>(counts, row_ptr, N);
  scatter_kernel<<<(E + 255) / 256, 256, 0, stream>>>(src, dst, edge_attr_idx,
                                                      counts, packed, E0, N);

  const float* Ws[2] = {w1f, w2f};
  const float* atts[2] = {att1f, att2f};
  const float* euws[2] = {euw1f, euw2f};
  const float* bs[2] = {b1f, b2f_};

  for (int round = 0; round < 2; ++round) {
    for (int l = 0; l < 2; ++l) {
      int do_elu = (l == 0) ? 1 : 0;
      int do_final = (round == 1 && l == 1) ? 1 : 0;
      if (store_f)
        gemm_xh_s_kernel<0><<<(N + 15) / 16, 384, 0, stream>>>(
            xf, xb, Ws[l], atts[l], xh, s_i, s_j, N);
      else
        gemm_xh_s_kernel<1><<<(N + 15) / 16, 384, 0, stream>>>(
            xf, xb, Ws[l], atts[l], xh, s_i, s_j, N);
      edge_aggr_kernel<<<nb4, 256, 0, stream>>>(
          (const bf162*)xh, s_i, s_j, s_et + l * 195, (const float2*)eef,
          row_ptr, packed, euws[l], bs[l], xf, xb, d_out, flag,
          N, E, do_elu, store_f, do_final);
    }
  }
}

// Round 7
// 381.963 us; speedup vs baseline: 1.5795x; 1.3348x over previous
//
#include <hip/hip_runtime.h>
#include <hip/hip_bf16.h>

typedef __hip_bfloat16 bf16;
typedef __attribute__((ext_vector_type(8))) short short8;
typedef __attribute__((ext_vector_type(4))) float f32x4;

__device__ __forceinline__ float b2f(bf16 v) { return __bfloat162float(v); }
// int (2 packed bf16) -> two floats. x = low half, y = high half.
__device__ __forceinline__ float2 i2f2(int w) {
  float lo = __uint_as_float(((unsigned)w) << 16);
  float hi = __uint_as_float(((unsigned)w) & 0xFFFF0000u);
  return make_float2(lo, hi);
}
// float -> bf16 bits (RNE; inputs finite)
__device__ __forceinline__ unsigned f2bfb(float f) {
  unsigned u = __float_as_uint(f);
  unsigned r = 0x7FFFu + ((u >> 16) & 1u);
  return (u + r) >> 16;
}
// pack two floats into one dword of 2 bf16 (a = low, b = high)
__device__ __forceinline__ unsigned pk2(float a, float b) {
  return f2bfb(a) | (f2bfb(b) << 16);
}
__device__ __forceinline__ float ldv(const void* p, int i, int f) {
  return f ? ((const float*)p)[i] : b2f(((const bf16*)p)[i]);
}

// ------------------------------------------------------------------
// 1 block: dtype detect (flag: 0=bf16, 1=fp32) + s_et table.
// ------------------------------------------------------------------
__global__ __launch_bounds__(512) void detect_set_kernel(
    const unsigned short* __restrict__ probe, int nhalves, int* __restrict__ flag,
    const void* __restrict__ eeraw, const void* __restrict__ att1raw,
    const void* __restrict__ att2raw, float* __restrict__ s_et) {
  __shared__ int cnt;
  __shared__ int fl;
  if (threadIdx.x == 0) cnt = 0;
  __syncthreads();
  int local = 0;
  for (int i = threadIdx.x; i < nhalves; i += 512) {
    int e = (probe[i] >> 7) & 0xFF;
    if (e >= 160) local++;
  }
  if (local) atomicAdd(&cnt, local);
  __syncthreads();
  if (threadIdx.x == 0) { fl = (cnt > 16) ? 1 : 0; *flag = fl; }
  __syncthreads();
  int f = fl;
  int id = threadIdx.x;
  if (id < 2 * 65 * 3) {
    int l = id / (65 * 3);
    int r = id % (65 * 3);
    int t = r / 3, h = r % 3;
    const void* att = l ? att2raw : att1raw;
    float s = 0.0f;
    if (t < 64) {
      for (int d = 0; d < 32; ++d)
        s += ldv(eeraw, t * 32 + d, f) * ldv(att, h * 288 + 256 + d, f);
    }
    s_et[id] = s;
  }
}

// ------------------------------------------------------------------
// weight materialization: fp32 small tensors + bf16 transposed GEMM
// operands (WT [384][128], euwT [128][160]); zero counts.
// ------------------------------------------------------------------
__global__ __launch_bounds__(256) void wconv_kernel(
    const void* __restrict__ ee, const void* __restrict__ w1,
    const void* __restrict__ a1, const void* __restrict__ eu1,
    const void* __restrict__ b1, const void* __restrict__ w2,
    const void* __restrict__ a2, const void* __restrict__ eu2,
    const void* __restrict__ b2, const int* __restrict__ flag,
    float* __restrict__ eef, float* __restrict__ att1f, float* __restrict__ att2f,
    float* __restrict__ b1f, float* __restrict__ b2f,
    bf16* __restrict__ WT1, bf16* __restrict__ WT2,
    bf16* __restrict__ euT1, bf16* __restrict__ euT2,
    int* __restrict__ counts, int N) {
  int i = blockIdx.x * 256 + threadIdx.x;
  int f = *flag;
  if (i < 2048) {
    eef[i] = ldv(ee, i, f);
  } else if (i < 2912) {
    att1f[i - 2048] = ldv(a1, i - 2048, f);
  } else if (i < 3776) {
    att2f[i - 2912] = ldv(a2, i - 2912, f);
  } else if (i < 3904) {
    b1f[i - 3776] = ldv(b1, i - 3776, f);
  } else if (i < 4032) {
    b2f[i - 3904] = ldv(b2, i - 3904, f);
  } else if (i < 53184) {
    int j = i - 4032; int c = j >> 7, k = j & 127;
    WT1[j] = __float2bfloat16(ldv(w1, k * 384 + c, f));
  } else if (i < 102336) {
    int j = i - 53184; int c = j >> 7, k = j & 127;
    WT2[j] = __float2bfloat16(ldv(w2, k * 384 + c, f));
  } else if (i < 122816) {
    int j = i - 102336; int c = j / 160, k = j % 160;
    euT1[j] = __float2bfloat16(ldv(eu1, k * 128 + c, f));
  } else if (i < 143296) {
    int j = i - 122816; int c = j / 160, k = j % 160;
    euT2[j] = __float2bfloat16(ldv(eu2, k * 128 + c, f));
  } else if (i < 143296 + N) {
    counts[i - 143296] = 0;
  }
}

// ------------------------------------------------------------------
// prep: x0 = maxnorm(node_emb[x_idx]) -> bf16 x (in d_out);
// + edge counting (grid-stride). counts pre-zeroed by wconv.
// ------------------------------------------------------------------
__global__ __launch_bounds__(256) void prep_kernel(
    const int* __restrict__ x_idx, const void* __restrict__ node_emb,
    const int* __restrict__ flag, bf16* __restrict__ xb,
    int* __restrict__ counts, const int* __restrict__ dst, int E0, int N) {
  int wid = threadIdx.x >> 6, lane = threadIdx.x & 63;
  int n = blockIdx.x * 4 + wid;
  if (n < N) {
    int idx = x_idx[n];
    if ((unsigned)idx >= (unsigned)N) idx = 0;
    float v0, v1;
    if (*flag) {
      const float* er = (const float*)node_emb + (size_t)idx * 128;
      v0 = er[lane]; v1 = er[lane + 64];
    } else {
      const bf16* er = (const bf16*)node_emb + (size_t)idx * 128;
      v0 = b2f(er[lane]); v1 = b2f(er[lane + 64]);
    }
    float ss = v0 * v0 + v1 * v1;
#pragma unroll
    for (int d = 32; d > 0; d >>= 1) ss += __shfl_xor(ss, d);
    float norm = sqrtf(ss);
    float scale = norm > 1.0f ? 1.0f / norm : 1.0f;
    xb[(size_t)n * 128 + lane] = __float2bfloat16(v0 * scale);
    xb[(size_t)n * 128 + 64 + lane] = __float2bfloat16(v1 * scale);
  }
  int gid = blockIdx.x * 256 + threadIdx.x;
  int stride = gridDim.x * 256;
  for (int i = gid; i < E0; i += stride) {
    int d = dst[i];
    if ((unsigned)d >= (unsigned)N) d = 0;
    atomicAdd(&counts[d], 1);
  }
}

// ------------------------------------------------------------------
// exclusive scan with +1 per row (self loop). counts becomes cursor.
// ------------------------------------------------------------------
__global__ __launch_bounds__(64) void scan_kernel(
    int* __restrict__ counts, int* __restrict__ row_ptr, int N) {
  int lane = threadIdx.x;
  int chunk = (N + 63) / 64;
  int lo = lane * chunk;
  int hi = lo + chunk; if (hi > N) hi = N; if (lo > N) lo = N;
  int s = 0;
  for (int i = lo; i < hi; ++i) s += counts[i] + 1;
  int incl = s;
#pragma unroll
  for (int d = 1; d < 64; d <<= 1) {
    int t = __shfl_up(incl, d);
    if (lane >= d) incl += t;
  }
  int run = incl - s;
  for (int i = lo; i < hi; ++i) {
    int c = counts[i] + 1;
    row_ptr[i] = run;
    counts[i] = run;
    run += c;
  }
  if (lane == 63) row_ptr[N] = run;
}

// ------------------------------------------------------------------
// scatter edges (+self loops, etype=64) into CSR: packed = src | et<<16
// ------------------------------------------------------------------
__global__ __launch_bounds__(256) void scatter_kernel(
    const int* __restrict__ src, const int* __restrict__ dst,
    const int* __restrict__ et, int* __restrict__ cursor,
    int* __restrict__ packed, int E0, int N) {
  int E = E0 + N;
  int i = blockIdx.x * blockDim.x + threadIdx.x;
  if (i < E0) {
    int d = dst[i];
    if ((unsigned)d >= (unsigned)N) d = 0;
    int p = atomicAdd(&cursor[d], 1);
    if ((unsigned)p >= (unsigned)E) p = 0;
    int t = et[i] & 63;
    packed[p] = (src[i] & 0xFFFF) | (t << 16);
  } else if (i < E) {
    int n = i - E0;
    int p = atomicAdd(&cursor[n], 1);
    if ((unsigned)p >= (unsigned)E) p = 0;
    packed[p] = (n & 0xFFFF) | (64 << 16);
  }
}

// ------------------------------------------------------------------
// xh = x @ W via MFMA 16x16x32 bf16. x [N][128] bf16, WT [384][128] bf16.
// Block = 4 waves: 16 rows x 64 cols. Grid (N/16, 6).
// Output permuted: xh half-index = node*384 + pair*6 + head*2 + sub,
// where col f = head*128 + pair*2 + sub.
// ------------------------------------------------------------------
__global__ __launch_bounds__(256) void gemm_xh_mfma(
    const bf16* __restrict__ x, const bf16* __restrict__ WT,
    bf16* __restrict__ xh, int N) {
  int wave = threadIdx.x >> 6, lane = threadIdx.x & 63;
  int row_base = blockIdx.x * 16;
  int col_base = blockIdx.y * 64 + wave * 16;
  int quad = lane >> 4, r16 = lane & 15;
  int row = row_base + r16; if (row >= N) row = N - 1;
  int col = col_base + r16;
  f32x4 acc = {0.f, 0.f, 0.f, 0.f};
  const short8* ap = (const short8*)(x + (size_t)row * 128 + quad * 8);
  const short8* bp = (const short8*)(WT + (size_t)col * 128 + quad * 8);
#pragma unroll
  for (int kk = 0; kk < 4; ++kk) {
    short8 a = ap[kk * 4];
    short8 b = bp[kk * 4];
    acc = __builtin_amdgcn_mfma_f32_16x16x32_bf16(a, b, acc, 0, 0, 0);
  }
  int h = col >> 7, fi = col & 127, pair = fi >> 1, sub = fi & 1;
  size_t base = (size_t)pair * 6 + h * 2 + sub;
#pragma unroll
  for (int r = 0; r < 4; ++r) {
    int node = row_base + quad * 4 + r;
    if (node < N) xh[(size_t)node * 384 + base] = __float2bfloat16(acc[r]);
  }
}

// ------------------------------------------------------------------
// s_i[n,h] = dot(xh[n,h], att[h,0:128]); s_j: att[h,128:256].
// Reads permuted xh (3 dwords per lane). One wave per node.
// ------------------------------------------------------------------
__global__ __launch_bounds__(256) void s_kernel(
    const int* __restrict__ xh_i, const float2* __restrict__ attf2,
    float* __restrict__ s_i, float* __restrict__ s_j, int N) {
  int wid = threadIdx.x >> 6, lane = threadIdx.x & 63;
  int n = blockIdx.x * 4 + wid;
  if (n >= N) return;
  const int* p = xh_i + (size_t)n * 192 + lane * 3;
  int w0 = p[0], w1 = p[1], w2 = p[2];
  float2 v[3] = {i2f2(w0), i2f2(w1), i2f2(w2)};
#pragma unroll
  for (int h = 0; h < 3; ++h) {
    float2 ai = attf2[h * 144 + lane];
    float2 aj = attf2[h * 144 + 64 + lane];
    float pi = v[h].x * ai.x + v[h].y * ai.y;
    float pj = v[h].x * aj.x + v[h].y * aj.y;
#pragma unroll
    for (int d = 32; d > 0; d >>= 1) {
      pi += __shfl_xor(pi, d);
      pj += __shfl_xor(pj, d);
    }
    if (lane == 0) {
      s_i[n * 3 + h] = pi;
      s_j[n * 3 + h] = pj;
    }
  }
}

// ------------------------------------------------------------------
// per-dst softmax + weighted aggregation -> bf16 aggr [N][160].
// Phase A: one edge per lane, exp weights in regs (clamp, no max pass).
// Phase B: serial aggregation, params via shfl, one 3-dword gather/edge.
// ------------------------------------------------------------------
__global__ __launch_bounds__(256) void edge_aggr_kernel(
    const int* __restrict__ xh_i, const float* __restrict__ s_i,
    const float* __restrict__ s_j, const float* __restrict__ s_et,
    const float2* __restrict__ eef2, const int* __restrict__ row_ptr,
    const int* __restrict__ packed, unsigned* __restrict__ aggr_u,
    int N, int E) {
  int wid = threadIdx.x >> 6, lane = threadIdx.x & 63;
  int n = blockIdx.x * 4 + wid;
  if (n >= N) return;
  int start = row_ptr[n], end = row_ptr[n + 1];
  if (start < 0) start = 0;
  if (start > E) start = E;
  if (end < start) end = start;
  if (end > E) end = E;
  int deg = end - start;
  float si0 = s_i[n * 3 + 0], si1 = s_i[n * 3 + 1], si2 = s_i[n * 3 + 2];

  // ---- phase A ----
  float p0r[2], p1r[2], p2r[2];
  int pkr[2];
  float dp0 = 0.0f, dp1 = 0.0f, dp2 = 0.0f;
#pragma unroll
  for (int it = 0; it < 2; ++it) {
    p0r[it] = p1r[it] = p2r[it] = 0.0f; pkr[it] = 0;
    int slot = it * 64 + lane;
    if (slot < deg) {
      int p = packed[start + slot];
      int s = p & 0xFFFF; if (s >= N) s = N - 1;
      int t = (p >> 16) & 127; if (t > 64) t = 64;
      float a0 = si0 + s_j[s * 3 + 0] + s_et[t * 3 + 0];
      float a1 = si1 + s_j[s * 3 + 1] + s_et[t * 3 + 1];
      float a2 = si2 + s_j[s * 3 + 2] + s_et[t * 3 + 2];
      a0 = a0 > 0.0f ? a0 : 0.2f * a0;
      a1 = a1 > 0.0f ? a1 : 0.2f * a1;
      a2 = a2 > 0.0f ? a2 : 0.2f * a2;
      a0 = fminf(fmaxf(a0, -60.0f), 60.0f);
      a1 = fminf(fmaxf(a1, -60.0f), 60.0f);
      a2 = fminf(fmaxf(a2, -60.0f), 60.0f);
      float p0 = __expf(a0), p1 = __expf(a1), p2 = __expf(a2);
      dp0 += p0; dp1 += p1; dp2 += p2;
      p0r[it] = p0; p1r[it] = p1; p2r[it] = p2;
      pkr[it] = s | (t << 16);
    }
  }
#pragma unroll
  for (int d = 32; d > 0; d >>= 1) {
    dp0 += __shfl_xor(dp0, d);
    dp1 += __shfl_xor(dp1, d);
    dp2 += __shfl_xor(dp2, d);
  }
  float d0 = dp0, d1 = dp1, d2 = dp2;

  // ---- phase B ----
  float2 ax0 = make_float2(0.f, 0.f), ax1 = ax0, ax2 = ax0;
  float2 ae0 = ax0, ae1 = ax0, ae2 = ax0;
  int mm = deg < 128 ? deg : 128;

  auto agg_range = [&](int pk_s, float q0_s, float q1_s, float q2_s, int cnt) {
    int j = 0;
    for (; j + 2 <= cnt; j += 2) {
      int pkA = __shfl(pk_s, j), pkB = __shfl(pk_s, j + 1);
      float qA0 = __shfl(q0_s, j), qB0 = __shfl(q0_s, j + 1);
      float qA1 = __shfl(q1_s, j), qB1 = __shfl(q1_s, j + 1);
      float qA2 = __shfl(q2_s, j), qB2 = __shfl(q2_s, j + 1);
      int sA = pkA & 0xFFFF, tA = pkA >> 16;
      int sB = pkB & 0xFFFF, tB = pkB >> 16;
      const int* xpA = xh_i + (size_t)sA * 192 + lane * 3;
      const int* xpB = xh_i + (size_t)sB * 192 + lane * 3;
      int wA0 = xpA[0], wA1 = xpA[1], wA2 = xpA[2];
      int wB0 = xpB[0], wB1 = xpB[1], wB2 = xpB[2];
      float2 vA0 = i2f2(wA0), vA1 = i2f2(wA1), vA2 = i2f2(wA2);
      float2 vB0 = i2f2(wB0), vB1 = i2f2(wB1), vB2 = i2f2(wB2);
      ax0.x = fmaf(qA0, vA0.x, ax0.x); ax0.y = fmaf(qA0, vA0.y, ax0.y);
      ax1.x = fmaf(qA1, vA1.x, ax1.x); ax1.y = fmaf(qA1, vA1.y, ax1.y);
      ax2.x = fmaf(qA2, vA2.x, ax2.x); ax2.y = fmaf(qA2, vA2.y, ax2.y);
      ax0.x = fmaf(qB0, vB0.x, ax0.x); ax0.y = fmaf(qB0, vB0.y, ax0.y);
      ax1.x = fmaf(qB1, vB1.x, ax1.x); ax1.y = fmaf(qB1, vB1.y, ax1.y);
      ax2.x = fmaf(qB2, vB2.x, ax2.x); ax2.y = fmaf(qB2, vB2.y, ax2.y);
      if (lane < 16) {
        if (tA != 64) {
          float2 ev = eef2[tA * 16 + lane];
          ae0.x = fmaf(qA0, ev.x, ae0.x); ae0.y = fmaf(qA0, ev.y, ae0.y);
          ae1.x = fmaf(qA1, ev.x, ae1.x); ae1.y = fmaf(qA1, ev.y, ae1.y);
          ae2.x = fmaf(qA2, ev.x, ae2.x); ae2.y = fmaf(qA2, ev.y, ae2.y);
        }
        if (tB != 64) {
          float2 ev = eef2[tB * 16 + lane];
          ae0.x = fmaf(qB0, ev.x, ae0.x); ae0.y = fmaf(qB0, ev.y, ae0.y);
          ae1.x = fmaf(qB1, ev.x, ae1.x); ae1.y = fmaf(qB1, ev.y, ae1.y);
          ae2.x = fmaf(qB2, ev.x, ae2.x); ae2.y = fmaf(qB2, ev.y, ae2.y);
        }
      }
    }
    if (j < cnt) {
      int pkA = __shfl(pk_s, j);
      float qA0 = __shfl(q0_s, j), qA1 = __shfl(q1_s, j), qA2 = __shfl(q2_s, j);
      int sA = pkA & 0xFFFF, tA = pkA >> 16;
      const int* xpA = xh_i + (size_t)sA * 192 + lane * 3;
      int wA0 = xpA[0], wA1 = xpA[1], wA2 = xpA[2];
      float2 vA0 = i2f2(wA0), vA1 = i2f2(wA1), vA2 = i2f2(wA2);
      ax0.x = fmaf(qA0, vA0.x, ax0.x); ax0.y = fmaf(qA0, vA0.y, ax0.y);
      ax1.x = fmaf(qA1, vA1.x, ax1.x); ax1.y = fmaf(qA1, vA1.y, ax1.y);
      ax2.x = fmaf(qA2, vA2.x, ax2.x); ax2.y = fmaf(qA2, vA2.y, ax2.y);
      if (lane < 16 && tA != 64) {
        float2 ev = eef2[tA * 16 + lane];
        ae0.x = fmaf(qA0, ev.x, ae0.x); ae0.y = fmaf(qA0, ev.y, ae0.y);
        ae1.x = fmaf(qA1, ev.x, ae1.x); ae1.y = fmaf(qA1, ev.y, ae1.y);
        ae2.x = fmaf(qA2, ev.x, ae2.x); ae2.y = fmaf(qA2, ev.y, ae2.y);
      }
    }
  };
  agg_range(pkr[0], p0r[0], p1r[0], p2r[0], mm < 64 ? mm : 64);
  if (mm > 64) agg_range(pkr[1], p0r[1], p1r[1], p2r[1], mm - 64);

  // rare fallback: degree > 128
  for (int e = start + 128; e < end; ++e) {
    int p = packed[e];
    int s = p & 0xFFFF; if (s >= N) s = N - 1;
    int t = (p >> 16) & 127; if (t > 64) t = 64;
    float a0 = si0 + s_j[s * 3 + 0] + s_et[t * 3 + 0];
    float a1 = si1 + s_j[s * 3 + 1] + s_et[t * 3 + 1];
    float a2 = si2 + s_j[s * 3 + 2] + s_et[t * 3 + 2];
    a0 = a0 > 0.0f ? a0 : 0.2f * a0;
    a1 = a1 > 0.0f ? a1 : 0.2f * a1;
    a2 = a2 > 0.0f ? a2 : 0.2f * a2;
    a0 = fminf(fmaxf(a0, -60.0f), 60.0f);
    a1 = fminf(fmaxf(a1, -60.0f), 60.0f);
    a2 = fminf(fmaxf(a2, -60.0f), 60.0f);
    float p0 = __expf(a0), p1 = __expf(a1), p2 = __expf(a2);
    d0 += p0; d1 += p1; d2 += p2;
    const int* xp = xh_i + (size_t)s * 192 + lane * 3;
    float2 v0 = i2f2(xp[0]), v1 = i2f2(xp[1]), v2 = i2f2(xp[2]);
    ax0.x = fmaf(p0, v0.x, ax0.x); ax0.y = fmaf(p0, v0.y, ax0.y);
    ax1.x = fmaf(p1, v1.x, ax1.x); ax1.y = fmaf(p1, v1.y, ax1.y);
    ax2.x = fmaf(p2, v2.x, ax2.x); ax2.y = fmaf(p2, v2.y, ax2.y);
    if (t != 64 && lane < 16) {
      float2 ev = eef2[t * 16 + lane];
      ae0.x = fmaf(p0, ev.x, ae0.x); ae0.y = fmaf(p0, ev.y, ae0.y);
      ae1.x = fmaf(p1, ev.x, ae1.x); ae1.y = fmaf(p1, ev.y, ae1.y);
      ae2.x = fmaf(p2, ev.x, ae2.x); ae2.y = fmaf(p2, ev.y, ae2.y);
    }
  }

  const float third = 1.0f / 3.0f;
  float i0 = third / fmaxf(d0, 1e-30f);
  float i1 = third / fmaxf(d1, 1e-30f);
  float i2 = third / fmaxf(d2, 1e-30f);
  aggr_u[(size_t)n * 80 + lane] =
      pk2(ax0.x * i0 + ax1.x * i1 + ax2.x * i2,
          ax0.y * i0 + ax1.y * i1 + ax2.y * i2);
  if (lane < 16)
    aggr_u[(size_t)n * 80 + 64 + lane] =
        pk2(ae0.x * i0 + ae1.x * i1 + ae2.x * i2,
            ae0.y * i0 + ae1.y * i1 + ae2.y * i2);
}

// ------------------------------------------------------------------
// out = aggr @ euw + bias via MFMA (K=160). aggr [N][160] bf16,
// euwT [128][160] bf16. Optional ELU. Intermediate -> bf16 x (d_out);
// final -> d_out in detected dtype. Grid (N/16, 2), 4 waves/block.
// ------------------------------------------------------------------
__global__ __launch_bounds__(256) void gemm_out_mfma(
    const bf16* __restrict__ aggr, const bf16* __restrict__ euwT,
    const float* __restrict__ biasf, bf16* __restrict__ xb,
    void* __restrict__ dout, const int* __restrict__ flag,
    int N, int do_elu, int do_final) {
  int wave = threadIdx.x >> 6, lane = threadIdx.x & 63;
  int row_base = blockIdx.x * 16;
  int col_base = blockIdx.y * 64 + wave * 16;
  int quad = lane >> 4, r16 = lane & 15;
  int row = row_base + r16; if (row >= N) row = N - 1;
  int col = col_base + r16;
  f32x4 acc = {0.f, 0.f, 0.f, 0.f};
  const short8* ap = (const short8*)(aggr + (size_t)row * 160 + quad * 8);
  const short8* bp = (const short8*)(euwT + (size_t)col * 160 + quad * 8);
#pragma unroll
  for (int kk = 0; kk < 5; ++kk) {
    short8 a = ap[kk * 4];
    short8 b = bp[kk * 4];
    acc = __builtin_amdgcn_mfma_f32_16x16x32_bf16(a, b, acc, 0, 0, 0);
  }
  float bv = biasf[col];
  int f = *flag;
#pragma unroll
  for (int r = 0; r < 4; ++r) {
    int node = row_base + quad * 4 + r;
    if (node < N) {
      float v = acc[r] + bv;
      if (do_elu) v = v > 0.0f ? v : expm1f(v);
      if (do_final) {
        if (f) ((float*)dout)[(size_t)node * 128 + col] = v;
        else   ((bf16*)dout)[(size_t)node * 128 + col] = __float2bfloat16(v);
      } else {
        xb[(size_t)node * 128 + col] = __float2bfloat16(v);
      }
    }
  }
}

// ------------------------------------------------------------------
extern "C" void kernel_launch(void* const* d_in, const int* in_sizes, int n_in,
                              void* d_out, int out_size, void* d_ws, size_t ws_size,
                              hipStream_t stream) {
  const int* x_idx = (const int*)d_in[0];
  const int* edge_index = (const int*)d_in[1];
  const int* edge_attr_idx = (const int*)d_in[2];

  int N = in_sizes[0];
  int E0 = in_sizes[1] / 2;
  int E = E0 + N;
  const int* src = edge_index;
  const int* dst = edge_index + E0;

  // ---- workspace carve (~12.2 MB) ----
  size_t off = 0;
  char* base = (char*)d_ws;
  auto carve = [&](size_t bytes) -> void* {
    void* p = base + off;
    off += (bytes + 255) & ~(size_t)255;
    return p;
  };
  int* flag     = (int*)carve(256);
  int* counts   = (int*)carve((size_t)N * 4);    // becomes cursor after scan
  int* row_ptr  = (int*)carve((size_t)(N + 1) * 4);
  int* packed   = (int*)carve((size_t)E * 4);
  float* s_i    = (float*)carve((size_t)N * 3 * 4);
  float* s_j    = (float*)carve((size_t)N * 3 * 4);
  float* s_et   = (float*)carve(2 * 65 * 3 * 4);
  float* eef    = (float*)carve(2048 * 4);
  float* att1f  = (float*)carve(864 * 4);
  float* att2f  = (float*)carve(864 * 4);
  float* b1f    = (float*)carve(128 * 4);
  float* b2f_   = (float*)carve(128 * 4);
  bf16* WT1     = (bf16*)carve(49152 * 2);
  bf16* WT2     = (bf16*)carve(49152 * 2);
  bf16* euT1    = (bf16*)carve(20480 * 2);
  bf16* euT2    = (bf16*)carve(20480 * 2);
  bf16* xh      = (bf16*)carve((size_t)N * 384 * 2 + 64);
  bf16* aggr    = (bf16*)carve((size_t)N * 160 * 2);
  bf16* xb      = (bf16*)d_out;  // bf16 x lives in d_out between layers
  (void)n_in; (void)out_size; (void)ws_size;

  // ---- setup: 5 dispatches ----
  detect_set_kernel<<<1, 512, 0, stream>>>(
      (const unsigned short*)d_in[5], 2048, flag, d_in[4], d_in[6], d_in[10], s_et);
  wconv_kernel<<<(143296 + N + 255) / 256, 256, 0, stream>>>(
      d_in[4], d_in[5], d_in[6], d_in[7], d_in[8], d_in[9], d_in[10], d_in[11],
      d_in[12], flag, eef, att1f, att2f, b1f, b2f_, WT1, WT2, euT1, euT2,
      counts, N);
  int nb4 = (N + 3) / 4;
  prep_kernel<<<nb4, 256, 0, stream>>>(x_idx, d_in[3], flag, xb, counts, dst,
                                       E0, N);
  scan_kernel<<<1, 64, 0, stream>>>(counts, row_ptr, N);
  scatter_kernel<<<(E + 255) / 256, 256, 0, stream>>>(src, dst, edge_attr_idx,
                                                      counts, packed, E0, N);

  const bf16* WTs[2] = {WT1, WT2};
  const float* atts[2] = {att1f, att2f};
  const bf16* euTs[2] = {euT1, euT2};
  const float* bs[2] = {b1f, b2f_};

  int nrb = (N + 15) / 16;
  for (int round = 0; round < 2; ++round) {
    for (int l = 0; l < 2; ++l) {
      int do_elu = (l == 0) ? 1 : 0;
      int do_final = (round == 1 && l == 1) ? 1 : 0;
      gemm_xh_mfma<<<dim3(nrb, 6), 256, 0, stream>>>(xb, WTs[l], xh, N);
      s_kernel<<<nb4, 256, 0, stream>>>((const int*)xh, (const float2*)atts[l],
                                        s_i, s_j, N);
      edge_aggr_kernel<<<nb4, 256, 0, stream>>>(
          (const int*)xh, s_i, s_j, s_et + l * 195, (const float2*)eef,
          row_ptr, packed, (unsigned*)aggr, N, E);
      gemm_out_mfma<<<dim3(nrb, 2), 256, 0, stream>>>(
          aggr, euTs[l], bs[l], xb, d_out, flag, N, do_elu, do_final);
    }
  }
}

// Round 8
// 328.554 us; speedup vs baseline: 1.8363x; 1.1626x over previous
//
#include <hip/hip_runtime.h>
#include <hip/hip_bf16.h>

typedef __hip_bfloat16 bf16;
typedef __attribute__((ext_vector_type(8))) short short8;
typedef __attribute__((ext_vector_type(4))) float f32x4;

__device__ __forceinline__ float b2f(bf16 v) { return __bfloat162float(v); }
// int (2 packed bf16) -> two floats. x = low half, y = high half.
__device__ __forceinline__ float2 i2f2(int w) {
  float lo = __uint_as_float(((unsigned)w) << 16);
  float hi = __uint_as_float(((unsigned)w) & 0xFFFF0000u);
  return make_float2(lo, hi);
}
// float -> bf16 bits (RNE; inputs finite)
__device__ __forceinline__ unsigned f2bfb(float f) {
  unsigned u = __float_as_uint(f);
  unsigned r = 0x7FFFu + ((u >> 16) & 1u);
  return (u + r) >> 16;
}
// pack two floats into one dword of 2 bf16 (a = low, b = high)
__device__ __forceinline__ unsigned pk2(float a, float b) {
  return f2bfb(a) | (f2bfb(b) << 16);
}
__device__ __forceinline__ float ldv(const void* p, int i, int f) {
  return f ? ((const float*)p)[i] : b2f(((const bf16*)p)[i]);
}

// ------------------------------------------------------------------
// 1 block: dtype detect (flag: 0=bf16, 1=fp32) + s_et table.
// ------------------------------------------------------------------
__global__ __launch_bounds__(512) void detect_set_kernel(
    const unsigned short* __restrict__ probe, int nhalves, int* __restrict__ flag,
    const void* __restrict__ eeraw, const void* __restrict__ att1raw,
    const void* __restrict__ att2raw, float* __restrict__ s_et) {
  __shared__ int cnt;
  __shared__ int fl;
  if (threadIdx.x == 0) cnt = 0;
  __syncthreads();
  int local = 0;
  for (int i = threadIdx.x; i < nhalves; i += 512) {
    int e = (probe[i] >> 7) & 0xFF;
    if (e >= 160) local++;
  }
  if (local) atomicAdd(&cnt, local);
  __syncthreads();
  if (threadIdx.x == 0) { fl = (cnt > 16) ? 1 : 0; *flag = fl; }
  __syncthreads();
  int f = fl;
  int id = threadIdx.x;
  if (id < 2 * 65 * 3) {
    int l = id / (65 * 3);
    int r = id % (65 * 3);
    int t = r / 3, h = r % 3;
    const void* att = l ? att2raw : att1raw;
    float s = 0.0f;
    if (t < 64) {
      for (int d = 0; d < 32; ++d)
        s += ldv(eeraw, t * 32 + d, f) * ldv(att, h * 288 + 256 + d, f);
    }
    s_et[id] = s;
  }
}

// ------------------------------------------------------------------
// weight materialization: fp32 small tensors + bf16 transposed GEMM
// operands (WT [384][128], euwT [128][160]); zero counts.
// ------------------------------------------------------------------
__global__ __launch_bounds__(256) void wconv_kernel(
    const void* __restrict__ ee, const void* __restrict__ w1,
    const void* __restrict__ a1, const void* __restrict__ eu1,
    const void* __restrict__ b1, const void* __restrict__ w2,
    const void* __restrict__ a2, const void* __restrict__ eu2,
    const void* __restrict__ b2, const int* __restrict__ flag,
    float* __restrict__ eef, float* __restrict__ att1f, float* __restrict__ att2f,
    float* __restrict__ b1f, float* __restrict__ b2f,
    bf16* __restrict__ WT1, bf16* __restrict__ WT2,
    bf16* __restrict__ euT1, bf16* __restrict__ euT2,
    int* __restrict__ counts, int N) {
  int i = blockIdx.x * 256 + threadIdx.x;
  int f = *flag;
  if (i < 2048) {
    eef[i] = ldv(ee, i, f);
  } else if (i < 2912) {
    att1f[i - 2048] = ldv(a1, i - 2048, f);
  } else if (i < 3776) {
    att2f[i - 2912] = ldv(a2, i - 2912, f);
  } else if (i < 3904) {
    b1f[i - 3776] = ldv(b1, i - 3776, f);
  } else if (i < 4032) {
    b2f[i - 3904] = ldv(b2, i - 3904, f);
  } else if (i < 53184) {
    int j = i - 4032; int c = j >> 7, k = j & 127;
    WT1[j] = __float2bfloat16(ldv(w1, k * 384 + c, f));
  } else if (i < 102336) {
    int j = i - 53184; int c = j >> 7, k = j & 127;
    WT2[j] = __float2bfloat16(ldv(w2, k * 384 + c, f));
  } else if (i < 122816) {
    int j = i - 102336; int c = j / 160, k = j % 160;
    euT1[j] = __float2bfloat16(ldv(eu1, k * 128 + c, f));
  } else if (i < 143296) {
    int j = i - 122816; int c = j / 160, k = j % 160;
    euT2[j] = __float2bfloat16(ldv(eu2, k * 128 + c, f));
  } else if (i < 143296 + N) {
    counts[i - 143296] = 0;
  }
}

// ------------------------------------------------------------------
// prep: x0 = maxnorm(node_emb[x_idx]) -> bf16 x (in d_out);
// + edge counting (grid-stride). counts pre-zeroed by wconv.
// ------------------------------------------------------------------
__global__ __launch_bounds__(256) void prep_kernel(
    const int* __restrict__ x_idx, const void* __restrict__ node_emb,
    const int* __restrict__ flag, bf16* __restrict__ xb,
    int* __restrict__ counts, const int* __restrict__ dst, int E0, int N) {
  int wid = threadIdx.x >> 6, lane = threadIdx.x & 63;
  int n = blockIdx.x * 4 + wid;
  if (n < N) {
    int idx = x_idx[n];
    if ((unsigned)idx >= (unsigned)N) idx = 0;
    float v0, v1;
    if (*flag) {
      const float* er = (const float*)node_emb + (size_t)idx * 128;
      v0 = er[lane]; v1 = er[lane + 64];
    } else {
      const bf16* er = (const bf16*)node_emb + (size_t)idx * 128;
      v0 = b2f(er[lane]); v1 = b2f(er[lane + 64]);
    }
    float ss = v0 * v0 + v1 * v1;
#pragma unroll
    for (int d = 32; d > 0; d >>= 1) ss += __shfl_xor(ss, d);
    float norm = sqrtf(ss);
    float scale = norm > 1.0f ? 1.0f / norm : 1.0f;
    xb[(size_t)n * 128 + lane] = __float2bfloat16(v0 * scale);
    xb[(size_t)n * 128 + 64 + lane] = __float2bfloat16(v1 * scale);
  }
  int gid = blockIdx.x * 256 + threadIdx.x;
  int stride = gridDim.x * 256;
  for (int i = gid; i < E0; i += stride) {
    int d = dst[i];
    if ((unsigned)d >= (unsigned)N) d = 0;
    atomicAdd(&counts[d], 1);
  }
}

// ------------------------------------------------------------------
// parallel exclusive scan with +1 per row (self loop), one block of
// 1024 threads (16 waves). counts becomes cursor in place.
// ------------------------------------------------------------------
__global__ __launch_bounds__(1024) void scan_kernel(
    int* __restrict__ counts, int* __restrict__ row_ptr, int N) {
  __shared__ int wsum[16];
  int t = threadIdx.x;
  int chunk = (N + 1023) >> 10;
  int lo = t * chunk;
  int hi = lo + chunk;
  if (lo > N) lo = N;
  if (hi > N) hi = N;
  int s = 0;
  for (int i = lo; i < hi; ++i) s += counts[i] + 1;
  int lane = t & 63, wv = t >> 6;
  int incl = s;
#pragma unroll
  for (int d = 1; d < 64; d <<= 1) {
    int u = __shfl_up(incl, d);
    if (lane >= d) incl += u;
  }
  if (lane == 63) wsum[wv] = incl;
  __syncthreads();
  if (t == 0) {
    int run = 0;
#pragma unroll
    for (int w = 0; w < 16; ++w) { int c = wsum[w]; wsum[w] = run; run += c; }
  }
  __syncthreads();
  int run = incl - s + wsum[wv];  // exclusive prefix for this thread
  for (int i = lo; i < hi; ++i) {
    int c = counts[i] + 1;
    row_ptr[i] = run;
    counts[i] = run;
    run += c;
  }
  if (t == 1023) row_ptr[N] = run;
}

// ------------------------------------------------------------------
// scatter edges (+self loops, etype=64) into CSR: packed = src | et<<16
// ------------------------------------------------------------------
__global__ __launch_bounds__(256) void scatter_kernel(
    const int* __restrict__ src, const int* __restrict__ dst,
    const int* __restrict__ et, int* __restrict__ cursor,
    int* __restrict__ packed, int E0, int N) {
  int E = E0 + N;
  int i = blockIdx.x * blockDim.x + threadIdx.x;
  if (i < E0) {
    int d = dst[i];
    if ((unsigned)d >= (unsigned)N) d = 0;
    int p = atomicAdd(&cursor[d], 1);
    if ((unsigned)p >= (unsigned)E) p = 0;
    int t = et[i] & 63;
    packed[p] = (src[i] & 0xFFFF) | (t << 16);
  } else if (i < E) {
    int n = i - E0;
    int p = atomicAdd(&cursor[n], 1);
    if ((unsigned)p >= (unsigned)E) p = 0;
    packed[p] = (n & 0xFFFF) | (64 << 16);
  }
}

// ------------------------------------------------------------------
// xh = x @ W via MFMA + fused s_i/s_j. Block = 6 waves (384 thr),
// computes 16 rows x 384 cols. Wave w covers cols [w*64, w*64+64)
// (entirely within head w/2). Grid: N/16.
// xh stored permuted: half-index = node*384 + pair*6 + head*2 + sub,
// col = head*128 + pair*2 + sub.
// s_i[n,h] = dot(xh_f32[n,h,:], att[h,0:128]); s_j: att[h,128:256].
// ------------------------------------------------------------------
__global__ __launch_bounds__(384) void gemm_xh_s_mfma(
    const bf16* __restrict__ x, const bf16* __restrict__ WT,
    const float* __restrict__ attf, bf16* __restrict__ xh,
    float* __restrict__ s_i, float* __restrict__ s_j, int N) {
  __shared__ float lds_i[6][16];
  __shared__ float lds_j[6][16];
  int wave = threadIdx.x >> 6, lane = threadIdx.x & 63;
  int row_base = blockIdx.x * 16;
  int quad = lane >> 4, r16 = lane & 15;
  int row = row_base + r16; if (row >= N) row = N - 1;
  const short8* ap = (const short8*)(x + (size_t)row * 128 + quad * 8);
  short8 a[4];
#pragma unroll
  for (int kk = 0; kk < 4; ++kk) a[kk] = ap[kk * 4];

  float pi_r[4] = {0.f, 0.f, 0.f, 0.f};
  float pj_r[4] = {0.f, 0.f, 0.f, 0.f};
#pragma unroll
  for (int j = 0; j < 4; ++j) {
    int col = wave * 64 + j * 16 + r16;
    const short8* bp = (const short8*)(WT + (size_t)col * 128 + quad * 8);
    f32x4 acc = {0.f, 0.f, 0.f, 0.f};
#pragma unroll
    for (int kk = 0; kk < 4; ++kk)
      acc = __builtin_amdgcn_mfma_f32_16x16x32_bf16(a[kk], bp[kk * 4], acc, 0, 0, 0);
    int h = col >> 7, fi = col & 127, pair = fi >> 1, sub = fi & 1;
    size_t base = (size_t)pair * 6 + h * 2 + sub;
#pragma unroll
    for (int r = 0; r < 4; ++r) {
      int node = row_base + quad * 4 + r;
      if (node < N) xh[(size_t)node * 384 + base] = __float2bfloat16(acc[r]);
    }
    float ai = attf[h * 288 + fi];
    float aj = attf[h * 288 + 128 + fi];
#pragma unroll
    for (int r = 0; r < 4; ++r) {
      pi_r[r] = fmaf(acc[r], ai, pi_r[r]);
      pj_r[r] = fmaf(acc[r], aj, pj_r[r]);
    }
  }
  // reduce over the 16 col-lanes within each quad (rows stay distinct)
#pragma unroll
  for (int d = 1; d < 16; d <<= 1) {
#pragma unroll
    for (int r = 0; r < 4; ++r) {
      pi_r[r] += __shfl_xor(pi_r[r], d);
      pj_r[r] += __shfl_xor(pj_r[r], d);
    }
  }
  if (r16 == 0) {
#pragma unroll
    for (int r = 0; r < 4; ++r) {
      lds_i[wave][quad * 4 + r] = pi_r[r];
      lds_j[wave][quad * 4 + r] = pj_r[r];
    }
  }
  __syncthreads();
  int m = threadIdx.x;
  if (m < 48) {
    int h = m / 16, r = m % 16;
    int node = row_base + r;
    if (node < N) s_i[node * 3 + h] = lds_i[2 * h][r] + lds_i[2 * h + 1][r];
  } else if (m < 96) {
    int tt = m - 48;
    int h = tt / 16, r = tt % 16;
    int node = row_base + r;
    if (node < N) s_j[node * 3 + h] = lds_j[2 * h][r] + lds_j[2 * h + 1][r];
  }
}

// ------------------------------------------------------------------
// per-dst softmax + weighted aggregation -> bf16 aggr [N][160].
// Phase A: one edge per lane, exp weights in regs (clamp, no max pass).
// Phase B: serial aggregation, params via shfl, one 3-dword gather/edge.
// ------------------------------------------------------------------
__global__ __launch_bounds__(256) void edge_aggr_kernel(
    const int* __restrict__ xh_i, const float* __restrict__ s_i,
    const float* __restrict__ s_j, const float* __restrict__ s_et,
    const float2* __restrict__ eef2, const int* __restrict__ row_ptr,
    const int* __restrict__ packed, unsigned* __restrict__ aggr_u,
    int N, int E) {
  int wid = threadIdx.x >> 6, lane = threadIdx.x & 63;
  int n = blockIdx.x * 4 + wid;
  if (n >= N) return;
  int start = row_ptr[n], end = row_ptr[n + 1];
  if (start < 0) start = 0;
  if (start > E) start = E;
  if (end < start) end = start;
  if (end > E) end = E;
  int deg = end - start;
  float si0 = s_i[n * 3 + 0], si1 = s_i[n * 3 + 1], si2 = s_i[n * 3 + 2];

  // ---- phase A ----
  float p0r[2], p1r[2], p2r[2];
  int pkr[2];
  float dp0 = 0.0f, dp1 = 0.0f, dp2 = 0.0f;
#pragma unroll
  for (int it = 0; it < 2; ++it) {
    p0r[it] = p1r[it] = p2r[it] = 0.0f; pkr[it] = 0;
    int slot = it * 64 + lane;
    if (slot < deg) {
      int p = packed[start + slot];
      int s = p & 0xFFFF; if (s >= N) s = N - 1;
      int t = (p >> 16) & 127; if (t > 64) t = 64;
      float a0 = si0 + s_j[s * 3 + 0] + s_et[t * 3 + 0];
      float a1 = si1 + s_j[s * 3 + 1] + s_et[t * 3 + 1];
      float a2 = si2 + s_j[s * 3 + 2] + s_et[t * 3 + 2];
      a0 = a0 > 0.0f ? a0 : 0.2f * a0;
      a1 = a1 > 0.0f ? a1 : 0.2f * a1;
      a2 = a2 > 0.0f ? a2 : 0.2f * a2;
      a0 = fminf(fmaxf(a0, -60.0f), 60.0f);
      a1 = fminf(fmaxf(a1, -60.0f), 60.0f);
      a2 = fminf(fmaxf(a2, -60.0f), 60.0f);
      float p0 = __expf(a0), p1 = __expf(a1), p2 = __expf(a2);
      dp0 += p0; dp1 += p1; dp2 += p2;
      p0r[it] = p0; p1r[it] = p1; p2r[it] = p2;
      pkr[it] = s | (t << 16);
    }
  }
#pragma unroll
  for (int d = 32; d > 0; d >>= 1) {
    dp0 += __shfl_xor(dp0, d);
    dp1 += __shfl_xor(dp1, d);
    dp2 += __shfl_xor(dp2, d);
  }
  float d0 = dp0, d1 = dp1, d2 = dp2;

  // ---- phase B ----
  float2 ax0 = make_float2(0.f, 0.f), ax1 = ax0, ax2 = ax0;
  float2 ae0 = ax0, ae1 = ax0, ae2 = ax0;
  int mm = deg < 128 ? deg : 128;

  auto agg_range = [&](int pk_s, float q0_s, float q1_s, float q2_s, int cnt) {
    int j = 0;
    for (; j + 2 <= cnt; j += 2) {
      int pkA = __shfl(pk_s, j), pkB = __shfl(pk_s, j + 1);
      float qA0 = __shfl(q0_s, j), qB0 = __shfl(q0_s, j + 1);
      float qA1 = __shfl(q1_s, j), qB1 = __shfl(q1_s, j + 1);
      float qA2 = __shfl(q2_s, j), qB2 = __shfl(q2_s, j + 1);
      int sA = pkA & 0xFFFF, tA = pkA >> 16;
      int sB = pkB & 0xFFFF, tB = pkB >> 16;
      const int* xpA = xh_i + (size_t)sA * 192 + lane * 3;
      const int* xpB = xh_i + (size_t)sB * 192 + lane * 3;
      int wA0 = xpA[0], wA1 = xpA[1], wA2 = xpA[2];
      int wB0 = xpB[0], wB1 = xpB[1], wB2 = xpB[2];
      float2 vA0 = i2f2(wA0), vA1 = i2f2(wA1), vA2 = i2f2(wA2);
      float2 vB0 = i2f2(wB0), vB1 = i2f2(wB1), vB2 = i2f2(wB2);
      ax0.x = fmaf(qA0, vA0.x, ax0.x); ax0.y = fmaf(qA0, vA0.y, ax0.y);
      ax1.x = fmaf(qA1, vA1.x, ax1.x); ax1.y = fmaf(qA1, vA1.y, ax1.y);
      ax2.x = fmaf(qA2, vA2.x, ax2.x); ax2.y = fmaf(qA2, vA2.y, ax2.y);
      ax0.x = fmaf(qB0, vB0.x, ax0.x); ax0.y = fmaf(qB0, vB0.y, ax0.y);
      ax1.x = fmaf(qB1, vB1.x, ax1.x); ax1.y = fmaf(qB1, vB1.y, ax1.y);
      ax2.x = fmaf(qB2, vB2.x, ax2.x); ax2.y = fmaf(qB2, vB2.y, ax2.y);
      if (lane < 16) {
        if (tA != 64) {
          float2 ev = eef2[tA * 16 + lane];
          ae0.x = fmaf(qA0, ev.x, ae0.x); ae0.y = fmaf(qA0, ev.y, ae0.y);
          ae1.x = fmaf(qA1, ev.x, ae1.x); ae1.y = fmaf(qA1, ev.y, ae1.y);
          ae2.x = fmaf(qA2, ev.x, ae2.x); ae2.y = fmaf(qA2, ev.y, ae2.y);
        }
        if (tB != 64) {
          float2 ev = eef2[tB * 16 + lane];
          ae0.x = fmaf(qB0, ev.x, ae0.x); ae0.y = fmaf(qB0, ev.y, ae0.y);
          ae1.x = fmaf(qB1, ev.x, ae1.x); ae1.y = fmaf(qB1, ev.y, ae1.y);
          ae2.x = fmaf(qB2, ev.x, ae2.x); ae2.y = fmaf(qB2, ev.y, ae2.y);
        }
      }
    }
    if (j < cnt) {
      int pkA = __shfl(pk_s, j);
      float qA0 = __shfl(q0_s, j), qA1 = __shfl(q1_s, j), qA2 = __shfl(q2_s, j);
      int sA = pkA & 0xFFFF, tA = pkA >> 16;
      const int* xpA = xh_i + (size_t)sA * 192 + lane * 3;
      int wA0 = xpA[0], wA1 = xpA[1], wA2 = xpA[2];
      float2 vA0 = i2f2(wA0), vA1 = i2f2(wA1), vA2 = i2f2(wA2);
      ax0.x = fmaf(qA0, vA0.x, ax0.x); ax0.y = fmaf(qA0, vA0.y, ax0.y);
      ax1.x = fmaf(qA1, vA1.x, ax1.x); ax1.y = fmaf(qA1, vA1.y, ax1.y);
      ax2.x = fmaf(qA2, vA2.x, ax2.x); ax2.y = fmaf(qA2, vA2.y, ax2.y);
      if (lane < 16 && tA != 64) {
        float2 ev = eef2[tA * 16 + lane];
        ae0.x = fmaf(qA0, ev.x, ae0.x); ae0.y = fmaf(qA0, ev.y, ae0.y);
        ae1.x = fmaf(qA1, ev.x, ae1.x); ae1.y = fmaf(qA1, ev.y, ae1.y);
        ae2.x = fmaf(qA2, ev.x, ae2.x); ae2.y = fmaf(qA2, ev.y, ae2.y);
      }
    }
  };
  agg_range(pkr[0], p0r[0], p1r[0], p2r[0], mm < 64 ? mm : 64);
  if (mm > 64) agg_range(pkr[1], p0r[1], p1r[1], p2r[1], mm - 64);

  // rare fallback: degree > 128
  for (int e = start + 128; e < end; ++e) {
    int p = packed[e];
    int s = p & 0xFFFF; if (s >= N) s = N - 1;
    int t = (p >> 16) & 127; if (t > 64) t = 64;
    float a0 = si0 + s_j[s * 3 + 0] + s_et[t * 3 + 0];
    float a1 = si1 + s_j[s * 3 + 1] + s_et[t * 3 + 1];
    float a2 = si2 + s_j[s * 3 + 2] + s_et[t * 3 + 2];
    a0 = a0 > 0.0f ? a0 : 0.2f * a0;
    a1 = a1 > 0.0f ? a1 : 0.2f * a1;
    a2 = a2 > 0.0f ? a2 : 0.2f * a2;
    a0 = fminf(fmaxf(a0, -60.0f), 60.0f);
    a1 = fminf(fmaxf(a1, -60.0f), 60.0f);
    a2 = fminf(fmaxf(a2, -60.0f), 60.0f);
    float p0 = __expf(a0), p1 = __expf(a1), p2 = __expf(a2);
    d0 += p0; d1 += p1; d2 += p2;
    const int* xp = xh_i + (size_t)s * 192 + lane * 3;
    float2 v0 = i2f2(xp[0]), v1 = i2f2(xp[1]), v2 = i2f2(xp[2]);
    ax0.x = fmaf(p0, v0.x, ax0.x); ax0.y = fmaf(p0, v0.y, ax0.y);
    ax1.x = fmaf(p1, v1.x, ax1.x); ax1.y = fmaf(p1, v1.y, ax1.y);
    ax2.x = fmaf(p2, v2.x, ax2.x); ax2.y = fmaf(p2, v2.y, ax2.y);
    if (t != 64 && lane < 16) {
      float2 ev = eef2[t * 16 + lane];
      ae0.x = fmaf(p0, ev.x, ae0.x); ae0.y = fmaf(p0, ev.y, ae0.y);
      ae1.x = fmaf(p1, ev.x, ae1.x); ae1.y = fmaf(p1, ev.y, ae1.y);
      ae2.x = fmaf(p2, ev.x, ae2.x); ae2.y = fmaf(p2, ev.y, ae2.y);
    }
  }

  const float third = 1.0f / 3.0f;
  float i0 = third / fmaxf(d0, 1e-30f);
  float i1 = third / fmaxf(d1, 1e-30f);
  float i2 = third / fmaxf(d2, 1e-30f);
  aggr_u[(size_t)n * 80 + lane] =
      pk2(ax0.x * i0 + ax1.x * i1 + ax2.x * i2,
          ax0.y * i0 + ax1.y * i1 + ax2.y * i2);
  if (lane < 16)
    aggr_u[(size_t)n * 80 + 64 + lane] =
        pk2(ae0.x * i0 + ae1.x * i1 + ae2.x * i2,
            ae0.y * i0 + ae1.y * i1 + ae2.y * i2);
}

// ------------------------------------------------------------------
// out = aggr @ euw + bias via MFMA (K=160). aggr [N][160] bf16,
// euwT [128][160] bf16. Optional ELU. Intermediate -> bf16 x (d_out);
// final -> d_out in detected dtype. Grid (N/16, 2), 4 waves/block.
// ------------------------------------------------------------------
__global__ __launch_bounds__(256) void gemm_out_mfma(
    const bf16* __restrict__ aggr, const bf16* __restrict__ euwT,
    const float* __restrict__ biasf, bf16* __restrict__ xb,
    void* __restrict__ dout, const int* __restrict__ flag,
    int N, int do_elu, int do_final) {
  int wave = threadIdx.x >> 6, lane = threadIdx.x & 63;
  int row_base = blockIdx.x * 16;
  int col_base = blockIdx.y * 64 + wave * 16;
  int quad = lane >> 4, r16 = lane & 15;
  int row = row_base + r16; if (row >= N) row = N - 1;
  int col = col_base + r16;
  f32x4 acc = {0.f, 0.f, 0.f, 0.f};
  const short8* ap = (const short8*)(aggr + (size_t)row * 160 + quad * 8);
  const short8* bp = (const short8*)(euwT + (size_t)col * 160 + quad * 8);
#pragma unroll
  for (int kk = 0; kk < 5; ++kk) {
    short8 a = ap[kk * 4];
    short8 b = bp[kk * 4];
    acc = __builtin_amdgcn_mfma_f32_16x16x32_bf16(a, b, acc, 0, 0, 0);
  }
  float bv = biasf[col];
  int f = *flag;
#pragma unroll
  for (int r = 0; r < 4; ++r) {
    int node = row_base + quad * 4 + r;
    if (node < N) {
      float v = acc[r] + bv;
      if (do_elu) v = v > 0.0f ? v : expm1f(v);
      if (do_final) {
        if (f) ((float*)dout)[(size_t)node * 128 + col] = v;
        else   ((bf16*)dout)[(size_t)node * 128 + col] = __float2bfloat16(v);
      } else {
        xb[(size_t)node * 128 + col] = __float2bfloat16(v);
      }
    }
  }
}

// ------------------------------------------------------------------
extern "C" void kernel_launch(void* const* d_in, const int* in_sizes, int n_in,
                              void* d_out, int out_size, void* d_ws, size_t ws_size,
                              hipStream_t stream) {
  const int* x_idx = (const int*)d_in[0];
  const int* edge_index = (const int*)d_in[1];
  const int* edge_attr_idx = (const int*)d_in[2];

  int N = in_sizes[0];
  int E0 = in_sizes[1] / 2;
  int E = E0 + N;
  const int* src = edge_index;
  const int* dst = edge_index + E0;

  // ---- workspace carve (~12.2 MB) ----
  size_t off = 0;
  char* base = (char*)d_ws;
  auto carve = [&](size_t bytes) -> void* {
    void* p = base + off;
    off += (bytes + 255) & ~(size_t)255;
    return p;
  };
  int* flag     = (int*)carve(256);
  int* counts   = (int*)carve((size_t)N * 4);    // becomes cursor after scan
  int* row_ptr  = (int*)carve((size_t)(N + 1) * 4);
  int* packed   = (int*)carve((size_t)E * 4);
  float* s_i    = (float*)carve((size_t)N * 3 * 4);
  float* s_j    = (float*)carve((size_t)N * 3 * 4);
  float* s_et   = (float*)carve(2 * 65 * 3 * 4);
  float* eef    = (float*)carve(2048 * 4);
  float* att1f  = (float*)carve(864 * 4);
  float* att2f  = (float*)carve(864 * 4);
  float* b1f    = (float*)carve(128 * 4);
  float* b2f_   = (float*)carve(128 * 4);
  bf16* WT1     = (bf16*)carve(49152 * 2);
  bf16* WT2     = (bf16*)carve(49152 * 2);
  bf16* euT1    = (bf16*)carve(20480 * 2);
  bf16* euT2    = (bf16*)carve(20480 * 2);
  bf16* xh      = (bf16*)carve((size_t)N * 384 * 2 + 64);
  bf16* aggr    = (bf16*)carve((size_t)N * 160 * 2);
  bf16* xb      = (bf16*)d_out;  // bf16 x lives in d_out between layers
  (void)n_in; (void)out_size; (void)ws_size;

  // ---- setup: 5 dispatches ----
  detect_set_kernel<<<1, 512, 0, stream>>>(
      (const unsigned short*)d_in[5], 2048, flag, d_in[4], d_in[6], d_in[10], s_et);
  wconv_kernel<<<(143296 + N + 255) / 256, 256, 0, stream>>>(
      d_in[4], d_in[5], d_in[6], d_in[7], d_in[8], d_in[9], d_in[10], d_in[11],
      d_in[12], flag, eef, att1f, att2f, b1f, b2f_, WT1, WT2, euT1, euT2,
      counts, N);
  int nb4 = (N + 3) / 4;
  prep_kernel<<<nb4, 256, 0, stream>>>(x_idx, d_in[3], flag, xb, counts, dst,
                                       E0, N);
  scan_kernel<<<1, 1024, 0, stream>>>(counts, row_ptr, N);
  scatter_kernel<<<(E + 255) / 256, 256, 0, stream>>>(src, dst, edge_attr_idx,
                                                      counts, packed, E0, N);

  const bf16* WTs[2] = {WT1, WT2};
  const float* atts[2] = {att1f, att2f};
  const bf16* euTs[2] = {euT1, euT2};
  const float* bs[2] = {b1f, b2f_};

  int nrb = (N + 15) / 16;
  for (int round = 0; round < 2; ++round) {
    for (int l = 0; l < 2; ++l) {
      int do_elu = (l == 0) ? 1 : 0;
      int do_final = (round == 1 && l == 1) ? 1 : 0;
      gemm_xh_s_mfma<<<nrb, 384, 0, stream>>>(xb, WTs[l], atts[l], xh,
                                              s_i, s_j, N);
      edge_aggr_kernel<<<nb4, 256, 0, stream>>>(
          (const int*)xh, s_i, s_j, s_et + l * 195, (const float2*)eef,
          row_ptr, packed, (unsigned*)aggr, N, E);
      gemm_out_mfma<<<dim3(nrb, 2), 256, 0, stream>>>(
          aggr, euTs[l], bs[l], xb, d_out, flag, N, do_elu, do_final);
    }
  }
}

// Round 9
// 325.456 us; speedup vs baseline: 1.8538x; 1.0095x over previous
//
#include <hip/hip_runtime.h>
#include <hip/hip_bf16.h>

typedef __hip_bfloat16 bf16;
typedef __attribute__((ext_vector_type(8))) short short8;
typedef __attribute__((ext_vector_type(4))) float f32x4;

__device__ __forceinline__ float b2f(bf16 v) { return __bfloat162float(v); }
// int (2 packed bf16) -> two floats. x = low half, y = high half.
__device__ __forceinline__ float2 i2f2(int w) {
  float lo = __uint_as_float(((unsigned)w) << 16);
  float hi = __uint_as_float(((unsigned)w) & 0xFFFF0000u);
  return make_float2(lo, hi);
}
// float -> bf16 bits (RNE; inputs finite)
__device__ __forceinline__ unsigned f2bfb(float f) {
  unsigned u = __float_as_uint(f);
  unsigned r = 0x7FFFu + ((u >> 16) & 1u);
  return (u + r) >> 16;
}
__device__ __forceinline__ unsigned pk2(float a, float b) {
  return f2bfb(a) | (f2bfb(b) << 16);
}
__device__ __forceinline__ float ldv(const void* p, int i, int f) {
  return f ? ((const float*)p)[i] : b2f(((const bf16*)p)[i]);
}

// ------------------------------------------------------------------
// weight materialization + per-block dtype detect (no cross-block dep:
// every block counts big-exponent halves in w1's first 2048 halves).
// Also: fp32 small tensors, bf16 transposed GEMM operands, zero counts,
// block 0 additionally computes s_et and publishes flag.
// ------------------------------------------------------------------
__global__ __launch_bounds__(256) void wconv_kernel(
    const void* __restrict__ ee, const void* __restrict__ w1,
    const void* __restrict__ a1, const void* __restrict__ eu1,
    const void* __restrict__ b1, const void* __restrict__ w2,
    const void* __restrict__ a2, const void* __restrict__ eu2,
    const void* __restrict__ b2, int* __restrict__ flag,
    float* __restrict__ eef, float* __restrict__ att1f, float* __restrict__ att2f,
    float* __restrict__ b1f, float* __restrict__ b2f,
    bf16* __restrict__ WT1, bf16* __restrict__ WT2,
    bf16* __restrict__ euT1, bf16* __restrict__ euT2,
    float* __restrict__ s_et, int* __restrict__ counts, int N) {
  __shared__ int cnt;
  __shared__ int fl;
  if (threadIdx.x == 0) cnt = 0;
  __syncthreads();
  const unsigned short* probe = (const unsigned short*)w1;
  int local = 0;
#pragma unroll
  for (int k = 0; k < 8; ++k) {
    int e = (probe[threadIdx.x * 8 + k] >> 7) & 0xFF;
    if (e >= 160) local++;
  }
  if (local) atomicAdd(&cnt, local);
  __syncthreads();
  if (threadIdx.x == 0) {
    fl = (cnt > 16) ? 1 : 0;
    if (blockIdx.x == 0) *flag = fl;
  }
  __syncthreads();
  int f = fl;

  int i = blockIdx.x * 256 + threadIdx.x;
  if (i < 2048) {
    eef[i] = ldv(ee, i, f);
  } else if (i < 2912) {
    att1f[i - 2048] = ldv(a1, i - 2048, f);
  } else if (i < 3776) {
    att2f[i - 2912] = ldv(a2, i - 2912, f);
  } else if (i < 3904) {
    b1f[i - 3776] = ldv(b1, i - 3776, f);
  } else if (i < 4032) {
    b2f[i - 3904] = ldv(b2, i - 3904, f);
  } else if (i < 53184) {
    int j = i - 4032; int c = j >> 7, k = j & 127;
    WT1[j] = __float2bfloat16(ldv(w1, k * 384 + c, f));
  } else if (i < 102336) {
    int j = i - 53184; int c = j >> 7, k = j & 127;
    WT2[j] = __float2bfloat16(ldv(w2, k * 384 + c, f));
  } else if (i < 122816) {
    int j = i - 102336; int c = j / 160, k = j % 160;
    euT1[j] = __float2bfloat16(ldv(eu1, k * 128 + c, f));
  } else if (i < 143296) {
    int j = i - 122816; int c = j / 160, k = j % 160;
    euT2[j] = __float2bfloat16(ldv(eu2, k * 128 + c, f));
  } else if (i < 143296 + N) {
    counts[i - 143296] = 0;
  }

  // block 0: s_et[l][t][h] = dot(edge_emb[t], att_l[h,256:288]); t==64 -> 0
  if (blockIdx.x == 0) {
    for (int id = threadIdx.x; id < 2 * 65 * 3; id += 256) {
      int l = id / (65 * 3);
      int r = id % (65 * 3);
      int t = r / 3, h = r % 3;
      const void* att = l ? a2 : a1;
      float s = 0.0f;
      if (t < 64) {
        for (int d = 0; d < 32; ++d)
          s += ldv(ee, t * 32 + d, f) * ldv(att, h * 288 + 256 + d, f);
      }
      s_et[id] = s;
    }
  }
}

// ------------------------------------------------------------------
// prep: x0 = maxnorm(node_emb[x_idx]) -> bf16 x (in d_out);
// + edge counting (grid-stride). counts pre-zeroed by wconv.
// ------------------------------------------------------------------
__global__ __launch_bounds__(256) void prep_kernel(
    const int* __restrict__ x_idx, const void* __restrict__ node_emb,
    const int* __restrict__ flag, bf16* __restrict__ xb,
    int* __restrict__ counts, const int* __restrict__ dst, int E0, int N) {
  int wid = threadIdx.x >> 6, lane = threadIdx.x & 63;
  int n = blockIdx.x * 4 + wid;
  if (n < N) {
    int idx = x_idx[n];
    if ((unsigned)idx >= (unsigned)N) idx = 0;
    float v0, v1;
    if (*flag) {
      const float* er = (const float*)node_emb + (size_t)idx * 128;
      v0 = er[lane]; v1 = er[lane + 64];
    } else {
      const bf16* er = (const bf16*)node_emb + (size_t)idx * 128;
      v0 = b2f(er[lane]); v1 = b2f(er[lane + 64]);
    }
    float ss = v0 * v0 + v1 * v1;
#pragma unroll
    for (int d = 32; d > 0; d >>= 1) ss += __shfl_xor(ss, d);
    float norm = sqrtf(ss);
    float scale = norm > 1.0f ? 1.0f / norm : 1.0f;
    xb[(size_t)n * 128 + lane] = __float2bfloat16(v0 * scale);
    xb[(size_t)n * 128 + 64 + lane] = __float2bfloat16(v1 * scale);
  }
  int gid = blockIdx.x * 256 + threadIdx.x;
  int stride = gridDim.x * 256;
  for (int i = gid; i < E0; i += stride) {
    int d = dst[i];
    if ((unsigned)d >= (unsigned)N) d = 0;
    atomicAdd(&counts[d], 1);
  }
}

// ------------------------------------------------------------------
// parallel exclusive scan with +1 per row (self loop), one block of
// 1024 threads (16 waves). counts becomes cursor in place.
// ------------------------------------------------------------------
__global__ __launch_bounds__(1024) void scan_kernel(
    int* __restrict__ counts, int* __restrict__ row_ptr, int N) {
  __shared__ int wsum[16];
  int t = threadIdx.x;
  int chunk = (N + 1023) >> 10;
  int lo = t * chunk;
  int hi = lo + chunk;
  if (lo > N) lo = N;
  if (hi > N) hi = N;
  int s = 0;
  for (int i = lo; i < hi; ++i) s += counts[i] + 1;
  int lane = t & 63, wv = t >> 6;
  int incl = s;
#pragma unroll
  for (int d = 1; d < 64; d <<= 1) {
    int u = __shfl_up(incl, d);
    if (lane >= d) incl += u;
  }
  if (lane == 63) wsum[wv] = incl;
  __syncthreads();
  if (t == 0) {
    int run = 0;
#pragma unroll
    for (int w = 0; w < 16; ++w) { int c = wsum[w]; wsum[w] = run; run += c; }
  }
  __syncthreads();
  int run = incl - s + wsum[wv];  // exclusive prefix for this thread
  for (int i = lo; i < hi; ++i) {
    int c = counts[i] + 1;
    row_ptr[i] = run;
    counts[i] = run;
    run += c;
  }
  if (t == 1023) row_ptr[N] = run;
}

// ------------------------------------------------------------------
// scatter edges (+self loops, etype=64) into CSR: packed = src | et<<16
// ------------------------------------------------------------------
__global__ __launch_bounds__(256) void scatter_kernel(
    const int* __restrict__ src, const int* __restrict__ dst,
    const int* __restrict__ et, int* __restrict__ cursor,
    int* __restrict__ packed, int E0, int N) {
  int E = E0 + N;
  int i = blockIdx.x * blockDim.x + threadIdx.x;
  if (i < E0) {
    int d = dst[i];
    if ((unsigned)d >= (unsigned)N) d = 0;
    int p = atomicAdd(&cursor[d], 1);
    if ((unsigned)p >= (unsigned)E) p = 0;
    int t = et[i] & 63;
    packed[p] = (src[i] & 0xFFFF) | (t << 16);
  } else if (i < E) {
    int n = i - E0;
    int p = atomicAdd(&cursor[n], 1);
    if ((unsigned)p >= (unsigned)E) p = 0;
    packed[p] = (n & 0xFFFF) | (64 << 16);
  }
}

// ------------------------------------------------------------------
// xh = x @ W via MFMA + fused s_i/s_j. Block = 6 waves (384 thr),
// 32 rows x 384 cols (B-fragments reused across both 16-row tiles).
// Grid: N/32. Wave w covers cols [w*64, w*64+64) (inside head w/2).
// xh permuted: half-index = node*384 + pair*6 + head*2 + sub,
// col = head*128 + pair*2 + sub.
// ------------------------------------------------------------------
__global__ __launch_bounds__(384) void gemm_xh_s_mfma(
    const bf16* __restrict__ x, const bf16* __restrict__ WT,
    const float* __restrict__ attf, bf16* __restrict__ xh,
    float* __restrict__ s_i, float* __restrict__ s_j, int N) {
  __shared__ float lds_i[6][32];
  __shared__ float lds_j[6][32];
  int wave = threadIdx.x >> 6, lane = threadIdx.x & 63;
  int row_base = blockIdx.x * 32;
  int quad = lane >> 4, r16 = lane & 15;
  int rowA = row_base + r16;      if (rowA >= N) rowA = N - 1;
  int rowB = row_base + 16 + r16; if (rowB >= N) rowB = N - 1;
  const short8* apA = (const short8*)(x + (size_t)rowA * 128 + quad * 8);
  const short8* apB = (const short8*)(x + (size_t)rowB * 128 + quad * 8);
  short8 aA[4], aB[4];
#pragma unroll
  for (int kk = 0; kk < 4; ++kk) { aA[kk] = apA[kk * 4]; aB[kk] = apB[kk * 4]; }

  float piA[4] = {0.f, 0.f, 0.f, 0.f}, pjA[4] = {0.f, 0.f, 0.f, 0.f};
  float piB[4] = {0.f, 0.f, 0.f, 0.f}, pjB[4] = {0.f, 0.f, 0.f, 0.f};
#pragma unroll
  for (int j = 0; j < 4; ++j) {
    int col = wave * 64 + j * 16 + r16;
    const short8* bp = (const short8*)(WT + (size_t)col * 128 + quad * 8);
    short8 b[4];
#pragma unroll
    for (int kk = 0; kk < 4; ++kk) b[kk] = bp[kk * 4];
    f32x4 accA = {0.f, 0.f, 0.f, 0.f};
    f32x4 accB = {0.f, 0.f, 0.f, 0.f};
#pragma unroll
    for (int kk = 0; kk < 4; ++kk) {
      accA = __builtin_amdgcn_mfma_f32_16x16x32_bf16(aA[kk], b[kk], accA, 0, 0, 0);
      accB = __builtin_amdgcn_mfma_f32_16x16x32_bf16(aB[kk], b[kk], accB, 0, 0, 0);
    }
    int h = col >> 7, fi = col & 127, pair = fi >> 1, sub = fi & 1;
    size_t base = (size_t)pair * 6 + h * 2 + sub;
#pragma unroll
    for (int r = 0; r < 4; ++r) {
      int nA = row_base + quad * 4 + r;
      int nB = row_base + 16 + quad * 4 + r;
      if (nA < N) xh[(size_t)nA * 384 + base] = __float2bfloat16(accA[r]);
      if (nB < N) xh[(size_t)nB * 384 + base] = __float2bfloat16(accB[r]);
    }
    float ai = attf[h * 288 + fi];
    float aj = attf[h * 288 + 128 + fi];
#pragma unroll
    for (int r = 0; r < 4; ++r) {
      piA[r] = fmaf(accA[r], ai, piA[r]);
      pjA[r] = fmaf(accA[r], aj, pjA[r]);
      piB[r] = fmaf(accB[r], ai, piB[r]);
      pjB[r] = fmaf(accB[r], aj, pjB[r]);
    }
  }
  // reduce over the 16 col-lanes within each quad (rows stay distinct)
#pragma unroll
  for (int d = 1; d < 16; d <<= 1) {
#pragma unroll
    for (int r = 0; r < 4; ++r) {
      piA[r] += __shfl_xor(piA[r], d);
      pjA[r] += __shfl_xor(pjA[r], d);
      piB[r] += __shfl_xor(piB[r], d);
      pjB[r] += __shfl_xor(pjB[r], d);
    }
  }
  if (r16 == 0) {
#pragma unroll
    for (int r = 0; r < 4; ++r) {
      lds_i[wave][quad * 4 + r] = piA[r];
      lds_j[wave][quad * 4 + r] = pjA[r];
      lds_i[wave][16 + quad * 4 + r] = piB[r];
      lds_j[wave][16 + quad * 4 + r] = pjB[r];
    }
  }
  __syncthreads();
  int m = threadIdx.x;
  if (m < 96) {
    int h = m / 32, r = m % 32;
    int node = row_base + r;
    if (node < N) s_i[node * 3 + h] = lds_i[2 * h][r] + lds_i[2 * h + 1][r];
  } else if (m < 192) {
    int tt = m - 96;
    int h = tt / 32, r = tt % 32;
    int node = row_base + r;
    if (node < N) s_j[node * 3 + h] = lds_j[2 * h][r] + lds_j[2 * h + 1][r];
  }
}

// ------------------------------------------------------------------
// per-dst softmax + weighted aggregation -> bf16 aggr [N][160].
// 2 waves per node (block = 4 waves = 2 nodes). Wave w handles edge
// slots {2*lane + w}; partials combined via LDS.
// Phase A: one edge per lane, exp weights in regs (clamp, no max pass).
// Phase B: serial aggregation, params via shfl, one 3-dword gather/edge.
// ------------------------------------------------------------------
__global__ __launch_bounds__(256) void edge_aggr_kernel(
    const int* __restrict__ xh_i, const float* __restrict__ s_i,
    const float* __restrict__ s_j, const float* __restrict__ s_et,
    const float2* __restrict__ eef2, const int* __restrict__ row_ptr,
    const int* __restrict__ packed, unsigned* __restrict__ aggr_u,
    int N, int E) {
  __shared__ float lds[2][512];
  int wid = threadIdx.x >> 6, lane = threadIdx.x & 63;
  int nodeLocal = wid >> 1, w = wid & 1;
  int n0 = blockIdx.x * 2 + nodeLocal;
  int n = n0 < N ? n0 : N - 1;  // clamp; all threads stay for barrier
  int start = row_ptr[n], end = row_ptr[n + 1];
  if (start < 0) start = 0;
  if (start > E) start = E;
  if (end < start) end = start;
  if (end > E) end = E;
  int deg = end - start;
  float si0 = s_i[n * 3 + 0], si1 = s_i[n * 3 + 1], si2 = s_i[n * 3 + 2];

  // ---- phase A: slot = 2*lane + w ----
  float p0r = 0.f, p1r = 0.f, p2r = 0.f;
  int pkr = 0;
  float dp0 = 0.0f, dp1 = 0.0f, dp2 = 0.0f;
  int slot = 2 * lane + w;
  if (slot < deg) {
    int p = packed[start + slot];
    int s = p & 0xFFFF; if (s >= N) s = N - 1;
    int t = (p >> 16) & 127; if (t > 64) t = 64;
    float a0 = si0 + s_j[s * 3 + 0] + s_et[t * 3 + 0];
    float a1 = si1 + s_j[s * 3 + 1] + s_et[t * 3 + 1];
    float a2 = si2 + s_j[s * 3 + 2] + s_et[t * 3 + 2];
    a0 = a0 > 0.0f ? a0 : 0.2f * a0;
    a1 = a1 > 0.0f ? a1 : 0.2f * a1;
    a2 = a2 > 0.0f ? a2 : 0.2f * a2;
    a0 = fminf(fmaxf(a0, -60.0f), 60.0f);
    a1 = fminf(fmaxf(a1, -60.0f), 60.0f);
    a2 = fminf(fmaxf(a2, -60.0f), 60.0f);
    p0r = __expf(a0); p1r = __expf(a1); p2r = __expf(a2);
    dp0 = p0r; dp1 = p1r; dp2 = p2r;
    pkr = s | (t << 16);
  }
#pragma unroll
  for (int d = 32; d > 0; d >>= 1) {
    dp0 += __shfl_xor(dp0, d);
    dp1 += __shfl_xor(dp1, d);
    dp2 += __shfl_xor(dp2, d);
  }
  float d0 = dp0, d1 = dp1, d2 = dp2;  // this wave's partial denominator

  // ---- phase B: this wave's cnt edges (register slots 0..cnt-1) ----
  float2 ax0 = make_float2(0.f, 0.f), ax1 = ax0, ax2 = ax0;
  float2 ae0 = ax0, ae1 = ax0, ae2 = ax0;
  int capped = deg < 128 ? deg : 128;
  int cnt = (capped > w) ? ((capped - w + 1) >> 1) : 0;

  {
    int j = 0;
    for (; j + 2 <= cnt; j += 2) {
      int pkA = __shfl(pkr, j), pkB = __shfl(pkr, j + 1);
      float qA0 = __shfl(p0r, j), qB0 = __shfl(p0r, j + 1);
      float qA1 = __shfl(p1r, j), qB1 = __shfl(p1r, j + 1);
      float qA2 = __shfl(p2r, j), qB2 = __shfl(p2r, j + 1);
      int sA = pkA & 0xFFFF, tA = pkA >> 16;
      int sB = pkB & 0xFFFF, tB = pkB >> 16;
      const int* xpA = xh_i + (size_t)sA * 192 + lane * 3;
      const int* xpB = xh_i + (size_t)sB * 192 + lane * 3;
      int wA0 = xpA[0], wA1 = xpA[1], wA2 = xpA[2];
      int wB0 = xpB[0], wB1 = xpB[1], wB2 = xpB[2];
      float2 vA0 = i2f2(wA0), vA1 = i2f2(wA1), vA2 = i2f2(wA2);
      float2 vB0 = i2f2(wB0), vB1 = i2f2(wB1), vB2 = i2f2(wB2);
      ax0.x = fmaf(qA0, vA0.x, ax0.x); ax0.y = fmaf(qA0, vA0.y, ax0.y);
      ax1.x = fmaf(qA1, vA1.x, ax1.x); ax1.y = fmaf(qA1, vA1.y, ax1.y);
      ax2.x = fmaf(qA2, vA2.x, ax2.x); ax2.y = fmaf(qA2, vA2.y, ax2.y);
      ax0.x = fmaf(qB0, vB0.x, ax0.x); ax0.y = fmaf(qB0, vB0.y, ax0.y);
      ax1.x = fmaf(qB1, vB1.x, ax1.x); ax1.y = fmaf(qB1, vB1.y, ax1.y);
      ax2.x = fmaf(qB2, vB2.x, ax2.x); ax2.y = fmaf(qB2, vB2.y, ax2.y);
      if (lane < 16) {
        if (tA != 64) {
          float2 ev = eef2[tA * 16 + lane];
          ae0.x = fmaf(qA0, ev.x, ae0.x); ae0.y = fmaf(qA0, ev.y, ae0.y);
          ae1.x = fmaf(qA1, ev.x, ae1.x); ae1.y = fmaf(qA1, ev.y, ae1.y);
          ae2.x = fmaf(qA2, ev.x, ae2.x); ae2.y = fmaf(qA2, ev.y, ae2.y);
        }
        if (tB != 64) {
          float2 ev = eef2[tB * 16 + lane];
          ae0.x = fmaf(qB0, ev.x, ae0.x); ae0.y = fmaf(qB0, ev.y, ae0.y);
          ae1.x = fmaf(qB1, ev.x, ae1.x); ae1.y = fmaf(qB1, ev.y, ae1.y);
          ae2.x = fmaf(qB2, ev.x, ae2.x); ae2.y = fmaf(qB2, ev.y, ae2.y);
        }
      }
    }
    if (j < cnt) {
      int pkA = __shfl(pkr, j);
      float qA0 = __shfl(p0r, j), qA1 = __shfl(p1r, j), qA2 = __shfl(p2r, j);
      int sA = pkA & 0xFFFF, tA = pkA >> 16;
      const int* xpA = xh_i + (size_t)sA * 192 + lane * 3;
      int wA0 = xpA[0], wA1 = xpA[1], wA2 = xpA[2];
      float2 vA0 = i2f2(wA0), vA1 = i2f2(wA1), vA2 = i2f2(wA2);
      ax0.x = fmaf(qA0, vA0.x, ax0.x); ax0.y = fmaf(qA0, vA0.y, ax0.y);
      ax1.x = fmaf(qA1, vA1.x, ax1.x); ax1.y = fmaf(qA1, vA1.y, ax1.y);
      ax2.x = fmaf(qA2, vA2.x, ax2.x); ax2.y = fmaf(qA2, vA2.y, ax2.y);
      if (lane < 16 && tA != 64) {
        float2 ev = eef2[tA * 16 + lane];
        ae0.x = fmaf(qA0, ev.x, ae0.x); ae0.y = fmaf(qA0, ev.y, ae0.y);
        ae1.x = fmaf(qA1, ev.x, ae1.x); ae1.y = fmaf(qA1, ev.y, ae1.y);
        ae2.x = fmaf(qA2, ev.x, ae2.x); ae2.y = fmaf(qA2, ev.y, ae2.y);
      }
    }
  }

  // rare fallback: degree > 128, wave 0 handles remainder serially
  if (w == 0) {
    for (int e = start + 128; e < end; ++e) {
      int p = packed[e];
      int s = p & 0xFFFF; if (s >= N) s = N - 1;
      int t = (p >> 16) & 127; if (t > 64) t = 64;
      float a0 = si0 + s_j[s * 3 + 0] + s_et[t * 3 + 0];
      float a1 = si1 + s_j[s * 3 + 1] + s_et[t * 3 + 1];
      float a2 = si2 + s_j[s * 3 + 2] + s_et[t * 3 + 2];
      a0 = a0 > 0.0f ? a0 : 0.2f * a0;
      a1 = a1 > 0.0f ? a1 : 0.2f * a1;
      a2 = a2 > 0.0f ? a2 : 0.2f * a2;
      a0 = fminf(fmaxf(a0, -60.0f), 60.0f);
      a1 = fminf(fmaxf(a1, -60.0f), 60.0f);
      a2 = fminf(fmaxf(a2, -60.0f), 60.0f);
      float p0 = __expf(a0), p1 = __expf(a1), p2 = __expf(a2);
      d0 += p0; d1 += p1; d2 += p2;
      const int* xp = xh_i + (size_t)s * 192 + lane * 3;
      float2 v0 = i2f2(xp[0]), v1 = i2f2(xp[1]), v2 = i2f2(xp[2]);
      ax0.x = fmaf(p0, v0.x, ax0.x); ax0.y = fmaf(p0, v0.y, ax0.y);
      ax1.x = fmaf(p1, v1.x, ax1.x); ax1.y = fmaf(p1, v1.y, ax1.y);
      ax2.x = fmaf(p2, v2.x, ax2.x); ax2.y = fmaf(p2, v2.y, ax2.y);
      if (t != 64 && lane < 16) {
        float2 ev = eef2[t * 16 + lane];
        ae0.x = fmaf(p0, ev.x, ae0.x); ae0.y = fmaf(p0, ev.y, ae0.y);
        ae1.x = fmaf(p1, ev.x, ae1.x); ae1.y = fmaf(p1, ev.y, ae1.y);
        ae2.x = fmaf(p2, ev.x, ae2.x); ae2.y = fmaf(p2, ev.y, ae2.y);
      }
    }
  }

  // ---- combine the two waves' partials via LDS ----
  float* L = lds[nodeLocal];
  if (w == 1) {
    L[lane * 2 + 0] = ax0.x;       L[lane * 2 + 1] = ax0.y;
    L[128 + lane * 2 + 0] = ax1.x; L[128 + lane * 2 + 1] = ax1.y;
    L[256 + lane * 2 + 0] = ax2.x; L[256 + lane * 2 + 1] = ax2.y;
    if (lane < 16) {
      L[384 + lane * 2 + 0] = ae0.x; L[384 + lane * 2 + 1] = ae0.y;
      L[416 + lane * 2 + 0] = ae1.x; L[416 + lane * 2 + 1] = ae1.y;
      L[448 + lane * 2 + 0] = ae2.x; L[448 + lane * 2 + 1] = ae2.y;
    }
    if (lane == 0) { L[480] = d0; L[481] = d1; L[482] = d2; }
  }
  __syncthreads();
  if (w == 0 && n0 < N) {
    ax0.x += L[lane * 2 + 0];       ax0.y += L[lane * 2 + 1];
    ax1.x += L[128 + lane * 2 + 0]; ax1.y += L[128 + lane * 2 + 1];
    ax2.x += L[256 + lane * 2 + 0]; ax2.y += L[256 + lane * 2 + 1];
    if (lane < 16) {
      ae0.x += L[384 + lane * 2 + 0]; ae0.y += L[384 + lane * 2 + 1];
      ae1.x += L[416 + lane * 2 + 0]; ae1.y += L[416 + lane * 2 + 1];
      ae2.x += L[448 + lane * 2 + 0]; ae2.y += L[448 + lane * 2 + 1];
    }
    d0 += L[480]; d1 += L[481]; d2 += L[482];
    const float third = 1.0f / 3.0f;
    float i0 = third / fmaxf(d0, 1e-30f);
    float i1 = third / fmaxf(d1, 1e-30f);
    float i2 = third / fmaxf(d2, 1e-30f);
    aggr_u[(size_t)n0 * 80 + lane] =
        pk2(ax0.x * i0 + ax1.x * i1 + ax2.x * i2,
            ax0.y * i0 + ax1.y * i1 + ax2.y * i2);
    if (lane < 16)
      aggr_u[(size_t)n0 * 80 + 64 + lane] =
          pk2(ae0.x * i0 + ae1.x * i1 + ae2.x * i2,
              ae0.y * i0 + ae1.y * i1 + ae2.y * i2);
  }
}

// ------------------------------------------------------------------
// out = aggr @ euw + bias via MFMA (K=160). aggr [N][160] bf16,
// euwT [128][160] bf16. Optional ELU. Intermediate -> bf16 x (d_out);
// final -> d_out in detected dtype. Grid (N/16, 2), 4 waves/block.
// ------------------------------------------------------------------
__global__ __launch_bounds__(256) void gemm_out_mfma(
    const bf16* __restrict__ aggr, const bf16* __restrict__ euwT,
    const float* __restrict__ biasf, bf16* __restrict__ xb,
    void* __restrict__ dout, const int* __restrict__ flag,
    int N, int do_elu, int do_final) {
  int wave = threadIdx.x >> 6, lane = threadIdx.x & 63;
  int row_base = blockIdx.x * 16;
  int col_base = blockIdx.y * 64 + wave * 16;
  int quad = lane >> 4, r16 = lane & 15;
  int row = row_base + r16; if (row >= N) row = N - 1;
  int col = col_base + r16;
  f32x4 acc = {0.f, 0.f, 0.f, 0.f};
  const short8* ap = (const short8*)(aggr + (size_t)row * 160 + quad * 8);
  const short8* bp = (const short8*)(euwT + (size_t)col * 160 + quad * 8);
#pragma unroll
  for (int kk = 0; kk < 5; ++kk) {
    short8 a = ap[kk * 4];
    short8 b = bp[kk * 4];
    acc = __builtin_amdgcn_mfma_f32_16x16x32_bf16(a, b, acc, 0, 0, 0);
  }
  float bv = biasf[col];
  int f = *flag;
#pragma unroll
  for (int r = 0; r < 4; ++r) {
    int node = row_base + quad * 4 + r;
    if (node < N) {
      float v = acc[r] + bv;
      if (do_elu) v = v > 0.0f ? v : expm1f(v);
      if (do_final) {
        if (f) ((float*)dout)[(size_t)node * 128 + col] = v;
        else   ((bf16*)dout)[(size_t)node * 128 + col] = __float2bfloat16(v);
      } else {
        xb[(size_t)node * 128 + col] = __float2bfloat16(v);
      }
    }
  }
}

// ------------------------------------------------------------------
extern "C" void kernel_launch(void* const* d_in, const int* in_sizes, int n_in,
                              void* d_out, int out_size, void* d_ws, size_t ws_size,
                              hipStream_t stream) {
  const int* x_idx = (const int*)d_in[0];
  const int* edge_index = (const int*)d_in[1];
  const int* edge_attr_idx = (const int*)d_in[2];

  int N = in_sizes[0];
  int E0 = in_sizes[1] / 2;
  int E = E0 + N;
  const int* src = edge_index;
  const int* dst = edge_index + E0;

  // ---- workspace carve (~12.2 MB) ----
  size_t off = 0;
  char* base = (char*)d_ws;
  auto carve = [&](size_t bytes) -> void* {
    void* p = base + off;
    off += (bytes + 255) & ~(size_t)255;
    return p;
  };
  int* flag     = (int*)carve(256);
  int* counts   = (int*)carve((size_t)N * 4);    // becomes cursor after scan
  int* row_ptr  = (int*)carve((size_t)(N + 1) * 4);
  int* packed   = (int*)carve((size_t)E * 4);
  float* s_i    = (float*)carve((size_t)N * 3 * 4);
  float* s_j    = (float*)carve((size_t)N * 3 * 4);
  float* s_et   = (float*)carve(2 * 65 * 3 * 4);
  float* eef    = (float*)carve(2048 * 4);
  float* att1f  = (float*)carve(864 * 4);
  float* att2f  = (float*)carve(864 * 4);
  float* b1f    = (float*)carve(128 * 4);
  float* b2f_   = (float*)carve(128 * 4);
  bf16* WT1     = (bf16*)carve(49152 * 2);
  bf16* WT2     = (bf16*)carve(49152 * 2);
  bf16* euT1    = (bf16*)carve(20480 * 2);
  bf16* euT2    = (bf16*)carve(20480 * 2);
  bf16* xh      = (bf16*)carve((size_t)N * 384 * 2 + 64);
  bf16* aggr    = (bf16*)carve((size_t)N * 160 * 2);
  bf16* xb      = (bf16*)d_out;  // bf16 x lives in d_out between layers
  (void)n_in; (void)out_size; (void)ws_size;

  // ---- setup: 4 dispatches ----
  wconv_kernel<<<(143296 + N + 255) / 256, 256, 0, stream>>>(
      d_in[4], d_in[5], d_in[6], d_in[7], d_in[8], d_in[9], d_in[10], d_in[11],
      d_in[12], flag, eef, att1f, att2f, b1f, b2f_, WT1, WT2, euT1, euT2,
      s_et, counts, N);
  int nb4 = (N + 3) / 4;
  prep_kernel<<<nb4, 256, 0, stream>>>(x_idx, d_in[3], flag, xb, counts, dst,
                                       E0, N);
  scan_kernel<<<1, 1024, 0, stream>>>(counts, row_ptr, N);
  scatter_kernel<<<(E + 255) / 256, 256, 0, stream>>>(src, dst, edge_attr_idx,
                                                      counts, packed, E0, N);

  const bf16* WTs[2] = {WT1, WT2};
  const float* atts[2] = {att1f, att2f};
  const bf16* euTs[2] = {euT1, euT2};
  const float* bs[2] = {b1f, b2f_};

  int nrb16 = (N + 15) / 16;
  int nrb32 = (N + 31) / 32;
  int nb2 = (N + 1) / 2;
  for (int round = 0; round < 2; ++round) {
    for (int l = 0; l < 2; ++l) {
      int do_elu = (l == 0) ? 1 : 0;
      int do_final = (round == 1 && l == 1) ? 1 : 0;
      gemm_xh_s_mfma<<<nrb32, 384, 0, stream>>>(xb, WTs[l], atts[l], xh,
                                                s_i, s_j, N);
      edge_aggr_kernel<<<nb2, 256, 0, stream>>>(
          (const int*)xh, s_i, s_j, s_et + l * 195, (const float2*)eef,
          row_ptr, packed, (unsigned*)aggr, N, E);
      gemm_out_mfma<<<dim3(nrb16, 2), 256, 0, stream>>>(
          aggr, euTs[l], bs[l], xb, d_out, flag, N, do_elu, do_final);
    }
  }
}

// Round 10
// 317.953 us; speedup vs baseline: 1.8975x; 1.0236x over previous
//
#include <hip/hip_runtime.h>
#include <hip/hip_bf16.h>

typedef __hip_bfloat16 bf16;
typedef __attribute__((ext_vector_type(8))) short short8;
typedef __attribute__((ext_vector_type(4))) float f32x4;

__device__ __forceinline__ float b2f(bf16 v) { return __bfloat162float(v); }
// int (2 packed bf16) -> two floats. x = low half, y = high half.
__device__ __forceinline__ float2 i2f2(int w) {
  float lo = __uint_as_float(((unsigned)w) << 16);
  float hi = __uint_as_float(((unsigned)w) & 0xFFFF0000u);
  return make_float2(lo, hi);
}
// float -> bf16 bits (RNE; inputs finite)
__device__ __forceinline__ unsigned f2bfb(float f) {
  unsigned u = __float_as_uint(f);
  unsigned r = 0x7FFFu + ((u >> 16) & 1u);
  return (u + r) >> 16;
}
__device__ __forceinline__ unsigned pk2(float a, float b) {
  return f2bfb(a) | (f2bfb(b) << 16);
}
__device__ __forceinline__ float ldv(const void* p, int i, int f) {
  return f ? ((const float*)p)[i] : b2f(((const bf16*)p)[i]);
}

// ------------------------------------------------------------------
// weight materialization + per-block dtype detect + counts zero;
// block 0 computes s_et and publishes flag.
// ------------------------------------------------------------------
__global__ __launch_bounds__(256) void wconv_kernel(
    const void* __restrict__ ee, const void* __restrict__ w1,
    const void* __restrict__ a1, const void* __restrict__ eu1,
    const void* __restrict__ b1, const void* __restrict__ w2,
    const void* __restrict__ a2, const void* __restrict__ eu2,
    const void* __restrict__ b2, int* __restrict__ flag,
    float* __restrict__ eef, float* __restrict__ att1f, float* __restrict__ att2f,
    float* __restrict__ b1f, float* __restrict__ b2f,
    bf16* __restrict__ WT1, bf16* __restrict__ WT2,
    bf16* __restrict__ euT1, bf16* __restrict__ euT2,
    float* __restrict__ s_et, int* __restrict__ counts, int N) {
  __shared__ int cnt;
  __shared__ int fl;
  if (threadIdx.x == 0) cnt = 0;
  __syncthreads();
  const unsigned short* probe = (const unsigned short*)w1;
  int local = 0;
#pragma unroll
  for (int k = 0; k < 8; ++k) {
    int e = (probe[threadIdx.x * 8 + k] >> 7) & 0xFF;
    if (e >= 160) local++;
  }
  if (local) atomicAdd(&cnt, local);
  __syncthreads();
  if (threadIdx.x == 0) {
    fl = (cnt > 16) ? 1 : 0;
    if (blockIdx.x == 0) *flag = fl;
  }
  __syncthreads();
  int f = fl;

  int i = blockIdx.x * 256 + threadIdx.x;
  if (i < 2048) {
    eef[i] = ldv(ee, i, f);
  } else if (i < 2912) {
    att1f[i - 2048] = ldv(a1, i - 2048, f);
  } else if (i < 3776) {
    att2f[i - 2912] = ldv(a2, i - 2912, f);
  } else if (i < 3904) {
    b1f[i - 3776] = ldv(b1, i - 3776, f);
  } else if (i < 4032) {
    b2f[i - 3904] = ldv(b2, i - 3904, f);
  } else if (i < 53184) {
    int j = i - 4032; int c = j >> 7, k = j & 127;
    WT1[j] = __float2bfloat16(ldv(w1, k * 384 + c, f));
  } else if (i < 102336) {
    int j = i - 53184; int c = j >> 7, k = j & 127;
    WT2[j] = __float2bfloat16(ldv(w2, k * 384 + c, f));
  } else if (i < 122816) {
    int j = i - 102336; int c = j / 160, k = j % 160;
    euT1[j] = __float2bfloat16(ldv(eu1, k * 128 + c, f));
  } else if (i < 143296) {
    int j = i - 122816; int c = j / 160, k = j % 160;
    euT2[j] = __float2bfloat16(ldv(eu2, k * 128 + c, f));
  } else if (i < 143296 + N) {
    counts[i - 143296] = 0;
  }

  if (blockIdx.x == 0) {
    for (int id = threadIdx.x; id < 2 * 65 * 3; id += 256) {
      int l = id / (65 * 3);
      int r = id % (65 * 3);
      int t = r / 3, h = r % 3;
      const void* att = l ? a2 : a1;
      float s = 0.0f;
      if (t < 64) {
        for (int d = 0; d < 32; ++d)
          s += ldv(ee, t * 32 + d, f) * ldv(att, h * 288 + 256 + d, f);
      }
      s_et[id] = s;
    }
  }
}

// ------------------------------------------------------------------
// prep: x0 = maxnorm(node_emb[x_idx]) -> bf16 x (in d_out);
// + edge counting (grid-stride). counts pre-zeroed by wconv.
// ------------------------------------------------------------------
__global__ __launch_bounds__(256) void prep_kernel(
    const int* __restrict__ x_idx, const void* __restrict__ node_emb,
    const int* __restrict__ flag, bf16* __restrict__ xb,
    int* __restrict__ counts, const int* __restrict__ dst, int E0, int N) {
  int wid = threadIdx.x >> 6, lane = threadIdx.x & 63;
  int n = blockIdx.x * 4 + wid;
  if (n < N) {
    int idx = x_idx[n];
    if ((unsigned)idx >= (unsigned)N) idx = 0;
    float v0, v1;
    if (*flag) {
      const float* er = (const float*)node_emb + (size_t)idx * 128;
      v0 = er[lane]; v1 = er[lane + 64];
    } else {
      const bf16* er = (const bf16*)node_emb + (size_t)idx * 128;
      v0 = b2f(er[lane]); v1 = b2f(er[lane + 64]);
    }
    float ss = v0 * v0 + v1 * v1;
#pragma unroll
    for (int d = 32; d > 0; d >>= 1) ss += __shfl_xor(ss, d);
    float norm = sqrtf(ss);
    float scale = norm > 1.0f ? 1.0f / norm : 1.0f;
    xb[(size_t)n * 128 + lane] = __float2bfloat16(v0 * scale);
    xb[(size_t)n * 128 + 64 + lane] = __float2bfloat16(v1 * scale);
  }
  int gid = blockIdx.x * 256 + threadIdx.x;
  int stride = gridDim.x * 256;
  for (int i = gid; i < E0; i += stride) {
    int d = dst[i];
    if ((unsigned)d >= (unsigned)N) d = 0;
    atomicAdd(&counts[d], 1);
  }
}

// ------------------------------------------------------------------
// parallel exclusive scan with +1 per row (self loop), one block of
// 1024 threads (16 waves). counts becomes cursor in place.
// ------------------------------------------------------------------
__global__ __launch_bounds__(1024) void scan_kernel(
    int* __restrict__ counts, int* __restrict__ row_ptr, int N) {
  __shared__ int wsum[16];
  int t = threadIdx.x;
  int chunk = (N + 1023) >> 10;
  int lo = t * chunk;
  int hi = lo + chunk;
  if (lo > N) lo = N;
  if (hi > N) hi = N;
  int s = 0;
  for (int i = lo; i < hi; ++i) s += counts[i] + 1;
  int lane = t & 63, wv = t >> 6;
  int incl = s;
#pragma unroll
  for (int d = 1; d < 64; d <<= 1) {
    int u = __shfl_up(incl, d);
    if (lane >= d) incl += u;
  }
  if (lane == 63) wsum[wv] = incl;
  __syncthreads();
  if (t == 0) {
    int run = 0;
#pragma unroll
    for (int w = 0; w < 16; ++w) { int c = wsum[w]; wsum[w] = run; run += c; }
  }
  __syncthreads();
  int run = incl - s + wsum[wv];  // exclusive prefix for this thread
  for (int i = lo; i < hi; ++i) {
    int c = counts[i] + 1;
    row_ptr[i] = run;
    counts[i] = run;
    run += c;
  }
  if (t == 1023) row_ptr[N] = run;
}

// ------------------------------------------------------------------
// scatter edges (+self loops, etype=64) into CSR: packed = src | et<<16
// ------------------------------------------------------------------
__global__ __launch_bounds__(256) void scatter_kernel(
    const int* __restrict__ src, const int* __restrict__ dst,
    const int* __restrict__ et, int* __restrict__ cursor,
    int* __restrict__ packed, int E0, int N) {
  int E = E0 + N;
  int i = blockIdx.x * blockDim.x + threadIdx.x;
  if (i < E0) {
    int d = dst[i];
    if ((unsigned)d >= (unsigned)N) d = 0;
    int p = atomicAdd(&cursor[d], 1);
    if ((unsigned)p >= (unsigned)E) p = 0;
    int t = et[i] & 63;
    packed[p] = (src[i] & 0xFFFF) | (t << 16);
  } else if (i < E) {
    int n = i - E0;
    int p = atomicAdd(&cursor[n], 1);
    if ((unsigned)p >= (unsigned)E) p = 0;
    packed[p] = (n & 0xFFFF) | (64 << 16);
  }
}

// ------------------------------------------------------------------
// xh = x @ W via MFMA + fused s_i/s_j (layer 0 only; x = bf16 in d_out).
// Block = 6 waves (384 thr), 32 rows x 384 cols. Grid: N/32.
// xh permuted: half-index = node*384 + pair*6 + head*2 + sub,
// col = head*128 + pair*2 + sub.
// ------------------------------------------------------------------
__global__ __launch_bounds__(384) void gemm_xh_s_mfma(
    const bf16* __restrict__ x, const bf16* __restrict__ WT,
    const float* __restrict__ attf, bf16* __restrict__ xh,
    float* __restrict__ s_i, float* __restrict__ s_j, int N) {
  __shared__ float lds_i[6][32];
  __shared__ float lds_j[6][32];
  int wave = threadIdx.x >> 6, lane = threadIdx.x & 63;
  int row_base = blockIdx.x * 32;
  int quad = lane >> 4, r16 = lane & 15;
  int rowA = row_base + r16;      if (rowA >= N) rowA = N - 1;
  int rowB = row_base + 16 + r16; if (rowB >= N) rowB = N - 1;
  const short8* apA = (const short8*)(x + (size_t)rowA * 128 + quad * 8);
  const short8* apB = (const short8*)(x + (size_t)rowB * 128 + quad * 8);
  short8 aA[4], aB[4];
#pragma unroll
  for (int kk = 0; kk < 4; ++kk) { aA[kk] = apA[kk * 4]; aB[kk] = apB[kk * 4]; }

  float piA[4] = {0.f, 0.f, 0.f, 0.f}, pjA[4] = {0.f, 0.f, 0.f, 0.f};
  float piB[4] = {0.f, 0.f, 0.f, 0.f}, pjB[4] = {0.f, 0.f, 0.f, 0.f};
#pragma unroll
  for (int j = 0; j < 4; ++j) {
    int col = wave * 64 + j * 16 + r16;
    const short8* bp = (const short8*)(WT + (size_t)col * 128 + quad * 8);
    short8 b[4];
#pragma unroll
    for (int kk = 0; kk < 4; ++kk) b[kk] = bp[kk * 4];
    f32x4 accA = {0.f, 0.f, 0.f, 0.f};
    f32x4 accB = {0.f, 0.f, 0.f, 0.f};
#pragma unroll
    for (int kk = 0; kk < 4; ++kk) {
      accA = __builtin_amdgcn_mfma_f32_16x16x32_bf16(aA[kk], b[kk], accA, 0, 0, 0);
      accB = __builtin_amdgcn_mfma_f32_16x16x32_bf16(aB[kk], b[kk], accB, 0, 0, 0);
    }
    int h = col >> 7, fi = col & 127, pair = fi >> 1, sub = fi & 1;
    size_t base = (size_t)pair * 6 + h * 2 + sub;
#pragma unroll
    for (int r = 0; r < 4; ++r) {
      int nA = row_base + quad * 4 + r;
      int nB = row_base + 16 + quad * 4 + r;
      if (nA < N) xh[(size_t)nA * 384 + base] = __float2bfloat16(accA[r]);
      if (nB < N) xh[(size_t)nB * 384 + base] = __float2bfloat16(accB[r]);
    }
    float ai = attf[h * 288 + fi];
    float aj = attf[h * 288 + 128 + fi];
#pragma unroll
    for (int r = 0; r < 4; ++r) {
      piA[r] = fmaf(accA[r], ai, piA[r]);
      pjA[r] = fmaf(accA[r], aj, pjA[r]);
      piB[r] = fmaf(accB[r], ai, piB[r]);
      pjB[r] = fmaf(accB[r], aj, pjB[r]);
    }
  }
#pragma unroll
  for (int d = 1; d < 16; d <<= 1) {
#pragma unroll
    for (int r = 0; r < 4; ++r) {
      piA[r] += __shfl_xor(piA[r], d);
      pjA[r] += __shfl_xor(pjA[r], d);
      piB[r] += __shfl_xor(piB[r], d);
      pjB[r] += __shfl_xor(pjB[r], d);
    }
  }
  if (r16 == 0) {
#pragma unroll
    for (int r = 0; r < 4; ++r) {
      lds_i[wave][quad * 4 + r] = piA[r];
      lds_j[wave][quad * 4 + r] = pjA[r];
      lds_i[wave][16 + quad * 4 + r] = piB[r];
      lds_j[wave][16 + quad * 4 + r] = pjB[r];
    }
  }
  __syncthreads();
  int m = threadIdx.x;
  if (m < 96) {
    int h = m / 32, r = m % 32;
    int node = row_base + r;
    if (node < N) s_i[node * 3 + h] = lds_i[2 * h][r] + lds_i[2 * h + 1][r];
  } else if (m < 192) {
    int tt = m - 96;
    int h = tt / 32, r = tt % 32;
    int node = row_base + r;
    if (node < N) s_j[node * 3 + h] = lds_j[2 * h][r] + lds_j[2 * h + 1][r];
  }
}

// ------------------------------------------------------------------
// FOX: fused layer boundary. Phase 1: out = aggr @ euw + bias (+ELU),
// 16x128 bf16 tile kept in LDS. Phase 2: xh' = out @ W via MFMA with
// A-fragments read from LDS, + fused s_i/s_j (R7 body). Grid N/16,
// 384 threads (6 waves).
// ------------------------------------------------------------------
__global__ __launch_bounds__(384) void fox_kernel(
    const bf16* __restrict__ aggr, const bf16* __restrict__ euwT,
    const float* __restrict__ biasf, int do_elu,
    const bf16* __restrict__ WT, const float* __restrict__ attf,
    bf16* __restrict__ xh, float* __restrict__ s_i, float* __restrict__ s_j,
    int N) {
  __shared__ bf16 xtile[16][136];  // [m][k], row stride 272 B (16B-aligned)
  __shared__ float lds_i[6][16];
  __shared__ float lds_j[6][16];
  int wave = threadIdx.x >> 6, lane = threadIdx.x & 63;
  int quad = lane >> 4, r16 = lane & 15;
  int row_base = blockIdx.x * 16;
  int row = row_base + r16; if (row >= N) row = N - 1;

  // ---- phase 1: out tile (K=160) ----
  const short8* ap = (const short8*)(aggr + (size_t)row * 160 + quad * 8);
  short8 aa[5];
#pragma unroll
  for (int kk = 0; kk < 5; ++kk) aa[kk] = ap[kk * 4];
  for (int t = wave; t < 8; t += 6) {
    int col = t * 16 + r16;
    const short8* bp = (const short8*)(euwT + (size_t)col * 160 + quad * 8);
    f32x4 acc = {0.f, 0.f, 0.f, 0.f};
#pragma unroll
    for (int kk = 0; kk < 5; ++kk)
      acc = __builtin_amdgcn_mfma_f32_16x16x32_bf16(aa[kk], bp[kk * 4], acc, 0, 0, 0);
    float bv = biasf[col];
#pragma unroll
    for (int r = 0; r < 4; ++r) {
      float v = acc[r] + bv;
      if (do_elu) v = v > 0.0f ? v : expm1f(v);
      xtile[quad * 4 + r][col] = __float2bfloat16(v);
    }
  }
  __syncthreads();

  // ---- phase 2: xh' = xtile @ W (K=128), A from LDS ----
  short8 a[4];
#pragma unroll
  for (int kk = 0; kk < 4; ++kk)
    a[kk] = *(const short8*)(&xtile[r16][quad * 8 + kk * 32]);

  float pi_r[4] = {0.f, 0.f, 0.f, 0.f};
  float pj_r[4] = {0.f, 0.f, 0.f, 0.f};
#pragma unroll
  for (int j = 0; j < 4; ++j) {
    int col = wave * 64 + j * 16 + r16;
    const short8* bp = (const short8*)(WT + (size_t)col * 128 + quad * 8);
    f32x4 acc = {0.f, 0.f, 0.f, 0.f};
#pragma unroll
    for (int kk = 0; kk < 4; ++kk)
      acc = __builtin_amdgcn_mfma_f32_16x16x32_bf16(a[kk], bp[kk * 4], acc, 0, 0, 0);
    int h = col >> 7, fi = col & 127, pair = fi >> 1, sub = fi & 1;
    size_t base = (size_t)pair * 6 + h * 2 + sub;
#pragma unroll
    for (int r = 0; r < 4; ++r) {
      int node = row_base + quad * 4 + r;
      if (node < N) xh[(size_t)node * 384 + base] = __float2bfloat16(acc[r]);
    }
    float ai = attf[h * 288 + fi];
    float aj = attf[h * 288 + 128 + fi];
#pragma unroll
    for (int r = 0; r < 4; ++r) {
      pi_r[r] = fmaf(acc[r], ai, pi_r[r]);
      pj_r[r] = fmaf(acc[r], aj, pj_r[r]);
    }
  }
#pragma unroll
  for (int d = 1; d < 16; d <<= 1) {
#pragma unroll
    for (int r = 0; r < 4; ++r) {
      pi_r[r] += __shfl_xor(pi_r[r], d);
      pj_r[r] += __shfl_xor(pj_r[r], d);
    }
  }
  if (r16 == 0) {
#pragma unroll
    for (int r = 0; r < 4; ++r) {
      lds_i[wave][quad * 4 + r] = pi_r[r];
      lds_j[wave][quad * 4 + r] = pj_r[r];
    }
  }
  __syncthreads();
  int m = threadIdx.x;
  if (m < 48) {
    int h = m / 16, r = m % 16;
    int node = row_base + r;
    if (node < N) s_i[node * 3 + h] = lds_i[2 * h][r] + lds_i[2 * h + 1][r];
  } else if (m < 96) {
    int tt = m - 48;
    int h = tt / 16, r = tt % 16;
    int node = row_base + r;
    if (node < N) s_j[node * 3 + h] = lds_j[2 * h][r] + lds_j[2 * h + 1][r];
  }
}

// ------------------------------------------------------------------
// per-dst softmax + weighted aggregation -> bf16 aggr [N][160].
// 2 waves per node; partials combined via LDS. (R9, unchanged)
// ------------------------------------------------------------------
__global__ __launch_bounds__(256) void edge_aggr_kernel(
    const int* __restrict__ xh_i, const float* __restrict__ s_i,
    const float* __restrict__ s_j, const float* __restrict__ s_et,
    const float2* __restrict__ eef2, const int* __restrict__ row_ptr,
    const int* __restrict__ packed, unsigned* __restrict__ aggr_u,
    int N, int E) {
  __shared__ float lds[2][512];
  int wid = threadIdx.x >> 6, lane = threadIdx.x & 63;
  int nodeLocal = wid >> 1, w = wid & 1;
  int n0 = blockIdx.x * 2 + nodeLocal;
  int n = n0 < N ? n0 : N - 1;
  int start = row_ptr[n], end = row_ptr[n + 1];
  if (start < 0) start = 0;
  if (start > E) start = E;
  if (end < start) end = start;
  if (end > E) end = E;
  int deg = end - start;
  float si0 = s_i[n * 3 + 0], si1 = s_i[n * 3 + 1], si2 = s_i[n * 3 + 2];

  float p0r = 0.f, p1r = 0.f, p2r = 0.f;
  int pkr = 0;
  float dp0 = 0.0f, dp1 = 0.0f, dp2 = 0.0f;
  int slot = 2 * lane + w;
  if (slot < deg) {
    int p = packed[start + slot];
    int s = p & 0xFFFF; if (s >= N) s = N - 1;
    int t = (p >> 16) & 127; if (t > 64) t = 64;
    float a0 = si0 + s_j[s * 3 + 0] + s_et[t * 3 + 0];
    float a1 = si1 + s_j[s * 3 + 1] + s_et[t * 3 + 1];
    float a2 = si2 + s_j[s * 3 + 2] + s_et[t * 3 + 2];
    a0 = a0 > 0.0f ? a0 : 0.2f * a0;
    a1 = a1 > 0.0f ? a1 : 0.2f * a1;
    a2 = a2 > 0.0f ? a2 : 0.2f * a2;
    a0 = fminf(fmaxf(a0, -60.0f), 60.0f);
    a1 = fminf(fmaxf(a1, -60.0f), 60.0f);
    a2 = fminf(fmaxf(a2, -60.0f), 60.0f);
    p0r = __expf(a0); p1r = __expf(a1); p2r = __expf(a2);
    dp0 = p0r; dp1 = p1r; dp2 = p2r;
    pkr = s | (t << 16);
  }
#pragma unroll
  for (int d = 32; d > 0; d >>= 1) {
    dp0 += __shfl_xor(dp0, d);
    dp1 += __shfl_xor(dp1, d);
    dp2 += __shfl_xor(dp2, d);
  }
  float d0 = dp0, d1 = dp1, d2 = dp2;

  float2 ax0 = make_float2(0.f, 0.f), ax1 = ax0, ax2 = ax0;
  float2 ae0 = ax0, ae1 = ax0, ae2 = ax0;
  int capped = deg < 128 ? deg : 128;
  int cnt = (capped > w) ? ((capped - w + 1) >> 1) : 0;

  {
    int j = 0;
    for (; j + 2 <= cnt; j += 2) {
      int pkA = __shfl(pkr, j), pkB = __shfl(pkr, j + 1);
      float qA0 = __shfl(p0r, j), qB0 = __shfl(p0r, j + 1);
      float qA1 = __shfl(p1r, j), qB1 = __shfl(p1r, j + 1);
      float qA2 = __shfl(p2r, j), qB2 = __shfl(p2r, j + 1);
      int sA = pkA & 0xFFFF, tA = pkA >> 16;
      int sB = pkB & 0xFFFF, tB = pkB >> 16;
      const int* xpA = xh_i + (size_t)sA * 192 + lane * 3;
      const int* xpB = xh_i + (size_t)sB * 192 + lane * 3;
      int wA0 = xpA[0], wA1 = xpA[1], wA2 = xpA[2];
      int wB0 = xpB[0], wB1 = xpB[1], wB2 = xpB[2];
      float2 vA0 = i2f2(wA0), vA1 = i2f2(wA1), vA2 = i2f2(wA2);
      float2 vB0 = i2f2(wB0), vB1 = i2f2(wB1), vB2 = i2f2(wB2);
      ax0.x = fmaf(qA0, vA0.x, ax0.x); ax0.y = fmaf(qA0, vA0.y, ax0.y);
      ax1.x = fmaf(qA1, vA1.x, ax1.x); ax1.y = fmaf(qA1, vA1.y, ax1.y);
      ax2.x = fmaf(qA2, vA2.x, ax2.x); ax2.y = fmaf(qA2, vA2.y, ax2.y);
      ax0.x = fmaf(qB0, vB0.x, ax0.x); ax0.y = fmaf(qB0, vB0.y, ax0.y);
      ax1.x = fmaf(qB1, vB1.x, ax1.x); ax1.y = fmaf(qB1, vB1.y, ax1.y);
      ax2.x = fmaf(qB2, vB2.x, ax2.x); ax2.y = fmaf(qB2, vB2.y, ax2.y);
      if (lane < 16) {
        if (tA != 64) {
          float2 ev = eef2[tA * 16 + lane];
          ae0.x = fmaf(qA0, ev.x, ae0.x); ae0.y = fmaf(qA0, ev.y, ae0.y);
          ae1.x = fmaf(qA1, ev.x, ae1.x); ae1.y = fmaf(qA1, ev.y, ae1.y);
          ae2.x = fmaf(qA2, ev.x, ae2.x); ae2.y = fmaf(qA2, ev.y, ae2.y);
        }
        if (tB != 64) {
          float2 ev = eef2[tB * 16 + lane];
          ae0.x = fmaf(qB0, ev.x, ae0.x); ae0.y = fmaf(qB0, ev.y, ae0.y);
          ae1.x = fmaf(qB1, ev.x, ae1.x); ae1.y = fmaf(qB1, ev.y, ae1.y);
          ae2.x = fmaf(qB2, ev.x, ae2.x); ae2.y = fmaf(qB2, ev.y, ae2.y);
        }
      }
    }
    if (j < cnt) {
      int pkA = __shfl(pkr, j);
      float qA0 = __shfl(p0r, j), qA1 = __shfl(p1r, j), qA2 = __shfl(p2r, j);
      int sA = pkA & 0xFFFF, tA = pkA >> 16;
      const int* xpA = xh_i + (size_t)sA * 192 + lane * 3;
      int wA0 = xpA[0], wA1 = xpA[1], wA2 = xpA[2];
      float2 vA0 = i2f2(wA0), vA1 = i2f2(wA1), vA2 = i2f2(wA2);
      ax0.x = fmaf(qA0, vA0.x, ax0.x); ax0.y = fmaf(qA0, vA0.y, ax0.y);
      ax1.x = fmaf(qA1, vA1.x, ax1.x); ax1.y = fmaf(qA1, vA1.y, ax1.y);
      ax2.x = fmaf(qA2, vA2.x, ax2.x); ax2.y = fmaf(qA2, vA2.y, ax2.y);
      if (lane < 16 && tA != 64) {
        float2 ev = eef2[tA * 16 + lane];
        ae0.x = fmaf(qA0, ev.x, ae0.x); ae0.y = fmaf(qA0, ev.y, ae0.y);
        ae1.x = fmaf(qA1, ev.x, ae1.x); ae1.y = fmaf(qA1, ev.y, ae1.y);
        ae2.x = fmaf(qA2, ev.x, ae2.x); ae2.y = fmaf(qA2, ev.y, ae2.y);
      }
    }
  }

  if (w == 0) {
    for (int e = start + 128; e < end; ++e) {
      int p = packed[e];
      int s = p & 0xFFFF; if (s >= N) s = N - 1;
      int t = (p >> 16) & 127; if (t > 64) t = 64;
      float a0 = si0 + s_j[s * 3 + 0] + s_et[t * 3 + 0];
      float a1 = si1 + s_j[s * 3 + 1] + s_et[t * 3 + 1];
      float a2 = si2 + s_j[s * 3 + 2] + s_et[t * 3 + 2];
      a0 = a0 > 0.0f ? a0 : 0.2f * a0;
      a1 = a1 > 0.0f ? a1 : 0.2f * a1;
      a2 = a2 > 0.0f ? a2 : 0.2f * a2;
      a0 = fminf(fmaxf(a0, -60.0f), 60.0f);
      a1 = fminf(fmaxf(a1, -60.0f), 60.0f);
      a2 = fminf(fmaxf(a2, -60.0f), 60.0f);
      float p0 = __expf(a0), p1 = __expf(a1), p2 = __expf(a2);
      d0 += p0; d1 += p1; d2 += p2;
      const int* xp = xh_i + (size_t)s * 192 + lane * 3;
      float2 v0 = i2f2(xp[0]), v1 = i2f2(xp[1]), v2 = i2f2(xp[2]);
      ax0.x = fmaf(p0, v0.x, ax0.x); ax0.y = fmaf(p0, v0.y, ax0.y);
      ax1.x = fmaf(p1, v1.x, ax1.x); ax1.y = fmaf(p1, v1.y, ax1.y);
      ax2.x = fmaf(p2, v2.x, ax2.x); ax2.y = fmaf(p2, v2.y, ax2.y);
      if (t != 64 && lane < 16) {
        float2 ev = eef2[t * 16 + lane];
        ae0.x = fmaf(p0, ev.x, ae0.x); ae0.y = fmaf(p0, ev.y, ae0.y);
        ae1.x = fmaf(p1, ev.x, ae1.x); ae1.y = fmaf(p1, ev.y, ae1.y);
        ae2.x = fmaf(p2, ev.x, ae2.x); ae2.y = fmaf(p2, ev.y, ae2.y);
      }
    }
  }

  float* L = lds[nodeLocal];
  if (w == 1) {
    L[lane * 2 + 0] = ax0.x;       L[lane * 2 + 1] = ax0.y;
    L[128 + lane * 2 + 0] = ax1.x; L[128 + lane * 2 + 1] = ax1.y;
    L[256 + lane * 2 + 0] = ax2.x; L[256 + lane * 2 + 1] = ax2.y;
    if (lane < 16) {
      L[384 + lane * 2 + 0] = ae0.x; L[384 + lane * 2 + 1] = ae0.y;
      L[416 + lane * 2 + 0] = ae1.x; L[416 + lane * 2 + 1] = ae1.y;
      L[448 + lane * 2 + 0] = ae2.x; L[448 + lane * 2 + 1] = ae2.y;
    }
    if (lane == 0) { L[480] = d0; L[481] = d1; L[482] = d2; }
  }
  __syncthreads();
  if (w == 0 && n0 < N) {
    ax0.x += L[lane * 2 + 0];       ax0.y += L[lane * 2 + 1];
    ax1.x += L[128 + lane * 2 + 0]; ax1.y += L[128 + lane * 2 + 1];
    ax2.x += L[256 + lane * 2 + 0]; ax2.y += L[256 + lane * 2 + 1];
    if (lane < 16) {
      ae0.x += L[384 + lane * 2 + 0]; ae0.y += L[384 + lane * 2 + 1];
      ae1.x += L[416 + lane * 2 + 0]; ae1.y += L[416 + lane * 2 + 1];
      ae2.x += L[448 + lane * 2 + 0]; ae2.y += L[448 + lane * 2 + 1];
    }
    d0 += L[480]; d1 += L[481]; d2 += L[482];
    const float third = 1.0f / 3.0f;
    float i0 = third / fmaxf(d0, 1e-30f);
    float i1 = third / fmaxf(d1, 1e-30f);
    float i2 = third / fmaxf(d2, 1e-30f);
    aggr_u[(size_t)n0 * 80 + lane] =
        pk2(ax0.x * i0 + ax1.x * i1 + ax2.x * i2,
            ax0.y * i0 + ax1.y * i1 + ax2.y * i2);
    if (lane < 16)
      aggr_u[(size_t)n0 * 80 + 64 + lane] =
          pk2(ae0.x * i0 + ae1.x * i1 + ae2.x * i2,
              ae0.y * i0 + ae1.y * i1 + ae2.y * i2);
  }
}

// ------------------------------------------------------------------
// final layer: out = aggr @ euw + bias via MFMA, store d_out in
// detected dtype. Grid (N/16, 2), 4 waves/block.
// ------------------------------------------------------------------
__global__ __launch_bounds__(256) void gemm_out_mfma(
    const bf16* __restrict__ aggr, const bf16* __restrict__ euwT,
    const float* __restrict__ biasf, void* __restrict__ dout,
    const int* __restrict__ flag, int N) {
  int wave = threadIdx.x >> 6, lane = threadIdx.x & 63;
  int row_base = blockIdx.x * 16;
  int col_base = blockIdx.y * 64 + wave * 16;
  int quad = lane >> 4, r16 = lane & 15;
  int row = row_base + r16; if (row >= N) row = N - 1;
  int col = col_base + r16;
  f32x4 acc = {0.f, 0.f, 0.f, 0.f};
  const short8* ap = (const short8*)(aggr + (size_t)row * 160 + quad * 8);
  const short8* bp = (const short8*)(euwT + (size_t)col * 160 + quad * 8);
#pragma unroll
  for (int kk = 0; kk < 5; ++kk) {
    short8 a = ap[kk * 4];
    short8 b = bp[kk * 4];
    acc = __builtin_amdgcn_mfma_f32_16x16x32_bf16(a, b, acc, 0, 0, 0);
  }
  float bv = biasf[col];
  int f = *flag;
#pragma unroll
  for (int r = 0; r < 4; ++r) {
    int node = row_base + quad * 4 + r;
    if (node < N) {
      float v = acc[r] + bv;
      if (f) ((float*)dout)[(size_t)node * 128 + col] = v;
      else   ((bf16*)dout)[(size_t)node * 128 + col] = __float2bfloat16(v);
    }
  }
}

// ------------------------------------------------------------------
extern "C" void kernel_launch(void* const* d_in, const int* in_sizes, int n_in,
                              void* d_out, int out_size, void* d_ws, size_t ws_size,
                              hipStream_t stream) {
  const int* x_idx = (const int*)d_in[0];
  const int* edge_index = (const int*)d_in[1];
  const int* edge_attr_idx = (const int*)d_in[2];

  int N = in_sizes[0];
  int E0 = in_sizes[1] / 2;
  int E = E0 + N;
  const int* src = edge_index;
  const int* dst = edge_index + E0;

  // ---- workspace carve (~12.2 MB) ----
  size_t off = 0;
  char* base = (char*)d_ws;
  auto carve = [&](size_t bytes) -> void* {
    void* p = base + off;
    off += (bytes + 255) & ~(size_t)255;
    return p;
  };
  int* flag     = (int*)carve(256);
  int* counts   = (int*)carve((size_t)N * 4);    // becomes cursor after scan
  int* row_ptr  = (int*)carve((size_t)(N + 1) * 4);
  int* packed   = (int*)carve((size_t)E * 4);
  float* s_i    = (float*)carve((size_t)N * 3 * 4);
  float* s_j    = (float*)carve((size_t)N * 3 * 4);
  float* s_et   = (float*)carve(2 * 65 * 3 * 4);
  float* eef    = (float*)carve(2048 * 4);
  float* att1f  = (float*)carve(864 * 4);
  float* att2f  = (float*)carve(864 * 4);
  float* b1f    = (float*)carve(128 * 4);
  float* b2f_   = (float*)carve(128 * 4);
  bf16* WT1     = (bf16*)carve(49152 * 2);
  bf16* WT2     = (bf16*)carve(49152 * 2);
  bf16* euT1    = (bf16*)carve(20480 * 2);
  bf16* euT2    = (bf16*)carve(20480 * 2);
  bf16* xh      = (bf16*)carve((size_t)N * 384 * 2 + 64);
  bf16* aggr    = (bf16*)carve((size_t)N * 160 * 2);
  bf16* xb      = (bf16*)d_out;  // bf16 x0 lives in d_out
  (void)n_in; (void)out_size; (void)ws_size;

  // ---- setup: 4 dispatches ----
  wconv_kernel<<<(143296 + N + 255) / 256, 256, 0, stream>>>(
      d_in[4], d_in[5], d_in[6], d_in[7], d_in[8], d_in[9], d_in[10], d_in[11],
      d_in[12], flag, eef, att1f, att2f, b1f, b2f_, WT1, WT2, euT1, euT2,
      s_et, counts, N);
  int nb4 = (N + 3) / 4;
  prep_kernel<<<nb4, 256, 0, stream>>>(x_idx, d_in[3], flag, xb, counts, dst,
                                       E0, N);
  scan_kernel<<<1, 1024, 0, stream>>>(counts, row_ptr, N);
  scatter_kernel<<<(E + 255) / 256, 256, 0, stream>>>(src, dst, edge_attr_idx,
                                                      counts, packed, E0, N);

  int nrb16 = (N + 15) / 16;
  int nrb32 = (N + 31) / 32;
  int nb2 = (N + 1) / 2;

  // layer (0,0): W1/att1
  gemm_xh_s_mfma<<<nrb32, 384, 0, stream>>>(xb, WT1, att1f, xh, s_i, s_j, N);
  edge_aggr_kernel<<<nb2, 256, 0, stream>>>(
      (const int*)xh, s_i, s_j, s_et, (const float2*)eef,
      row_ptr, packed, (unsigned*)aggr, N, E);
  // boundary (0,0)->(0,1): euw1+b1+ELU, then W2/att2
  fox_kernel<<<nrb16, 384, 0, stream>>>(aggr, euT1, b1f, 1, WT2, att2f,
                                        xh, s_i, s_j, N);
  edge_aggr_kernel<<<nb2, 256, 0, stream>>>(
      (const int*)xh, s_i, s_j, s_et + 195, (const float2*)eef,
      row_ptr, packed, (unsigned*)aggr, N, E);
  // boundary (0,1)->(1,0): euw2+b2 (no ELU), then W1/att1
  fox_kernel<<<nrb16, 384, 0, stream>>>(aggr, euT2, b2f_, 0, WT1, att1f,
                                        xh, s_i, s_j, N);
  edge_aggr_kernel<<<nb2, 256, 0, stream>>>(
      (const int*)xh, s_i, s_j, s_et, (const float2*)eef,
      row_ptr, packed, (unsigned*)aggr, N, E);
  // boundary (1,0)->(1,1): euw1+b1+ELU, then W2/att2
  fox_kernel<<<nrb16, 384, 0, stream>>>(aggr, euT1, b1f, 1, WT2, att2f,
                                        xh, s_i, s_j, N);
  edge_aggr_kernel<<<nb2, 256, 0, stream>>>(
      (const int*)xh, s_i, s_j, s_et + 195, (const float2*)eef,
      row_ptr, packed, (unsigned*)aggr, N, E);
  // final: euw2+b2, store d_out
  gemm_out_mfma<<<dim3(nrb16, 2), 256, 0, stream>>>(aggr, euT2, b2f_,
                                                    d_out, flag, N);
}

// Round 11
// 315.798 us; speedup vs baseline: 1.9105x; 1.0068x over previous
//
#include <hip/hip_runtime.h>
#include <hip/hip_bf16.h>

typedef __hip_bfloat16 bf16;
typedef __attribute__((ext_vector_type(8))) short short8;
typedef __attribute__((ext_vector_type(4))) float f32x4;
typedef __attribute__((ext_vector_type(4), aligned(4))) int i32x4u;
typedef __attribute__((ext_vector_type(4))) int i32x4;

__device__ __forceinline__ float b2f(bf16 v) { return __bfloat162float(v); }
// int (2 packed bf16) -> two floats. x = low half, y = high half.
__device__ __forceinline__ float2 i2f2(int w) {
  float lo = __uint_as_float(((unsigned)w) << 16);
  float hi = __uint_as_float(((unsigned)w) & 0xFFFF0000u);
  return make_float2(lo, hi);
}
// float -> bf16 bits (RNE; inputs finite)
__device__ __forceinline__ unsigned f2bfb(float f) {
  unsigned u = __float_as_uint(f);
  unsigned r = 0x7FFFu + ((u >> 16) & 1u);
  return (u + r) >> 16;
}
__device__ __forceinline__ unsigned pk2(float a, float b) {
  return f2bfb(a) | (f2bfb(b) << 16);
}
__device__ __forceinline__ float ldv(const void* p, int i, int f) {
  return f ? ((const float*)p)[i] : b2f(((const bf16*)p)[i]);
}

#define SH 392  // stage row stride in halfs (384 + 8 pad, 16B-aligned)

// ------------------------------------------------------------------
// weight materialization + per-block dtype detect + counts zero;
// block 0 computes s_et and publishes flag.
// ------------------------------------------------------------------
__global__ __launch_bounds__(256) void wconv_kernel(
    const void* __restrict__ ee, const void* __restrict__ w1,
    const void* __restrict__ a1, const void* __restrict__ eu1,
    const void* __restrict__ b1, const void* __restrict__ w2,
    const void* __restrict__ a2, const void* __restrict__ eu2,
    const void* __restrict__ b2, int* __restrict__ flag,
    float* __restrict__ eef, float* __restrict__ att1f, float* __restrict__ att2f,
    float* __restrict__ b1f, float* __restrict__ b2f,
    bf16* __restrict__ WT1, bf16* __restrict__ WT2,
    bf16* __restrict__ euT1, bf16* __restrict__ euT2,
    float* __restrict__ s_et, int* __restrict__ counts, int N) {
  __shared__ int cnt;
  __shared__ int fl;
  if (threadIdx.x == 0) cnt = 0;
  __syncthreads();
  const unsigned short* probe = (const unsigned short*)w1;
  int local = 0;
#pragma unroll
  for (int k = 0; k < 8; ++k) {
    int e = (probe[threadIdx.x * 8 + k] >> 7) & 0xFF;
    if (e >= 160) local++;
  }
  if (local) atomicAdd(&cnt, local);
  __syncthreads();
  if (threadIdx.x == 0) {
    fl = (cnt > 16) ? 1 : 0;
    if (blockIdx.x == 0) *flag = fl;
  }
  __syncthreads();
  int f = fl;

  int i = blockIdx.x * 256 + threadIdx.x;
  if (i < 2048) {
    eef[i] = ldv(ee, i, f);
  } else if (i < 2912) {
    att1f[i - 2048] = ldv(a1, i - 2048, f);
  } else if (i < 3776) {
    att2f[i - 2912] = ldv(a2, i - 2912, f);
  } else if (i < 3904) {
    b1f[i - 3776] = ldv(b1, i - 3776, f);
  } else if (i < 4032) {
    b2f[i - 3904] = ldv(b2, i - 3904, f);
  } else if (i < 53184) {
    int j = i - 4032; int c = j >> 7, k = j & 127;
    WT1[j] = __float2bfloat16(ldv(w1, k * 384 + c, f));
  } else if (i < 102336) {
    int j = i - 53184; int c = j >> 7, k = j & 127;
    WT2[j] = __float2bfloat16(ldv(w2, k * 384 + c, f));
  } else if (i < 122816) {
    int j = i - 102336; int c = j / 160, k = j % 160;
    euT1[j] = __float2bfloat16(ldv(eu1, k * 128 + c, f));
  } else if (i < 143296) {
    int j = i - 122816; int c = j / 160, k = j % 160;
    euT2[j] = __float2bfloat16(ldv(eu2, k * 128 + c, f));
  } else if (i < 143296 + N) {
    counts[i - 143296] = 0;
  }

  if (blockIdx.x == 0) {
    for (int id = threadIdx.x; id < 2 * 65 * 3; id += 256) {
      int l = id / (65 * 3);
      int r = id % (65 * 3);
      int t = r / 3, h = r % 3;
      const void* att = l ? a2 : a1;
      float s = 0.0f;
      if (t < 64) {
        for (int d = 0; d < 32; ++d)
          s += ldv(ee, t * 32 + d, f) * ldv(att, h * 288 + 256 + d, f);
      }
      s_et[id] = s;
    }
  }
}

// ------------------------------------------------------------------
// prep: x0 = maxnorm(node_emb[x_idx]) -> bf16 x (in d_out);
// + edge counting (grid-stride). counts pre-zeroed by wconv.
// ------------------------------------------------------------------
__global__ __launch_bounds__(256) void prep_kernel(
    const int* __restrict__ x_idx, const void* __restrict__ node_emb,
    const int* __restrict__ flag, bf16* __restrict__ xb,
    int* __restrict__ counts, const int* __restrict__ dst, int E0, int N) {
  int wid = threadIdx.x >> 6, lane = threadIdx.x & 63;
  int n = blockIdx.x * 4 + wid;
  if (n < N) {
    int idx = x_idx[n];
    if ((unsigned)idx >= (unsigned)N) idx = 0;
    float v0, v1;
    if (*flag) {
      const float* er = (const float*)node_emb + (size_t)idx * 128;
      v0 = er[lane]; v1 = er[lane + 64];
    } else {
      const bf16* er = (const bf16*)node_emb + (size_t)idx * 128;
      v0 = b2f(er[lane]); v1 = b2f(er[lane + 64]);
    }
    float ss = v0 * v0 + v1 * v1;
#pragma unroll
    for (int d = 32; d > 0; d >>= 1) ss += __shfl_xor(ss, d);
    float norm = sqrtf(ss);
    float scale = norm > 1.0f ? 1.0f / norm : 1.0f;
    xb[(size_t)n * 128 + lane] = __float2bfloat16(v0 * scale);
    xb[(size_t)n * 128 + 64 + lane] = __float2bfloat16(v1 * scale);
  }
  int gid = blockIdx.x * 256 + threadIdx.x;
  int stride = gridDim.x * 256;
  for (int i = gid; i < E0; i += stride) {
    int d = dst[i];
    if ((unsigned)d >= (unsigned)N) d = 0;
    atomicAdd(&counts[d], 1);
  }
}

// ------------------------------------------------------------------
// parallel exclusive scan with +1 per row (self loop), one block of
// 1024 threads (16 waves). counts becomes cursor in place.
// ------------------------------------------------------------------
__global__ __launch_bounds__(1024) void scan_kernel(
    int* __restrict__ counts, int* __restrict__ row_ptr, int N) {
  __shared__ int wsum[16];
  int t = threadIdx.x;
  int chunk = (N + 1023) >> 10;
  int lo = t * chunk;
  int hi = lo + chunk;
  if (lo > N) lo = N;
  if (hi > N) hi = N;
  int s = 0;
  for (int i = lo; i < hi; ++i) s += counts[i] + 1;
  int lane = t & 63, wv = t >> 6;
  int incl = s;
#pragma unroll
  for (int d = 1; d < 64; d <<= 1) {
    int u = __shfl_up(incl, d);
    if (lane >= d) incl += u;
  }
  if (lane == 63) wsum[wv] = incl;
  __syncthreads();
  if (t == 0) {
    int run = 0;
#pragma unroll
    for (int w = 0; w < 16; ++w) { int c = wsum[w]; wsum[w] = run; run += c; }
  }
  __syncthreads();
  int run = incl - s + wsum[wv];  // exclusive prefix for this thread
  for (int i = lo; i < hi; ++i) {
    int c = counts[i] + 1;
    row_ptr[i] = run;
    counts[i] = run;
    run += c;
  }
  if (t == 1023) row_ptr[N] = run;
}

// ------------------------------------------------------------------
// scatter edges (+self loops, etype=64) into CSR: packed = src | et<<16
// ------------------------------------------------------------------
__global__ __launch_bounds__(256) void scatter_kernel(
    const int* __restrict__ src, const int* __restrict__ dst,
    const int* __restrict__ et, int* __restrict__ cursor,
    int* __restrict__ packed, int E0, int N) {
  int E = E0 + N;
  int i = blockIdx.x * blockDim.x + threadIdx.x;
  if (i < E0) {
    int d = dst[i];
    if ((unsigned)d >= (unsigned)N) d = 0;
    int p = atomicAdd(&cursor[d], 1);
    if ((unsigned)p >= (unsigned)E) p = 0;
    int t = et[i] & 63;
    packed[p] = (src[i] & 0xFFFF) | (t << 16);
  } else if (i < E) {
    int n = i - E0;
    int p = atomicAdd(&cursor[n], 1);
    if ((unsigned)p >= (unsigned)E) p = 0;
    packed[p] = (n & 0xFFFF) | (64 << 16);
  }
}

// ------------------------------------------------------------------
// xh = x @ W via MFMA + fused s_i/s_j (layer 0; x = bf16 in d_out).
// Block = 6 waves (384 thr), 32 rows x 384 cols. Grid: N/32.
// xh permuted (half-index = node*384 + pair*6 + head*2 + sub) staged
// in LDS, written out as contiguous 16B chunks.
// ------------------------------------------------------------------
__global__ __launch_bounds__(384) void gemm_xh_s_mfma(
    const bf16* __restrict__ x, const bf16* __restrict__ WT,
    const float* __restrict__ attf, bf16* __restrict__ xh,
    float* __restrict__ s_i, float* __restrict__ s_j, int N) {
  __shared__ bf16 stage[32 * SH];
  __shared__ float lds_i[6][32];
  __shared__ float lds_j[6][32];
  int wave = threadIdx.x >> 6, lane = threadIdx.x & 63;
  int row_base = blockIdx.x * 32;
  int quad = lane >> 4, r16 = lane & 15;
  int rowA = row_base + r16;      if (rowA >= N) rowA = N - 1;
  int rowB = row_base + 16 + r16; if (rowB >= N) rowB = N - 1;
  const short8* apA = (const short8*)(x + (size_t)rowA * 128 + quad * 8);
  const short8* apB = (const short8*)(x + (size_t)rowB * 128 + quad * 8);
  short8 aA[4], aB[4];
#pragma unroll
  for (int kk = 0; kk < 4; ++kk) { aA[kk] = apA[kk * 4]; aB[kk] = apB[kk * 4]; }

  float piA[4] = {0.f, 0.f, 0.f, 0.f}, pjA[4] = {0.f, 0.f, 0.f, 0.f};
  float piB[4] = {0.f, 0.f, 0.f, 0.f}, pjB[4] = {0.f, 0.f, 0.f, 0.f};
#pragma unroll
  for (int j = 0; j < 4; ++j) {
    int col = wave * 64 + j * 16 + r16;
    const short8* bp = (const short8*)(WT + (size_t)col * 128 + quad * 8);
    short8 b[4];
#pragma unroll
    for (int kk = 0; kk < 4; ++kk) b[kk] = bp[kk * 4];
    f32x4 accA = {0.f, 0.f, 0.f, 0.f};
    f32x4 accB = {0.f, 0.f, 0.f, 0.f};
#pragma unroll
    for (int kk = 0; kk < 4; ++kk) {
      accA = __builtin_amdgcn_mfma_f32_16x16x32_bf16(aA[kk], b[kk], accA, 0, 0, 0);
      accB = __builtin_amdgcn_mfma_f32_16x16x32_bf16(aB[kk], b[kk], accB, 0, 0, 0);
    }
    int h = col >> 7, fi = col & 127, pair = fi >> 1, sub = fi & 1;
    int base = pair * 6 + h * 2 + sub;
#pragma unroll
    for (int r = 0; r < 4; ++r) {
      stage[(quad * 4 + r) * SH + base] = __float2bfloat16(accA[r]);
      stage[(16 + quad * 4 + r) * SH + base] = __float2bfloat16(accB[r]);
    }
    float ai = attf[h * 288 + fi];
    float aj = attf[h * 288 + 128 + fi];
#pragma unroll
    for (int r = 0; r < 4; ++r) {
      piA[r] = fmaf(accA[r], ai, piA[r]);
      pjA[r] = fmaf(accA[r], aj, pjA[r]);
      piB[r] = fmaf(accB[r], ai, piB[r]);
      pjB[r] = fmaf(accB[r], aj, pjB[r]);
    }
  }
#pragma unroll
  for (int d = 1; d < 16; d <<= 1) {
#pragma unroll
    for (int r = 0; r < 4; ++r) {
      piA[r] += __shfl_xor(piA[r], d);
      pjA[r] += __shfl_xor(pjA[r], d);
      piB[r] += __shfl_xor(piB[r], d);
      pjB[r] += __shfl_xor(pjB[r], d);
    }
  }
  if (r16 == 0) {
#pragma unroll
    for (int r = 0; r < 4; ++r) {
      lds_i[wave][quad * 4 + r] = piA[r];
      lds_j[wave][quad * 4 + r] = pjA[r];
      lds_i[wave][16 + quad * 4 + r] = piB[r];
      lds_j[wave][16 + quad * 4 + r] = pjB[r];
    }
  }
  __syncthreads();
  int m = threadIdx.x;
  if (m < 96) {
    int h = m / 32, r = m % 32;
    int node = row_base + r;
    if (node < N) s_i[node * 3 + h] = lds_i[2 * h][r] + lds_i[2 * h + 1][r];
  } else if (m < 192) {
    int tt = m - 96;
    int h = tt / 32, r = tt % 32;
    int node = row_base + r;
    if (node < N) s_j[node * 3 + h] = lds_j[2 * h][r] + lds_j[2 * h + 1][r];
  }
  // contiguous copy-out: 32 rows x 48 chunks of 16B
#pragma unroll
  for (int k = 0; k < 4; ++k) {
    int c = threadIdx.x + k * 384;
    int r = c / 48, o = c % 48;
    int node = row_base + r;
    if (node < N)
      *(i32x4*)(xh + (size_t)node * 384 + o * 8) =
          *(const i32x4*)(stage + r * SH + o * 8);
  }
}

// ------------------------------------------------------------------
// FOX: fused layer boundary. Phase 1: out = aggr @ euw + bias (+ELU),
// 16x128 bf16 tile in LDS. Phase 2: xh' = out @ W via MFMA (A from
// LDS) + fused s_i/s_j; xh' staged in LDS, contiguous copy-out.
// Grid N/16, 384 threads.
// ------------------------------------------------------------------
__global__ __launch_bounds__(384) void fox_kernel(
    const bf16* __restrict__ aggr, const bf16* __restrict__ euwT,
    const float* __restrict__ biasf, int do_elu,
    const bf16* __restrict__ WT, const float* __restrict__ attf,
    bf16* __restrict__ xh, float* __restrict__ s_i, float* __restrict__ s_j,
    int N) {
  __shared__ bf16 xtile[16][136];  // [m][k], row stride 272 B
  __shared__ bf16 stage[16 * SH];
  __shared__ float lds_i[6][16];
  __shared__ float lds_j[6][16];
  int wave = threadIdx.x >> 6, lane = threadIdx.x & 63;
  int quad = lane >> 4, r16 = lane & 15;
  int row_base = blockIdx.x * 16;
  int row = row_base + r16; if (row >= N) row = N - 1;

  // ---- phase 1: out tile (K=160) ----
  const short8* ap = (const short8*)(aggr + (size_t)row * 160 + quad * 8);
  short8 aa[5];
#pragma unroll
  for (int kk = 0; kk < 5; ++kk) aa[kk] = ap[kk * 4];
  for (int t = wave; t < 8; t += 6) {
    int col = t * 16 + r16;
    const short8* bp = (const short8*)(euwT + (size_t)col * 160 + quad * 8);
    f32x4 acc = {0.f, 0.f, 0.f, 0.f};
#pragma unroll
    for (int kk = 0; kk < 5; ++kk)
      acc = __builtin_amdgcn_mfma_f32_16x16x32_bf16(aa[kk], bp[kk * 4], acc, 0, 0, 0);
    float bv = biasf[col];
#pragma unroll
    for (int r = 0; r < 4; ++r) {
      float v = acc[r] + bv;
      if (do_elu) v = v > 0.0f ? v : expm1f(v);
      xtile[quad * 4 + r][col] = __float2bfloat16(v);
    }
  }
  __syncthreads();

  // ---- phase 2: xh' = xtile @ W (K=128), A from LDS ----
  short8 a[4];
#pragma unroll
  for (int kk = 0; kk < 4; ++kk)
    a[kk] = *(const short8*)(&xtile[r16][quad * 8 + kk * 32]);

  float pi_r[4] = {0.f, 0.f, 0.f, 0.f};
  float pj_r[4] = {0.f, 0.f, 0.f, 0.f};
#pragma unroll
  for (int j = 0; j < 4; ++j) {
    int col = wave * 64 + j * 16 + r16;
    const short8* bp = (const short8*)(WT + (size_t)col * 128 + quad * 8);
    f32x4 acc = {0.f, 0.f, 0.f, 0.f};
#pragma unroll
    for (int kk = 0; kk < 4; ++kk)
      acc = __builtin_amdgcn_mfma_f32_16x16x32_bf16(a[kk], bp[kk * 4], acc, 0, 0, 0);
    int h = col >> 7, fi = col & 127, pair = fi >> 1, sub = fi & 1;
    int base = pair * 6 + h * 2 + sub;
#pragma unroll
    for (int r = 0; r < 4; ++r)
      stage[(quad * 4 + r) * SH + base] = __float2bfloat16(acc[r]);
    float ai = attf[h * 288 + fi];
    float aj = attf[h * 288 + 128 + fi];
#pragma unroll
    for (int r = 0; r < 4; ++r) {
      pi_r[r] = fmaf(acc[r], ai, pi_r[r]);
      pj_r[r] = fmaf(acc[r], aj, pj_r[r]);
    }
  }
#pragma unroll
  for (int d = 1; d < 16; d <<= 1) {
#pragma unroll
    for (int r = 0; r < 4; ++r) {
      pi_r[r] += __shfl_xor(pi_r[r], d);
      pj_r[r] += __shfl_xor(pj_r[r], d);
    }
  }
  if (r16 == 0) {
#pragma unroll
    for (int r = 0; r < 4; ++r) {
      lds_i[wave][quad * 4 + r] = pi_r[r];
      lds_j[wave][quad * 4 + r] = pj_r[r];
    }
  }
  __syncthreads();
  int m = threadIdx.x;
  if (m < 48) {
    int h = m / 16, r = m % 16;
    int node = row_base + r;
    if (node < N) s_i[node * 3 + h] = lds_i[2 * h][r] + lds_i[2 * h + 1][r];
  } else if (m < 96) {
    int tt = m - 48;
    int h = tt / 16, r = tt % 16;
    int node = row_base + r;
    if (node < N) s_j[node * 3 + h] = lds_j[2 * h][r] + lds_j[2 * h + 1][r];
  }
  // contiguous copy-out: 16 rows x 48 chunks of 16B
#pragma unroll
  for (int k = 0; k < 2; ++k) {
    int c = threadIdx.x + k * 384;
    int r = c / 48, o = c % 48;
    int node = row_base + r;
    if (node < N)
      *(i32x4*)(xh + (size_t)node * 384 + o * 8) =
          *(const i32x4*)(stage + r * SH + o * 8);
  }
}

// ------------------------------------------------------------------
// per-dst softmax + weighted aggregation -> bf16 aggr [N][160].
// 2 waves per node; partials combined via LDS. Per-edge gather is a
// single dwordx4 (12B used + 4B overlap).
// ------------------------------------------------------------------
__global__ __launch_bounds__(256) void edge_aggr_kernel(
    const int* __restrict__ xh_i, const float* __restrict__ s_i,
    const float* __restrict__ s_j, const float* __restrict__ s_et,
    const float2* __restrict__ eef2, const int* __restrict__ row_ptr,
    const int* __restrict__ packed, unsigned* __restrict__ aggr_u,
    int N, int E) {
  __shared__ float lds[2][512];
  int wid = threadIdx.x >> 6, lane = threadIdx.x & 63;
  int nodeLocal = wid >> 1, w = wid & 1;
  int n0 = blockIdx.x * 2 + nodeLocal;
  int n = n0 < N ? n0 : N - 1;
  int start = row_ptr[n], end = row_ptr[n + 1];
  if (start < 0) start = 0;
  if (start > E) start = E;
  if (end < start) end = start;
  if (end > E) end = E;
  int deg = end - start;
  float si0 = s_i[n * 3 + 0], si1 = s_i[n * 3 + 1], si2 = s_i[n * 3 + 2];

  float p0r = 0.f, p1r = 0.f, p2r = 0.f;
  int pkr = 0;
  float dp0 = 0.0f, dp1 = 0.0f, dp2 = 0.0f;
  int slot = 2 * lane + w;
  if (slot < deg) {
    int p = packed[start + slot];
    int s = p & 0xFFFF; if (s >= N) s = N - 1;
    int t = (p >> 16) & 127; if (t > 64) t = 64;
    float a0 = si0 + s_j[s * 3 + 0] + s_et[t * 3 + 0];
    float a1 = si1 + s_j[s * 3 + 1] + s_et[t * 3 + 1];
    float a2 = si2 + s_j[s * 3 + 2] + s_et[t * 3 + 2];
    a0 = a0 > 0.0f ? a0 : 0.2f * a0;
    a1 = a1 > 0.0f ? a1 : 0.2f * a1;
    a2 = a2 > 0.0f ? a2 : 0.2f * a2;
    a0 = fminf(fmaxf(a0, -60.0f), 60.0f);
    a1 = fminf(fmaxf(a1, -60.0f), 60.0f);
    a2 = fminf(fmaxf(a2, -60.0f), 60.0f);
    p0r = __expf(a0); p1r = __expf(a1); p2r = __expf(a2);
    dp0 = p0r; dp1 = p1r; dp2 = p2r;
    pkr = s | (t << 16);
  }
#pragma unroll
  for (int d = 32; d > 0; d >>= 1) {
    dp0 += __shfl_xor(dp0, d);
    dp1 += __shfl_xor(dp1, d);
    dp2 += __shfl_xor(dp2, d);
  }
  float d0 = dp0, d1 = dp1, d2 = dp2;

  float2 ax0 = make_float2(0.f, 0.f), ax1 = ax0, ax2 = ax0;
  float2 ae0 = ax0, ae1 = ax0, ae2 = ax0;
  int capped = deg < 128 ? deg : 128;
  int cnt = (capped > w) ? ((capped - w + 1) >> 1) : 0;

  {
    int j = 0;
    for (; j + 2 <= cnt; j += 2) {
      int pkA = __shfl(pkr, j), pkB = __shfl(pkr, j + 1);
      float qA0 = __shfl(p0r, j), qB0 = __shfl(p0r, j + 1);
      float qA1 = __shfl(p1r, j), qB1 = __shfl(p1r, j + 1);
      float qA2 = __shfl(p2r, j), qB2 = __shfl(p2r, j + 1);
      int sA = pkA & 0xFFFF, tA = pkA >> 16;
      int sB = pkB & 0xFFFF, tB = pkB >> 16;
      i32x4u qA = *(const i32x4u*)(xh_i + (size_t)sA * 192 + lane * 3);
      i32x4u qB = *(const i32x4u*)(xh_i + (size_t)sB * 192 + lane * 3);
      float2 vA0 = i2f2(qA.x), vA1 = i2f2(qA.y), vA2 = i2f2(qA.z);
      float2 vB0 = i2f2(qB.x), vB1 = i2f2(qB.y), vB2 = i2f2(qB.z);
      ax0.x = fmaf(qA0, vA0.x, ax0.x); ax0.y = fmaf(qA0, vA0.y, ax0.y);
      ax1.x = fmaf(qA1, vA1.x, ax1.x); ax1.y = fmaf(qA1, vA1.y, ax1.y);
      ax2.x = fmaf(qA2, vA2.x, ax2.x); ax2.y = fmaf(qA2, vA2.y, ax2.y);
      ax0.x = fmaf(qB0, vB0.x, ax0.x); ax0.y = fmaf(qB0, vB0.y, ax0.y);
      ax1.x = fmaf(qB1, vB1.x, ax1.x); ax1.y = fmaf(qB1, vB1.y, ax1.y);
      ax2.x = fmaf(qB2, vB2.x, ax2.x); ax2.y = fmaf(qB2, vB2.y, ax2.y);
      if (lane < 16) {
        if (tA != 64) {
          float2 ev = eef2[tA * 16 + lane];
          ae0.x = fmaf(qA0, ev.x, ae0.x); ae0.y = fmaf(qA0, ev.y, ae0.y);
          ae1.x = fmaf(qA1, ev.x, ae1.x); ae1.y = fmaf(qA1, ev.y, ae1.y);
          ae2.x = fmaf(qA2, ev.x, ae2.x); ae2.y = fmaf(qA2, ev.y, ae2.y);
        }
        if (tB != 64) {
          float2 ev = eef2[tB * 16 + lane];
          ae0.x = fmaf(qB0, ev.x, ae0.x); ae0.y = fmaf(qB0, ev.y, ae0.y);
          ae1.x = fmaf(qB1, ev.x, ae1.x); ae1.y = fmaf(qB1, ev.y, ae1.y);
          ae2.x = fmaf(qB2, ev.x, ae2.x); ae2.y = fmaf(qB2, ev.y, ae2.y);
        }
      }
    }
    if (j < cnt) {
      int pkA = __shfl(pkr, j);
      float qA0 = __shfl(p0r, j), qA1 = __shfl(p1r, j), qA2 = __shfl(p2r, j);
      int sA = pkA & 0xFFFF, tA = pkA >> 16;
      i32x4u qA = *(const i32x4u*)(xh_i + (size_t)sA * 192 + lane * 3);
      float2 vA0 = i2f2(qA.x), vA1 = i2f2(qA.y), vA2 = i2f2(qA.z);
      ax0.x = fmaf(qA0, vA0.x, ax0.x); ax0.y = fmaf(qA0, vA0.y, ax0.y);
      ax1.x = fmaf(qA1, vA1.x, ax1.x); ax1.y = fmaf(qA1, vA1.y, ax1.y);
      ax2.x = fmaf(qA2, vA2.x, ax2.x); ax2.y = fmaf(qA2, vA2.y, ax2.y);
      if (lane < 16 && tA != 64) {
        float2 ev = eef2[tA * 16 + lane];
        ae0.x = fmaf(qA0, ev.x, ae0.x); ae0.y = fmaf(qA0, ev.y, ae0.y);
        ae1.x = fmaf(qA1, ev.x, ae1.x); ae1.y = fmaf(qA1, ev.y, ae1.y);
        ae2.x = fmaf(qA2, ev.x, ae2.x); ae2.y = fmaf(qA2, ev.y, ae2.y);
      }
    }
  }

  if (w == 0) {
    for (int e = start + 128; e < end; ++e) {
      int p = packed[e];
      int s = p & 0xFFFF; if (s >= N) s = N - 1;
      int t = (p >> 16) & 127; if (t > 64) t = 64;
      float a0 = si0 + s_j[s * 3 + 0] + s_et[t * 3 + 0];
      float a1 = si1 + s_j[s * 3 + 1] + s_et[t * 3 + 1];
      float a2 = si2 + s_j[s * 3 + 2] + s_et[t * 3 + 2];
      a0 = a0 > 0.0f ? a0 : 0.2f * a0;
      a1 = a1 > 0.0f ? a1 : 0.2f * a1;
      a2 = a2 > 0.0f ? a2 : 0.2f * a2;
      a0 = fminf(fmaxf(a0, -60.0f), 60.0f);
      a1 = fminf(fmaxf(a1, -60.0f), 60.0f);
      a2 = fminf(fmaxf(a2, -60.0f), 60.0f);
      float p0 = __expf(a0), p1 = __expf(a1), p2 = __expf(a2);
      d0 += p0; d1 += p1; d2 += p2;
      i32x4u q = *(const i32x4u*)(xh_i + (size_t)s * 192 + lane * 3);
      float2 v0 = i2f2(q.x), v1 = i2f2(q.y), v2 = i2f2(q.z);
      ax0.x = fmaf(p0, v0.x, ax0.x); ax0.y = fmaf(p0, v0.y, ax0.y);
      ax1.x = fmaf(p1, v1.x, ax1.x); ax1.y = fmaf(p1, v1.y, ax1.y);
      ax2.x = fmaf(p2, v2.x, ax2.x); ax2.y = fmaf(p2, v2.y, ax2.y);
      if (t != 64 && lane < 16) {
        float2 ev = eef2[t * 16 + lane];
        ae0.x = fmaf(p0, ev.x, ae0.x); ae0.y = fmaf(p0, ev.y, ae0.y);
        ae1.x = fmaf(p1, ev.x, ae1.x); ae1.y = fmaf(p1, ev.y, ae1.y);
        ae2.x = fmaf(p2, ev.x, ae2.x); ae2.y = fmaf(p2, ev.y, ae2.y);
      }
    }
  }

  float* L = lds[nodeLocal];
  if (w == 1) {
    L[lane * 2 + 0] = ax0.x;       L[lane * 2 + 1] = ax0.y;
    L[128 + lane * 2 + 0] = ax1.x; L[128 + lane * 2 + 1] = ax1.y;
    L[256 + lane * 2 + 0] = ax2.x; L[256 + lane * 2 + 1] = ax2.y;
    if (lane < 16) {
      L[384 + lane * 2 + 0] = ae0.x; L[384 + lane * 2 + 1] = ae0.y;
      L[416 + lane * 2 + 0] = ae1.x; L[416 + lane * 2 + 1] = ae1.y;
      L[448 + lane * 2 + 0] = ae2.x; L[448 + lane * 2 + 1] = ae2.y;
    }
    if (lane == 0) { L[480] = d0; L[481] = d1; L[482] = d2; }
  }
  __syncthreads();
  if (w == 0 && n0 < N) {
    ax0.x += L[lane * 2 + 0];       ax0.y += L[lane * 2 + 1];
    ax1.x += L[128 + lane * 2 + 0]; ax1.y += L[128 + lane * 2 + 1];
    ax2.x += L[256 + lane * 2 + 0]; ax2.y += L[256 + lane * 2 + 1];
    if (lane < 16) {
      ae0.x += L[384 + lane * 2 + 0]; ae0.y += L[384 + lane * 2 + 1];
      ae1.x += L[416 + lane * 2 + 0]; ae1.y += L[416 + lane * 2 + 1];
      ae2.x += L[448 + lane * 2 + 0]; ae2.y += L[448 + lane * 2 + 1];
    }
    d0 += L[480]; d1 += L[481]; d2 += L[482];
    const float third = 1.0f / 3.0f;
    float i0 = third / fmaxf(d0, 1e-30f);
    float i1 = third / fmaxf(d1, 1e-30f);
    float i2 = third / fmaxf(d2, 1e-30f);
    aggr_u[(size_t)n0 * 80 + lane] =
        pk2(ax0.x * i0 + ax1.x * i1 + ax2.x * i2,
            ax0.y * i0 + ax1.y * i1 + ax2.y * i2);
    if (lane < 16)
      aggr_u[(size_t)n0 * 80 + 64 + lane] =
          pk2(ae0.x * i0 + ae1.x * i1 + ae2.x * i2,
              ae0.y * i0 + ae1.y * i1 + ae2.y * i2);
  }
}

// ------------------------------------------------------------------
// final layer: out = aggr @ euw + bias via MFMA, store d_out in
// detected dtype. Grid (N/16, 2), 4 waves/block.
// ------------------------------------------------------------------
__global__ __launch_bounds__(256) void gemm_out_mfma(
    const bf16* __restrict__ aggr, const bf16* __restrict__ euwT,
    const float* __restrict__ biasf, void* __restrict__ dout,
    const int* __restrict__ flag, int N) {
  int wave = threadIdx.x >> 6, lane = threadIdx.x & 63;
  int row_base = blockIdx.x * 16;
  int col_base = blockIdx.y * 64 + wave * 16;
  int quad = lane >> 4, r16 = lane & 15;
  int row = row_base + r16; if (row >= N) row = N - 1;
  int col = col_base + r16;
  f32x4 acc = {0.f, 0.f, 0.f, 0.f};
  const short8* ap = (const short8*)(aggr + (size_t)row * 160 + quad * 8);
  const short8* bp = (const short8*)(euwT + (size_t)col * 160 + quad * 8);
#pragma unroll
  for (int kk = 0; kk < 5; ++kk) {
    short8 a = ap[kk * 4];
    short8 b = bp[kk * 4];
    acc = __builtin_amdgcn_mfma_f32_16x16x32_bf16(a, b, acc, 0, 0, 0);
  }
  float bv = biasf[col];
  int f = *flag;
#pragma unroll
  for (int r = 0; r < 4; ++r) {
    int node = row_base + quad * 4 + r;
    if (node < N) {
      float v = acc[r] + bv;
      if (f) ((float*)dout)[(size_t)node * 128 + col] = v;
      else   ((bf16*)dout)[(size_t)node * 128 + col] = __float2bfloat16(v);
    }
  }
}

// ------------------------------------------------------------------
extern "C" void kernel_launch(void* const* d_in, const int* in_sizes, int n_in,
                              void* d_out, int out_size, void* d_ws, size_t ws_size,
                              hipStream_t stream) {
  const int* x_idx = (const int*)d_in[0];
  const int* edge_index = (const int*)d_in[1];
  const int* edge_attr_idx = (const int*)d_in[2];

  int N = in_sizes[0];
  int E0 = in_sizes[1] / 2;
  int E = E0 + N;
  const int* src = edge_index;
  const int* dst = edge_index + E0;

  // ---- workspace carve (~12.2 MB) ----
  size_t off = 0;
  char* base = (char*)d_ws;
  auto carve = [&](size_t bytes) -> void* {
    void* p = base + off;
    off += (bytes + 255) & ~(size_t)255;
    return p;
  };
  int* flag     = (int*)carve(256);
  int* counts   = (int*)carve((size_t)N * 4);    // becomes cursor after scan
  int* row_ptr  = (int*)carve((size_t)(N + 1) * 4);
  int* packed   = (int*)carve((size_t)E * 4);
  float* s_i    = (float*)carve((size_t)N * 3 * 4);
  float* s_j    = (float*)carve((size_t)N * 3 * 4);
  float* s_et   = (float*)carve(2 * 65 * 3 * 4);
  float* eef    = (float*)carve(2048 * 4);
  float* att1f  = (float*)carve(864 * 4);
  float* att2f  = (float*)carve(864 * 4);
  float* b1f    = (float*)carve(128 * 4);
  float* b2f_   = (float*)carve(128 * 4);
  bf16* WT1     = (bf16*)carve(49152 * 2);
  bf16* WT2     = (bf16*)carve(49152 * 2);
  bf16* euT1    = (bf16*)carve(20480 * 2);
  bf16* euT2    = (bf16*)carve(20480 * 2);
  bf16* xh      = (bf16*)carve((size_t)N * 384 * 2 + 64);
  bf16* aggr    = (bf16*)carve((size_t)N * 160 * 2);
  bf16* xb      = (bf16*)d_out;  // bf16 x0 lives in d_out
  (void)n_in; (void)out_size; (void)ws_size;

  // ---- setup: 4 dispatches ----
  wconv_kernel<<<(143296 + N + 255) / 256, 256, 0, stream>>>(
      d_in[4], d_in[5], d_in[6], d_in[7], d_in[8], d_in[9], d_in[10], d_in[11],
      d_in[12], flag, eef, att1f, att2f, b1f, b2f_, WT1, WT2, euT1, euT2,
      s_et, counts, N);
  int nb4 = (N + 3) / 4;
  prep_kernel<<<nb4, 256, 0, stream>>>(x_idx, d_in[3], flag, xb, counts, dst,
                                       E0, N);
  scan_kernel<<<1, 1024, 0, stream>>>(counts, row_ptr, N);
  scatter_kernel<<<(E + 255) / 256, 256, 0, stream>>>(src, dst, edge_attr_idx,
                                                      counts, packed, E0, N);

  int nrb16 = (N + 15) / 16;
  int nrb32 = (N + 31) / 32;
  int nb2 = (N + 1) / 2;

  // layer (0,0): W1/att1
  gemm_xh_s_mfma<<<nrb32, 384, 0, stream>>>(xb, WT1, att1f, xh, s_i, s_j, N);
  edge_aggr_kernel<<<nb2, 256, 0, stream>>>(
      (const int*)xh, s_i, s_j, s_et, (const float2*)eef,
      row_ptr, packed, (unsigned*)aggr, N, E);
  // boundary (0,0)->(0,1): euw1+b1+ELU, then W2/att2
  fox_kernel<<<nrb16, 384, 0, stream>>>(aggr, euT1, b1f, 1, WT2, att2f,
                                        xh, s_i, s_j, N);
  edge_aggr_kernel<<<nb2, 256, 0, stream>>>(
      (const int*)xh, s_i, s_j, s_et + 195, (const float2*)eef,
      row_ptr, packed, (unsigned*)aggr, N, E);
  // boundary (0,1)->(1,0): euw2+b2 (no ELU), then W1/att1
  fox_kernel<<<nrb16, 384, 0, stream>>>(aggr, euT2, b2f_, 0, WT1, att1f,
                                        xh, s_i, s_j, N);
  edge_aggr_kernel<<<nb2, 256, 0, stream>>>(
      (const int*)xh, s_i, s_j, s_et, (const float2*)eef,
      row_ptr, packed, (unsigned*)aggr, N, E);
  // boundary (1,0)->(1,1): euw1+b1+ELU, then W2/att2
  fox_kernel<<<nrb16, 384, 0, stream>>>(aggr, euT1, b1f, 1, WT2, att2f,
                                        xh, s_i, s_j, N);
  edge_aggr_kernel<<<nb2, 256, 0, stream>>>(
      (const int*)xh, s_i, s_j, s_et + 195, (const float2*)eef,
      row_ptr, packed, (unsigned*)aggr, N, E);
  // final: euw2+b2, store d_out
  gemm_out_mfma<<<dim3(nrb16, 2), 256, 0, stream>>>(aggr, euT2, b2f_,
                                                    d_out, flag, N);
}